// Round 1
// baseline (9075.294 us; speedup 1.0000x reference)
//
#include <hip/hip_runtime.h>
#include <hip/hip_bf16.h>

#define A_N 100000
#define C_N 230
#define V_N 800
#define G_N 60

#define FLAG_ACC  1
#define FLAG_RELU 2

__device__ __forceinline__ float bf16dec(unsigned short u){
  return __uint_as_float(((unsigned)u) << 16);
}

// ---------------------------------------------------------------- detect dtype
// Reinterpret first 2048 16-bit halves of x_event as bf16. If the buffer holds
// fp32, ~half the halves are fp32-mantissa bits -> random bf16 exponents ->
// some |v| > 1e6 or NaN with probability ~1. If bf16-stored N(0,1): all small.
__global__ void detect_dtype(const unsigned short* __restrict__ p, int* __restrict__ flag){
  __shared__ int bad;
  if (threadIdx.x == 0) bad = 0;
  __syncthreads();
  for (int i = threadIdx.x; i < 2048; i += blockDim.x){
    float v = fabsf(bf16dec(p[i]));
    if (!(v <= 1e6f)) atomicOr(&bad, 1);   // catches NaN too
  }
  __syncthreads();
  if (threadIdx.x == 0) *flag = bad;       // 1 => inputs stored as fp32
}

// ---------------------------------------------------------------- convert all
struct ConvTab {
  const void* src[29];
  int dstoff[29];
  int cum[30];
};

__global__ void convert_all(ConvTab tab, float* __restrict__ wsf,
                            const int* __restrict__ flagp, int total){
  const int f = *flagp;
  for (int idx = blockIdx.x*blockDim.x + threadIdx.x; idx < total;
       idx += gridDim.x*blockDim.x){
    int t = 0;
    while (idx >= tab.cum[t+1]) ++t;
    int l = idx - tab.cum[t];
    float v = f ? ((const float*)tab.src[t])[l]
                : bf16dec(((const unsigned short*)tab.src[t])[l]);
    wsf[tab.dstoff[t] + l] = v;
  }
}

// ---------------------------------------------------------------- prep combos
// wrcomb[t] = sum_{k in S(t)} sage_Wr[k] / |S|, plus combined sage/gat biases.
__global__ void prep_combos(const float* __restrict__ sWr, const float* __restrict__ sbl,
                            const float* __restrict__ gbias,
                            float* __restrict__ wrcomb, float* __restrict__ sbcomb,
                            float* __restrict__ gbcomb){
  const int sets[4][3] = {{1,3,5},{0,-1,-1},{2,7,-1},{4,6,-1}};
  const float inv[4] = {1.f/3.f, 1.f, 0.5f, 0.5f};
  int idx = blockIdx.x*blockDim.x + threadIdx.x;
  if (idx >= 4*16384) return;
  int t = idx >> 14, j = idx & 16383;
  float s = 0.f;
  #pragma unroll
  for (int q = 0; q < 3; ++q){
    int k = sets[t][q];
    if (k >= 0) s += sWr[k*16384 + j];
  }
  wrcomb[idx] = s * inv[t];
  if (j < 128){
    float b1 = 0.f, b2 = 0.f;
    #pragma unroll
    for (int q = 0; q < 3; ++q){
      int k = sets[t][q];
      if (k >= 0){ b1 += sbl[k*128 + j]; b2 += gbias[k*128 + j]; }
    }
    sbcomb[t*128 + j] = b1 * inv[t];
    gbcomb[t*128 + j] = b2 * inv[t];
  }
}

// ---------------------------------------------------------------- encoder L1 (tiny K)
__global__ void enc_l1(const float* __restrict__ X, const float* __restrict__ W1,
                       const float* __restrict__ b1, float* __restrict__ Z,
                       int M, int K){
  int idx = blockIdx.x*blockDim.x + threadIdx.x;
  if (idx >= M*128) return;
  int r = idx >> 7, c = idx & 127;
  float s = b1[c];
  for (int k = 0; k < K; ++k) s = fmaf(X[r*K + k], W1[(k<<7) + c], s);
  Z[idx] = fmaxf(s, 0.f);
}

// ---------------------------------------------------------------- generic N=128 GEMM
// Y[M,128] = op( (X (*rowscale)) @ W[K,128] * scale + bias ), optional +=, relu.
// rowscale = 1/max(cnt[r],1) when cnt != null (SAGE segment-mean).
__global__ __launch_bounds__(256) void linear128(
    const float* __restrict__ X, const float* __restrict__ W,
    const float* __restrict__ bias, const int* __restrict__ cnt,
    float* __restrict__ Y, int M, int K, float scale, int flags)
{
  __shared__ float Ws[64][128];   // 32 KB
  __shared__ float XsT[64][36];   // 9 KB, k-major, padded to 144B rows (16B aligned)
  const int tid  = threadIdx.x;
  const int m0   = blockIdx.x * 32;
  const int col4 = (tid & 31) * 4;
  const int row4 = (tid >> 5) * 4;
  float acc[4][4] = {};
  for (int k0 = 0; k0 < K; k0 += 64){
    const int kc = min(64, K - k0);
    for (int i = tid*4; i < kc*128; i += 1024){
      *(float4*)&Ws[i>>7][i&127] = *(const float4*)(W + (size_t)(k0 + (i>>7))*128 + (i&127));
    }
    const int nf4 = kc >> 2;
    for (int i = tid; i < 32*nf4; i += 256){
      int r = i / nf4, fq = i - r*nf4;
      int gr = m0 + r;
      float4 x = {0.f,0.f,0.f,0.f};
      if (gr < M){
        x = *(const float4*)(X + (size_t)gr*K + k0 + fq*4);
        if (cnt){
          int cc = cnt[gr];
          float rs = 1.0f / (float)(cc > 1 ? cc : 1);
          x.x *= rs; x.y *= rs; x.z *= rs; x.w *= rs;
        }
      }
      XsT[fq*4+0][r] = x.x; XsT[fq*4+1][r] = x.y;
      XsT[fq*4+2][r] = x.z; XsT[fq*4+3][r] = x.w;
    }
    __syncthreads();
    #pragma unroll 8
    for (int k = 0; k < kc; ++k){
      float4 wv = *(float4*)&Ws[k][col4];
      float4 xv = *(float4*)&XsT[k][row4];
      acc[0][0] = fmaf(xv.x, wv.x, acc[0][0]); acc[0][1] = fmaf(xv.x, wv.y, acc[0][1]);
      acc[0][2] = fmaf(xv.x, wv.z, acc[0][2]); acc[0][3] = fmaf(xv.x, wv.w, acc[0][3]);
      acc[1][0] = fmaf(xv.y, wv.x, acc[1][0]); acc[1][1] = fmaf(xv.y, wv.y, acc[1][1]);
      acc[1][2] = fmaf(xv.y, wv.z, acc[1][2]); acc[1][3] = fmaf(xv.y, wv.w, acc[1][3]);
      acc[2][0] = fmaf(xv.z, wv.x, acc[2][0]); acc[2][1] = fmaf(xv.z, wv.y, acc[2][1]);
      acc[2][2] = fmaf(xv.z, wv.z, acc[2][2]); acc[2][3] = fmaf(xv.z, wv.w, acc[2][3]);
      acc[3][0] = fmaf(xv.w, wv.x, acc[3][0]); acc[3][1] = fmaf(xv.w, wv.y, acc[3][1]);
      acc[3][2] = fmaf(xv.w, wv.z, acc[3][2]); acc[3][3] = fmaf(xv.w, wv.w, acc[3][3]);
    }
    __syncthreads();
  }
  float4 bv = {0.f,0.f,0.f,0.f};
  if (bias) bv = *(const float4*)(bias + col4);
  #pragma unroll
  for (int i = 0; i < 4; ++i){
    int gr = m0 + row4 + i;
    if (gr >= M) break;
    float* yp = Y + (size_t)gr*128 + col4;
    float4 v;
    v.x = acc[i][0]*scale + bv.x; v.y = acc[i][1]*scale + bv.y;
    v.z = acc[i][2]*scale + bv.z; v.w = acc[i][3]*scale + bv.w;
    if (flags & FLAG_ACC){
      float4 o = *(float4*)yp;
      v.x += o.x; v.y += o.y; v.z += o.z; v.w += o.w;
    }
    if (flags & FLAG_RELU){
      v.x = fmaxf(v.x,0.f); v.y = fmaxf(v.y,0.f);
      v.z = fmaxf(v.z,0.f); v.w = fmaxf(v.w,0.f);
    }
    *(float4*)yp = v;
  }
}

// ---------------------------------------------------------------- SAGE scatter
// 32 lanes per edge, float4 per lane. Replicated accumulators (R power of 2).
__global__ void sage_scatter(const float* __restrict__ feat, const int* __restrict__ src,
    const int* __restrict__ dst, int E, float* __restrict__ agg, int* __restrict__ cnt,
    int ndst, int R)
{
  int g = (blockIdx.x*blockDim.x + threadIdx.x) >> 5;
  if (g >= E) return;
  int lane = threadIdx.x & 31;
  int s = src[g], d = dst[g];
  int rep = blockIdx.x & (R-1);
  float4 v = *(const float4*)(feat + (size_t)s*128 + lane*4);
  float* o = agg + ((size_t)rep*ndst + d)*128 + lane*4;
  atomicAdd(o+0, v.x); atomicAdd(o+1, v.y); atomicAdd(o+2, v.z); atomicAdd(o+3, v.w);
  if (lane == 0) atomicAdd(cnt + d, 1);
}

__global__ void reduce_rep_sum(float* __restrict__ buf, int n, int R){
  int idx = blockIdx.x*blockDim.x + threadIdx.x;
  if (idx >= n) return;
  float s = buf[idx];
  for (int r = 1; r < R; ++r) s += buf[(size_t)r*n + idx];
  buf[idx] = s;
}

__global__ void relu_k(float* __restrict__ x, int n){
  int idx = blockIdx.x*blockDim.x + threadIdx.x;
  if (idx < n) x[idx] = fmaxf(x[idx], 0.f);
}

// ---------------------------------------------------------------- GATv2 edge kernels
__global__ void gat_logit(const float* __restrict__ xl, const float* __restrict__ xr,
  const int* __restrict__ src, const int* __restrict__ dst, const float* __restrict__ att,
  float* __restrict__ logitbuf, unsigned* __restrict__ mrep, int E, int ndst, int R)
{
  int g = (blockIdx.x*blockDim.x + threadIdx.x) >> 5;
  if (g >= E) return;
  int lane = threadIdx.x & 31;
  int head = lane >> 3;
  int s = src[g], d = dst[g];
  float4 a  = *(const float4*)(xl + (size_t)s*128 + lane*4);
  float4 b  = *(const float4*)(xr + (size_t)d*128 + lane*4);
  float4 av = *(const float4*)(att + lane*4);
  float e0 = a.x + b.x, e1 = a.y + b.y, e2 = a.z + b.z, e3 = a.w + b.w;
  e0 = e0 > 0.f ? e0 : 0.2f*e0; e1 = e1 > 0.f ? e1 : 0.2f*e1;
  e2 = e2 > 0.f ? e2 : 0.2f*e2; e3 = e3 > 0.f ? e3 : 0.2f*e3;
  float sum = e0*av.x + e1*av.y + e2*av.z + e3*av.w;
  sum += __shfl_xor(sum, 1);
  sum += __shfl_xor(sum, 2);
  sum += __shfl_xor(sum, 4);
  if ((lane & 7) == 0){
    logitbuf[(size_t)g*4 + head] = sum;
    int ib = __float_as_int(sum);
    unsigned enc = (unsigned)(ib ^ ((ib >> 31) | 0x80000000));
    atomicMax(mrep + ((size_t)(blockIdx.x & (R-1))*ndst + d)*4 + head, enc);
  }
}

__global__ void reduce_m(const unsigned* __restrict__ rep, float* __restrict__ fin,
                         int n, int R){
  int idx = blockIdx.x*blockDim.x + threadIdx.x;
  if (idx >= n) return;
  unsigned e = rep[idx];
  for (int r = 1; r < R; ++r){ unsigned t = rep[(size_t)r*n + idx]; e = t > e ? t : e; }
  unsigned u = (e & 0x80000000u) ? (e ^ 0x80000000u) : ~e;
  fin[idx] = __uint_as_float(u);
}

__global__ void gat_den(float* __restrict__ logitbuf, const int* __restrict__ dst,
  const float* __restrict__ mfin, float* __restrict__ denrep, int E, int ndst, int R)
{
  int idx = blockIdx.x*blockDim.x + threadIdx.x;
  if (idx >= E*4) return;
  int e = idx >> 2, h = idx & 3;
  int d = dst[e];
  float ex = __expf(logitbuf[idx] - mfin[d*4 + h]);
  logitbuf[idx] = ex;   // overwrite logit with exp for the scatter pass
  atomicAdd(denrep + ((size_t)(blockIdx.x & (R-1))*ndst + d)*4 + h, ex);
}

__global__ void reduce_den(const float* __restrict__ rep, float* __restrict__ fin,
                           int n, int R){
  int idx = blockIdx.x*blockDim.x + threadIdx.x;
  if (idx >= n) return;
  float s = rep[idx];
  for (int r = 1; r < R; ++r) s += rep[(size_t)r*n + idx];
  fin[idx] = s;
}

__global__ void gat_scatter(const float* __restrict__ xl, const float* __restrict__ exbuf,
  const float* __restrict__ denfin, const int* __restrict__ src, const int* __restrict__ dst,
  float* __restrict__ out, int E, int ndst, int R, float invS)
{
  int g = (blockIdx.x*blockDim.x + threadIdx.x) >> 5;
  if (g >= E) return;
  int lane = threadIdx.x & 31, head = lane >> 3;
  int s = src[g], d = dst[g];
  float alpha = exbuf[(size_t)g*4 + head] / (denfin[d*4 + head] + 1e-16f) * invS;
  float4 v = *(const float4*)(xl + (size_t)s*128 + lane*4);
  float* o = out + ((size_t)(blockIdx.x & (R-1))*ndst + d)*128 + lane*4;
  atomicAdd(o+0, v.x*alpha); atomicAdd(o+1, v.y*alpha);
  atomicAdd(o+2, v.z*alpha); atomicAdd(o+3, v.w*alpha);
}

// ---------------------------------------------------------------- final output
__global__ void final_out(const float* __restrict__ outA, const float* __restrict__ outC,
  const float* __restrict__ outE, const float* __restrict__ outG,
  const float* __restrict__ gbcomb, const int* __restrict__ flagp, void* __restrict__ dout)
{
  const int f = *flagp;
  int idx = blockIdx.x*blockDim.x + threadIdx.x;
  const int total = 101090*128;
  if (idx >= total) return;
  int row = idx >> 7, c = idx & 127;
  float v; int t;
  if (row < A_N){ v = outA[idx]; t = 0; }
  else if (row < A_N + C_N){
    int l = row - A_N; v = 0.f; t = 1;
    for (int r = 0; r < 8; ++r) v += outC[((size_t)r*C_N + l)*128 + c];
  } else if (row < A_N + C_N + V_N){
    int l = row - (A_N + C_N); v = 0.f; t = 2;
    for (int r = 0; r < 8; ++r) v += outE[((size_t)r*V_N + l)*128 + c];
  } else {
    int l = row - (A_N + C_N + V_N); v = 0.f; t = 3;
    for (int r = 0; r < 8; ++r) v += outG[((size_t)r*G_N + l)*128 + c];
  }
  v += gbcomb[t*128 + c];
  if (f) ((float*)dout)[idx] = v;
  else   ((__hip_bfloat16*)dout)[idx] = __float2bfloat16(v);
}

__global__ void ws_fail(float* __restrict__ out, float mb){
  if (threadIdx.x == 0 && blockIdx.x == 0) out[0] = mb;  // signal ws shortfall via absmax
}

// ================================================================ host
extern "C" void kernel_launch(void* const* d_in, const int* in_sizes, int n_in,
                              void* d_out, int out_size, void* d_ws, size_t ws_size,
                              hipStream_t stream)
{
  float* wsf = (float*)d_ws;
  int* flagp = (int*)d_ws;
  size_t off = 16;
  auto alloc = [&](size_t n){ size_t o = off; off += (n + 15) & ~(size_t)15; return o; };

  static const int conv_in_idx[29] = {0,1,2,3, 8,9,10,11, 12,13,14,15, 16,17,18,19,
                                      20,21,22,23, 24,25,26, 27,28,29,30,31,32};
  static const int conv_n[29] = {700000,690,307200,120,
                                 896,128,16384,128, 384,128,16384,128,
                                 49152,128,16384,128, 256,128,16384,128,
                                 131072,1024,131072, 131072,1024,131072,1024,1024,1024};
  ConvTab tab;
  const float* cw[29];
  int total = 0;
  for (int i = 0; i < 29; ++i){
    tab.src[i] = d_in[conv_in_idx[i]];
    size_t o = alloc((size_t)conv_n[i]);
    tab.dstoff[i] = (int)o;
    cw[i] = wsf + o;
    tab.cum[i] = total; total += conv_n[i];
  }
  tab.cum[29] = total;

  const float* xf[4]  = {cw[0], cw[1], cw[2], cw[3]};
  const float* eW1[4] = {cw[4], cw[8],  cw[12], cw[16]};
  const float* eb1[4] = {cw[5], cw[9],  cw[13], cw[17]};
  const float* eW2[4] = {cw[6], cw[10], cw[14], cw[18]};
  const float* eb2[4] = {cw[7], cw[11], cw[15], cw[19]};
  const float* sWl = cw[20]; const float* sbl = cw[21]; const float* sWr = cw[22];
  const float* gWl = cw[23]; const float* gbl = cw[24]; const float* gWr = cw[25];
  const float* gbr = cw[26]; const float* gatt = cw[27]; const float* gbias = cw[28];

  float* wrcomb = wsf + alloc(4*16384);
  float* sbcomb = wsf + alloc(512);
  float* gbcomb = wsf + alloc(512);
  float* hC = wsf + alloc((size_t)C_N*128);
  float* hE = wsf + alloc((size_t)V_N*128);
  float* hG = wsf + alloc((size_t)G_N*128);
  float* yC = wsf + alloc((size_t)C_N*128);
  float* yE = wsf + alloc((size_t)V_N*128);
  float* yG = wsf + alloc((size_t)G_N*128);
  float* outC = wsf + alloc((size_t)8*C_N*128);
  float* outE = wsf + alloc((size_t)8*V_N*128);
  float* outG = wsf + alloc((size_t)8*G_N*128);
  float* fragL = wsf + alloc((size_t)V_N*128);
  float* fragR = wsf + alloc((size_t)V_N*128);
  unsigned* mrep = (unsigned*)(wsf + alloc(400000));
  float* denrep  = wsf + alloc(400000);
  float* mfin    = wsf + alloc(400000);
  float* denfin  = wsf + alloc(400000);
  float* logitbuf = wsf + alloc(2000000);
  int* cntb = (int*)(wsf + alloc(100000));
  float* bufA = wsf + alloc((size_t)A_N*128);  // hA, then GAT athlete out-accumulator
  float* bufZ = wsf + alloc((size_t)A_N*128);  // enc intermediate / SAGE agg / GAT big frag
  float* bufY = wsf + alloc((size_t)A_N*128);  // yA

  if (off*4 > ws_size){
    ws_fail<<<1, 64, 0, stream>>>((float*)d_out, (float)((off*4) >> 20));
    return;
  }

  const int n_nodes[4] = {A_N, C_N, V_N, G_N};
  const int et_src[8] = {0,1,0,2,0,3,2,3};
  const int et_dst[8] = {1,0,2,0,3,0,3,2};
  const int et_ei[8]  = {4,4,5,5,6,6,7,7};
  const int et_rev[8] = {0,1,0,1,0,1,0,1};
  const int et_E[8]   = {100000,100000,500000,500000,300000,300000,2000,2000};
  const float invS[4] = {1.f/3.f, 1.f, 0.5f, 0.5f};

  float* hbuf[4] = {bufA, hC, hE, hG};
  float* ybuf[4] = {bufY, yC, yE, yG};
  float* obuf[4] = {bufA, outC, outE, outG};

  detect_dtype<<<1, 256, 0, stream>>>((const unsigned short*)d_in[2], flagp);
  convert_all<<<2048, 256, 0, stream>>>(tab, wsf, flagp, total);
  prep_combos<<<(4*16384 + 255)/256, 256, 0, stream>>>(sWr, sbl, gbias, wrcomb, sbcomb, gbcomb);

  // ---------------- encoders
  enc_l1<<<(A_N*128 + 255)/256, 256, 0, stream>>>(xf[0], eW1[0], eb1[0], bufZ, A_N, 7);
  linear128<<<(A_N + 31)/32, 256, 0, stream>>>(bufZ, eW2[0], eb2[0], nullptr, bufA, A_N, 128, 1.f, 0);
  enc_l1<<<(C_N*128 + 255)/256, 256, 0, stream>>>(xf[1], eW1[1], eb1[1], fragL, C_N, 3);
  linear128<<<(C_N + 31)/32, 256, 0, stream>>>(fragL, eW2[1], eb2[1], nullptr, hC, C_N, 128, 1.f, 0);
  linear128<<<(V_N + 31)/32, 256, 0, stream>>>(xf[2], eW1[2], eb1[2], nullptr, logitbuf, V_N, 384, 1.f, FLAG_RELU);
  linear128<<<(V_N + 31)/32, 256, 0, stream>>>(logitbuf, eW2[2], eb2[2], nullptr, hE, V_N, 128, 1.f, 0);
  enc_l1<<<(G_N*128 + 255)/256, 256, 0, stream>>>(xf[3], eW1[3], eb1[3], fragL, G_N, 2);
  linear128<<<(G_N + 31)/32, 256, 0, stream>>>(fragL, eW2[3], eb2[3], nullptr, hG, G_N, 128, 1.f, 0);

  // ---------------- layer 1: hetero SAGE (mean aggr within etype, mean over etypes)
  for (int D = 0; D < 4; ++D){
    int nd = n_nodes[D];
    // x_dst @ (sum Wr_k)/|S| + (sum bl_k)/|S|  (first write, no accumulate)
    linear128<<<(nd + 31)/32, 256, 0, stream>>>(hbuf[D], wrcomb + D*16384, sbcomb + D*128,
                                                nullptr, ybuf[D], nd, 128, 1.f, 0);
    for (int k = 0; k < 8; ++k){
      if (et_dst[k] != D) continue;
      int E = et_E[k];
      int R = (nd <= 800) ? 8 : 1;
      const int* ei = (const int*)d_in[et_ei[k]];
      const int* sidx = ei + (et_rev[k] ? E : 0);
      const int* didx = ei + (et_rev[k] ? 0 : E);
      hipMemsetAsync(bufZ, 0, (size_t)R*nd*128*4, stream);
      hipMemsetAsync(cntb, 0, (size_t)nd*4, stream);
      sage_scatter<<<(E*32 + 255)/256, 256, 0, stream>>>(hbuf[et_src[k]], sidx, didx, E,
                                                         bufZ, cntb, nd, R);
      if (R > 1) reduce_rep_sum<<<(nd*128 + 255)/256, 256, 0, stream>>>(bufZ, nd*128, R);
      linear128<<<(nd + 31)/32, 256, 0, stream>>>(bufZ, sWl + k*16384, nullptr, cntb,
                                                  ybuf[D], nd, 128, invS[D], FLAG_ACC);
    }
    relu_k<<<(nd*128 + 255)/256, 256, 0, stream>>>(ybuf[D], nd*128);
  }

  // ---------------- layer 2: hetero GATv2 (mean over etypes)
  hipMemsetAsync(bufA, 0, (size_t)A_N*128*4, stream);
  hipMemsetAsync(outC, 0, (size_t)8*C_N*128*4, stream);
  hipMemsetAsync(outE, 0, (size_t)8*V_N*128*4, stream);
  hipMemsetAsync(outG, 0, (size_t)8*G_N*128*4, stream);
  for (int k = 0; k < 8; ++k){
    int st = et_src[k], dt = et_dst[k];
    int ns = n_nodes[st], nd = n_nodes[dt], E = et_E[k];
    const int* ei = (const int*)d_in[et_ei[k]];
    const int* sidx = ei + (et_rev[k] ? E : 0);
    const int* didx = ei + (et_rev[k] ? 0 : E);
    float* xl = (st == 0) ? bufZ : fragL;   // at most one of xl/xr is athlete-sized
    float* xr = (dt == 0) ? bufZ : fragR;
    linear128<<<(ns + 31)/32, 256, 0, stream>>>(ybuf[st], gWl + k*16384, gbl + k*128,
                                                nullptr, xl, ns, 128, 1.f, 0);
    linear128<<<(nd + 31)/32, 256, 0, stream>>>(ybuf[dt], gWr + k*16384, gbr + k*128,
                                                nullptr, xr, nd, 128, 1.f, 0);
    int R = (nd <= 800) ? 8 : 1;
    hipMemsetAsync(mrep,   0, (size_t)R*nd*4*4, stream);
    hipMemsetAsync(denrep, 0, (size_t)R*nd*4*4, stream);
    gat_logit<<<(E*32 + 255)/256, 256, 0, stream>>>(xl, xr, sidx, didx, gatt + k*128,
                                                    logitbuf, mrep, E, nd, R);
    reduce_m<<<(nd*4 + 255)/256, 256, 0, stream>>>(mrep, mfin, nd*4, R);
    gat_den<<<(E*4 + 255)/256, 256, 0, stream>>>(logitbuf, didx, mfin, denrep, E, nd, R);
    reduce_den<<<(nd*4 + 255)/256, 256, 0, stream>>>(denrep, denfin, nd*4, R);
    gat_scatter<<<(E*32 + 255)/256, 256, 0, stream>>>(xl, logitbuf, denfin, sidx, didx,
                                                      obuf[dt], E, nd, (dt == 0) ? 1 : 8,
                                                      invS[dt]);
  }

  final_out<<<(101090*128 + 255)/256, 256, 0, stream>>>(bufA, outC, outE, outG,
                                                        gbcomb, flagp, d_out);
}

// Round 2
// 2902.132 us; speedup vs baseline: 3.1271x; 3.1271x over previous
//
#include <hip/hip_runtime.h>
#include <hip/hip_bf16.h>

#define A_N 100000
#define C_N 230
#define V_N 800
#define G_N 60

#define FLAG_ACC  1
#define FLAG_RELU 2

#define NR_TOTAL 301950          // sum of dst-node counts over 8 relations
#define SCAN_N   302080          // 295 * 1024 (padded)
#define SCAN_NB  295
#define E_TOTAL  1804000

__device__ __forceinline__ float bf16dec(unsigned short u){
  return __uint_as_float(((unsigned)u) << 16);
}

// ---------------------------------------------------------------- detect dtype
__global__ void detect_dtype(const unsigned short* __restrict__ p, int* __restrict__ flag){
  __shared__ int bad;
  if (threadIdx.x == 0) bad = 0;
  __syncthreads();
  for (int i = threadIdx.x; i < 2048; i += blockDim.x){
    float v = fabsf(bf16dec(p[i]));
    if (!(v <= 1e6f)) atomicOr(&bad, 1);
  }
  __syncthreads();
  if (threadIdx.x == 0) *flag = bad;       // 1 => inputs stored as fp32
}

// ---------------------------------------------------------------- convert all
struct ConvTab {
  const void* src[29];
  int dstoff[29];
  int cum[30];
};

__global__ void convert_all(ConvTab tab, float* __restrict__ wsf,
                            const int* __restrict__ flagp, int total){
  const int f = *flagp;
  for (int idx = blockIdx.x*blockDim.x + threadIdx.x; idx < total;
       idx += gridDim.x*blockDim.x){
    int t = 0;
    while (idx >= tab.cum[t+1]) ++t;
    int l = idx - tab.cum[t];
    float v = f ? ((const float*)tab.src[t])[l]
                : bf16dec(((const unsigned short*)tab.src[t])[l]);
    wsf[tab.dstoff[t] + l] = v;
  }
}

// ---------------------------------------------------------------- prep combos
__global__ void prep_combos(const float* __restrict__ sWr, const float* __restrict__ sbl,
                            const float* __restrict__ gbias,
                            float* __restrict__ wrcomb, float* __restrict__ sbcomb,
                            float* __restrict__ gbcomb){
  const int sets[4][3] = {{1,3,5},{0,-1,-1},{2,7,-1},{4,6,-1}};
  const float inv[4] = {1.f/3.f, 1.f, 0.5f, 0.5f};
  int idx = blockIdx.x*blockDim.x + threadIdx.x;
  if (idx >= 4*16384) return;
  int t = idx >> 14, j = idx & 16383;
  float s = 0.f;
  #pragma unroll
  for (int q = 0; q < 3; ++q){
    int k = sets[t][q];
    if (k >= 0) s += sWr[k*16384 + j];
  }
  wrcomb[idx] = s * inv[t];
  if (j < 128){
    float b1 = 0.f, b2 = 0.f;
    #pragma unroll
    for (int q = 0; q < 3; ++q){
      int k = sets[t][q];
      if (k >= 0){ b1 += sbl[k*128 + j]; b2 += gbias[k*128 + j]; }
    }
    sbcomb[t*128 + j] = b1 * inv[t];
    gbcomb[t*128 + j] = b2 * inv[t];
  }
}

// ---------------------------------------------------------------- CSR build
struct EdgeTab { const int* sp[8]; const int* dp[8]; };
struct RelTab  { int estart[9]; int rowbase[8]; };

__global__ void hist_k(EdgeTab et, RelTab rt, int* __restrict__ cnt){
  for (int idx = blockIdx.x*blockDim.x + threadIdx.x; idx < E_TOTAL;
       idx += gridDim.x*blockDim.x){
    int k = 0;
    while (idx >= rt.estart[k+1]) ++k;
    int e = idx - rt.estart[k];
    int d = et.dp[k][e];
    atomicAdd(&cnt[rt.rowbase[k] + d], 1);
  }
}

__global__ void scan1(const int* __restrict__ cnt, int* __restrict__ rp, int* __restrict__ bsum){
  __shared__ int sd[256];
  int tid = threadIdx.x, blk = blockIdx.x;
  int base = blk*1024 + tid*4;
  int4 v = *(const int4*)(cnt + base);
  int s = v.x + v.y + v.z + v.w;
  sd[tid] = s;
  __syncthreads();
  for (int off = 1; off < 256; off <<= 1){
    int t = (tid >= off) ? sd[tid-off] : 0;
    __syncthreads();
    sd[tid] += t;
    __syncthreads();
  }
  int excl = sd[tid] - s;
  rp[base+0] = excl;
  rp[base+1] = excl + v.x;
  rp[base+2] = excl + v.x + v.y;
  rp[base+3] = excl + v.x + v.y + v.z;
  if (tid == 255) bsum[blk] = sd[255];
}

__global__ void scan2(int* __restrict__ bsum){
  __shared__ int sd[512];
  int tid = threadIdx.x;
  int v = (tid < SCAN_NB) ? bsum[tid] : 0;
  sd[tid] = v;
  __syncthreads();
  for (int off = 1; off < 512; off <<= 1){
    int t = (tid >= off) ? sd[tid-off] : 0;
    __syncthreads();
    sd[tid] += t;
    __syncthreads();
  }
  if (tid < SCAN_NB) bsum[tid] = sd[tid] - v;
}

__global__ void scan3(int* __restrict__ rp, int* __restrict__ woff,
                      const int* __restrict__ bsum){
  int idx = blockIdx.x*blockDim.x + threadIdx.x;
  if (idx >= SCAN_N) return;
  int v = rp[idx] + bsum[idx >> 10];
  rp[idx] = v;
  woff[idx] = v;
}

__global__ void place_k(EdgeTab et, RelTab rt, int* __restrict__ woff,
                        int* __restrict__ csr){
  for (int idx = blockIdx.x*blockDim.x + threadIdx.x; idx < E_TOTAL;
       idx += gridDim.x*blockDim.x){
    int k = 0;
    while (idx >= rt.estart[k+1]) ++k;
    int e = idx - rt.estart[k];
    int s = et.sp[k][e];
    int d = et.dp[k][e];
    int pos = atomicAdd(&woff[rt.rowbase[k] + d], 1);
    csr[pos] = s;
  }
}

// ---------------------------------------------------------------- encoder L1 (tiny K)
__global__ void enc_l1(const float* __restrict__ X, const float* __restrict__ W1,
                       const float* __restrict__ b1, float* __restrict__ Z,
                       int M, int K){
  int idx = blockIdx.x*blockDim.x + threadIdx.x;
  if (idx >= M*128) return;
  int r = idx >> 7, c = idx & 127;
  float s = b1[c];
  for (int k = 0; k < K; ++k) s = fmaf(X[r*K + k], W1[(k<<7) + c], s);
  Z[idx] = fmaxf(s, 0.f);
}

// ---------------------------------------------------------------- generic N=128 GEMM
// Y[M,128] = op( (X (*rowscale)) @ W[K,128] * scale + bias ), optional +=, relu.
// rowscale = 1/max(deg,1) from CSR row_ptr when rp != null (SAGE segment-mean).
__global__ __launch_bounds__(256) void linear128(
    const float* __restrict__ X, const float* __restrict__ W,
    const float* __restrict__ bias, const int* __restrict__ rp,
    float* __restrict__ Y, int M, int K, float scale, int flags)
{
  __shared__ float Ws[64][128];
  __shared__ float XsT[64][36];
  const int tid  = threadIdx.x;
  const int m0   = blockIdx.x * 32;
  const int col4 = (tid & 31) * 4;
  const int row4 = (tid >> 5) * 4;
  float acc[4][4] = {};
  for (int k0 = 0; k0 < K; k0 += 64){
    const int kc = min(64, K - k0);
    for (int i = tid*4; i < kc*128; i += 1024){
      *(float4*)&Ws[i>>7][i&127] = *(const float4*)(W + (size_t)(k0 + (i>>7))*128 + (i&127));
    }
    const int nf4 = kc >> 2;
    for (int i = tid; i < 32*nf4; i += 256){
      int r = i / nf4, fq = i - r*nf4;
      int gr = m0 + r;
      float4 x = {0.f,0.f,0.f,0.f};
      if (gr < M){
        x = *(const float4*)(X + (size_t)gr*K + k0 + fq*4);
        if (rp){
          int deg = rp[gr+1] - rp[gr];
          float rs = 1.0f / (float)(deg > 1 ? deg : 1);
          x.x *= rs; x.y *= rs; x.z *= rs; x.w *= rs;
        }
      }
      XsT[fq*4+0][r] = x.x; XsT[fq*4+1][r] = x.y;
      XsT[fq*4+2][r] = x.z; XsT[fq*4+3][r] = x.w;
    }
    __syncthreads();
    #pragma unroll 8
    for (int k = 0; k < kc; ++k){
      float4 wv = *(float4*)&Ws[k][col4];
      float4 xv = *(float4*)&XsT[k][row4];
      acc[0][0] = fmaf(xv.x, wv.x, acc[0][0]); acc[0][1] = fmaf(xv.x, wv.y, acc[0][1]);
      acc[0][2] = fmaf(xv.x, wv.z, acc[0][2]); acc[0][3] = fmaf(xv.x, wv.w, acc[0][3]);
      acc[1][0] = fmaf(xv.y, wv.x, acc[1][0]); acc[1][1] = fmaf(xv.y, wv.y, acc[1][1]);
      acc[1][2] = fmaf(xv.y, wv.z, acc[1][2]); acc[1][3] = fmaf(xv.y, wv.w, acc[1][3]);
      acc[2][0] = fmaf(xv.z, wv.x, acc[2][0]); acc[2][1] = fmaf(xv.z, wv.y, acc[2][1]);
      acc[2][2] = fmaf(xv.z, wv.z, acc[2][2]); acc[2][3] = fmaf(xv.z, wv.w, acc[2][3]);
      acc[3][0] = fmaf(xv.w, wv.x, acc[3][0]); acc[3][1] = fmaf(xv.w, wv.y, acc[3][1]);
      acc[3][2] = fmaf(xv.w, wv.z, acc[3][2]); acc[3][3] = fmaf(xv.w, wv.w, acc[3][3]);
    }
    __syncthreads();
  }
  float4 bv = {0.f,0.f,0.f,0.f};
  if (bias) bv = *(const float4*)(bias + col4);
  #pragma unroll
  for (int i = 0; i < 4; ++i){
    int gr = m0 + row4 + i;
    if (gr >= M) break;
    float* yp = Y + (size_t)gr*128 + col4;
    float4 v;
    v.x = acc[i][0]*scale + bv.x; v.y = acc[i][1]*scale + bv.y;
    v.z = acc[i][2]*scale + bv.z; v.w = acc[i][3]*scale + bv.w;
    if (flags & FLAG_ACC){
      float4 o = *(float4*)yp;
      v.x += o.x; v.y += o.y; v.z += o.z; v.w += o.w;
    }
    if (flags & FLAG_RELU){
      v.x = fmaxf(v.x,0.f); v.y = fmaxf(v.y,0.f);
      v.z = fmaxf(v.z,0.f); v.w = fmaxf(v.w,0.f);
    }
    *(float4*)yp = v;
  }
}

// ---------------------------------------------------------------- SAGE gather (CSR)
__global__ void sage_gather(const float* __restrict__ feat, const int* __restrict__ csr,
                            const int* __restrict__ rp, float* __restrict__ agg,
                            int nd, int nchunk){
  int gid = (blockIdx.x*blockDim.x + threadIdx.x) >> 6;
  if (gid >= nd*nchunk) return;
  int lane = threadIdx.x & 63;
  int row = gid / nchunk, c = gid - row*nchunk;
  int f = lane*2;
  int start = rp[row], end = rp[row+1];
  float2 acc = {0.f, 0.f};
  for (int i = start + c; i < end; i += nchunk){
    int s = csr[i];
    float2 v = *(const float2*)(feat + (size_t)s*128 + f);
    acc.x += v.x; acc.y += v.y;
  }
  float* o = agg + (size_t)row*128 + f;
  if (nchunk == 1){ o[0] = acc.x; o[1] = acc.y; }
  else { atomicAdd(o, acc.x); atomicAdd(o+1, acc.y); }
}

__global__ void relu_k(float* __restrict__ x, int n){
  int idx = blockIdx.x*blockDim.x + threadIdx.x;
  if (idx < n) x[idx] = fmaxf(x[idx], 0.f);
}

// ---------------------------------------------------------------- GATv2 online softmax
__global__ void gat_online(const float* __restrict__ xl, const float* __restrict__ xr,
    const float* __restrict__ att, const int* __restrict__ csr, const int* __restrict__ rp,
    float* __restrict__ outp, float* __restrict__ part, int nd, int nchunk, float invS)
{
  int gid = (blockIdx.x*blockDim.x + threadIdx.x) >> 6;
  if (gid >= nd*nchunk) return;
  int lane = threadIdx.x & 63;
  int row = gid / nchunk, c = gid - row*nchunk;
  int f = lane*2, h = lane >> 4;
  float2 xrv = *(const float2*)(xr + (size_t)row*128 + f);
  float2 av  = *(const float2*)(att + f);
  int start = rp[row], end = rp[row+1];
  float m = -INFINITY, l = 0.f;
  float2 acc = {0.f, 0.f};
  for (int i = start + c; i < end; i += nchunk){
    int s = csr[i];
    float2 xv = *(const float2*)(xl + (size_t)s*128 + f);
    float e0 = xv.x + xrv.x, e1 = xv.y + xrv.y;
    e0 = e0 > 0.f ? e0 : 0.2f*e0;
    e1 = e1 > 0.f ? e1 : 0.2f*e1;
    float p = e0*av.x + e1*av.y;
    p += __shfl_xor(p, 1); p += __shfl_xor(p, 2);
    p += __shfl_xor(p, 4); p += __shfl_xor(p, 8);
    float nm = fmaxf(m, p);
    float sc = __expf(m - nm);          // first iter: exp(-inf)=0, safe
    float pe = __expf(p - nm);
    l = l*sc + pe;
    acc.x = acc.x*sc + pe*xv.x;
    acc.y = acc.y*sc + pe*xv.y;
    m = nm;
  }
  if (nchunk == 1){
    float inv = invS / (l + 1e-16f);
    float* o = outp + (size_t)row*128 + f;
    o[0] += acc.x * inv;
    o[1] += acc.y * inv;
  } else {
    float* pr = part + (size_t)gid*136;
    if ((lane & 15) == 0){ pr[h] = m; pr[4+h] = l; }
    pr[8+f]   = acc.x;
    pr[8+f+1] = acc.y;
  }
}

__global__ void gat_merge(const float* __restrict__ part, float* __restrict__ outp,
                          int nd, int nchunk, float invS){
  int gid = (blockIdx.x*blockDim.x + threadIdx.x) >> 6;
  if (gid >= nd) return;
  int lane = threadIdx.x & 63;
  int f = lane*2, h = lane >> 4;
  float M = -INFINITY;
  for (int c = 0; c < nchunk; ++c)
    M = fmaxf(M, part[((size_t)gid*nchunk + c)*136 + h]);
  float L = 0.f;
  float2 acc = {0.f, 0.f};
  for (int c = 0; c < nchunk; ++c){
    const float* pr = part + ((size_t)gid*nchunk + c)*136;
    float mc = pr[h];
    float w = (mc == -INFINITY) ? 0.f : __expf(mc - M);
    L += pr[4+h] * w;
    acc.x += pr[8+f]   * w;
    acc.y += pr[8+f+1] * w;
  }
  float inv = invS / (L + 1e-16f);
  float* o = outp + (size_t)gid*128 + f;
  o[0] += acc.x * inv;
  o[1] += acc.y * inv;
}

// ---------------------------------------------------------------- final output
__global__ void final_out(const float* __restrict__ outA, const float* __restrict__ outC,
  const float* __restrict__ outE, const float* __restrict__ outG,
  const float* __restrict__ gbcomb, const int* __restrict__ flagp, void* __restrict__ dout)
{
  const int fl = *flagp;
  int idx = blockIdx.x*blockDim.x + threadIdx.x;
  const int total = 101090*128;
  if (idx >= total) return;
  int row = idx >> 7, c = idx & 127;
  float v; int t;
  if (row < A_N){ v = outA[idx]; t = 0; }
  else if (row < A_N + C_N){ v = outC[(row - A_N)*128 + c]; t = 1; }
  else if (row < A_N + C_N + V_N){ v = outE[(row - A_N - C_N)*128 + c]; t = 2; }
  else { v = outG[(row - A_N - C_N - V_N)*128 + c]; t = 3; }
  v += gbcomb[t*128 + c];
  if (fl) ((float*)dout)[idx] = v;
  else    ((__hip_bfloat16*)dout)[idx] = __float2bfloat16(v);
}

__global__ void ws_fail(float* __restrict__ out, float mb){
  if (threadIdx.x == 0 && blockIdx.x == 0) out[0] = mb;
}

// ================================================================ host
extern "C" void kernel_launch(void* const* d_in, const int* in_sizes, int n_in,
                              void* d_out, int out_size, void* d_ws, size_t ws_size,
                              hipStream_t stream)
{
  float* wsf = (float*)d_ws;
  int* flagp = (int*)d_ws;
  size_t off = 16;
  auto alloc = [&](size_t n){ size_t o = off; off += (n + 15) & ~(size_t)15; return o; };

  static const int conv_in_idx[29] = {0,1,2,3, 8,9,10,11, 12,13,14,15, 16,17,18,19,
                                      20,21,22,23, 24,25,26, 27,28,29,30,31,32};
  static const int conv_n[29] = {700000,690,307200,120,
                                 896,128,16384,128, 384,128,16384,128,
                                 49152,128,16384,128, 256,128,16384,128,
                                 131072,1024,131072, 131072,1024,131072,1024,1024,1024};
  ConvTab tab;
  const float* cw[29];
  int total = 0;
  for (int i = 0; i < 29; ++i){
    tab.src[i] = d_in[conv_in_idx[i]];
    size_t o = alloc((size_t)conv_n[i]);
    tab.dstoff[i] = (int)o;
    cw[i] = wsf + o;
    tab.cum[i] = total; total += conv_n[i];
  }
  tab.cum[29] = total;

  const float* xf[4]  = {cw[0], cw[1], cw[2], cw[3]};
  const float* eW1[4] = {cw[4], cw[8],  cw[12], cw[16]};
  const float* eb1[4] = {cw[5], cw[9],  cw[13], cw[17]};
  const float* eW2[4] = {cw[6], cw[10], cw[14], cw[18]};
  const float* eb2[4] = {cw[7], cw[11], cw[15], cw[19]};
  const float* sWl = cw[20]; const float* sbl = cw[21]; const float* sWr = cw[22];
  const float* gWl = cw[23]; const float* gbl = cw[24]; const float* gWr = cw[25];
  const float* gbr = cw[26]; const float* gatt = cw[27]; const float* gbias = cw[28];

  float* wrcomb = wsf + alloc(4*16384);
  float* sbcomb = wsf + alloc(512);
  float* gbcomb = wsf + alloc(512);
  float* hC = wsf + alloc((size_t)C_N*128);
  float* hE = wsf + alloc((size_t)V_N*128);
  float* hG = wsf + alloc((size_t)G_N*128);
  float* yC = wsf + alloc((size_t)C_N*128);
  float* yE = wsf + alloc((size_t)V_N*128);
  float* yG = wsf + alloc((size_t)G_N*128);
  float* outC = wsf + alloc((size_t)C_N*128);
  float* outE = wsf + alloc((size_t)V_N*128);
  float* outG = wsf + alloc((size_t)G_N*128);
  float* fragL = wsf + alloc((size_t)V_N*128);
  float* fragR = wsf + alloc((size_t)V_N*128);
  float* aggS  = wsf + alloc((size_t)V_N*128);
  int* cntb   = (int*)(wsf + alloc(SCAN_N));
  int* rpb    = (int*)(wsf + alloc(SCAN_N));
  int* woffb  = (int*)(wsf + alloc(SCAN_N));
  int* bsumb  = (int*)(wsf + alloc(1024));
  int* csrb   = (int*)(wsf + alloc(E_TOTAL));
  float* part = wsf + alloc((size_t)6400*136);
  float* bufA = wsf + alloc((size_t)A_N*128);  // hA, then GAT athlete out-accumulator
  float* bufZ = wsf + alloc((size_t)A_N*128);  // enc scratch / SAGE agg / GAT big frag
  float* bufY = wsf + alloc((size_t)A_N*128);  // yA

  if (off*4 > ws_size){
    ws_fail<<<1, 64, 0, stream>>>((float*)d_out, (float)((off*4) >> 20));
    return;
  }

  const int n_nodes[4] = {A_N, C_N, V_N, G_N};
  const int et_src[8] = {0,1,0,2,0,3,2,3};
  const int et_dst[8] = {1,0,2,0,3,0,3,2};
  const int et_ei[8]  = {4,4,5,5,6,6,7,7};
  const int et_rev[8] = {0,1,0,1,0,1,0,1};
  const int et_E[8]   = {100000,100000,500000,500000,300000,300000,2000,2000};
  const int et_nchunk[8] = {8,1,8,1,64,1,8,1};
  const float invS[4] = {1.f/3.f, 1.f, 0.5f, 0.5f};

  float* hbuf[4] = {bufA, hC, hE, hG};
  float* ybuf[4] = {bufY, yC, yE, yG};
  float* obuf[4] = {bufA, outC, outE, outG};

  EdgeTab et; RelTab rt;
  {
    int rb = 0, es = 0;
    for (int k = 0; k < 8; ++k){
      const int* ei = (const int*)d_in[et_ei[k]];
      int E = et_E[k];
      et.sp[k] = ei + (et_rev[k] ? E : 0);
      et.dp[k] = ei + (et_rev[k] ? 0 : E);
      rt.rowbase[k] = rb; rb += n_nodes[et_dst[k]];
      rt.estart[k] = es;  es += E;
    }
    rt.estart[8] = es;   // 1804000
  }

  detect_dtype<<<1, 256, 0, stream>>>((const unsigned short*)d_in[2], flagp);
  convert_all<<<2048, 256, 0, stream>>>(tab, wsf, flagp, total);
  prep_combos<<<(4*16384 + 255)/256, 256, 0, stream>>>(sWr, sbl, gbias, wrcomb, sbcomb, gbcomb);

  // ---------------- CSR build (all 8 relations, concatenated)
  hipMemsetAsync(cntb, 0, (size_t)SCAN_N*4, stream);
  hist_k<<<2048, 256, 0, stream>>>(et, rt, cntb);
  scan1<<<SCAN_NB, 256, 0, stream>>>(cntb, rpb, bsumb);
  scan2<<<1, 512, 0, stream>>>(bsumb);
  scan3<<<(SCAN_N + 255)/256, 256, 0, stream>>>(rpb, woffb, bsumb);
  place_k<<<2048, 256, 0, stream>>>(et, rt, woffb, csrb);

  // ---------------- encoders
  enc_l1<<<(A_N*128 + 255)/256, 256, 0, stream>>>(xf[0], eW1[0], eb1[0], bufZ, A_N, 7);
  linear128<<<(A_N + 31)/32, 256, 0, stream>>>(bufZ, eW2[0], eb2[0], nullptr, bufA, A_N, 128, 1.f, 0);
  enc_l1<<<(C_N*128 + 255)/256, 256, 0, stream>>>(xf[1], eW1[1], eb1[1], fragL, C_N, 3);
  linear128<<<(C_N + 31)/32, 256, 0, stream>>>(fragL, eW2[1], eb2[1], nullptr, hC, C_N, 128, 1.f, 0);
  linear128<<<(V_N + 31)/32, 256, 0, stream>>>(xf[2], eW1[2], eb1[2], nullptr, fragL, V_N, 384, 1.f, FLAG_RELU);
  linear128<<<(V_N + 31)/32, 256, 0, stream>>>(fragL, eW2[2], eb2[2], nullptr, hE, V_N, 128, 1.f, 0);
  enc_l1<<<(G_N*128 + 255)/256, 256, 0, stream>>>(xf[3], eW1[3], eb1[3], fragL, G_N, 2);
  linear128<<<(G_N + 31)/32, 256, 0, stream>>>(fragL, eW2[3], eb2[3], nullptr, hG, G_N, 128, 1.f, 0);

  // ---------------- layer 1: hetero SAGE (CSR gather, atomic-free big direction)
  for (int D = 0; D < 4; ++D){
    int nd = n_nodes[D];
    linear128<<<(nd + 31)/32, 256, 0, stream>>>(hbuf[D], wrcomb + D*16384, sbcomb + D*128,
                                                nullptr, ybuf[D], nd, 128, 1.f, 0);
    for (int k = 0; k < 8; ++k){
      if (et_dst[k] != D) continue;
      int nc = et_nchunk[k];
      const int* rp = rpb + rt.rowbase[k];
      float* agg = (D == 0) ? bufZ : aggS;
      if (nc > 1) hipMemsetAsync(agg, 0, (size_t)nd*128*4, stream);
      int waves = nd * nc;
      sage_gather<<<(waves*64 + 255)/256, 256, 0, stream>>>(hbuf[et_src[k]], csrb, rp,
                                                            agg, nd, nc);
      linear128<<<(nd + 31)/32, 256, 0, stream>>>(agg, sWl + k*16384, nullptr, rp,
                                                  ybuf[D], nd, 128, invS[D], FLAG_ACC);
    }
    relu_k<<<(nd*128 + 255)/256, 256, 0, stream>>>(ybuf[D], nd*128);
  }

  // ---------------- layer 2: hetero GATv2 (online softmax over CSR)
  hipMemsetAsync(bufA, 0, (size_t)A_N*128*4, stream);
  hipMemsetAsync(outC, 0, (size_t)C_N*128*4, stream);
  hipMemsetAsync(outE, 0, (size_t)V_N*128*4, stream);
  hipMemsetAsync(outG, 0, (size_t)G_N*128*4, stream);
  for (int k = 0; k < 8; ++k){
    int st = et_src[k], dt = et_dst[k];
    int ns = n_nodes[st], nd = n_nodes[dt];
    int nc = et_nchunk[k];
    const int* rp = rpb + rt.rowbase[k];
    float* xl = (st == 0) ? bufZ : fragL;   // exactly one side is athlete-sized
    float* xr = (dt == 0) ? bufZ : fragR;
    linear128<<<(ns + 31)/32, 256, 0, stream>>>(ybuf[st], gWl + k*16384, gbl + k*128,
                                                nullptr, xl, ns, 128, 1.f, 0);
    linear128<<<(nd + 31)/32, 256, 0, stream>>>(ybuf[dt], gWr + k*16384, gbr + k*128,
                                                nullptr, xr, nd, 128, 1.f, 0);
    int waves = nd * nc;
    gat_online<<<(waves*64 + 255)/256, 256, 0, stream>>>(xl, xr, gatt + k*128, csrb, rp,
                                                         obuf[dt], part, nd, nc, invS[dt]);
    if (nc > 1)
      gat_merge<<<(nd*64 + 255)/256, 256, 0, stream>>>(part, obuf[dt], nd, nc, invS[dt]);
  }

  final_out<<<(101090*128 + 255)/256, 256, 0, stream>>>(bufA, outC, outE, outG,
                                                        gbcomb, flagp, d_out);
}

// Round 3
// 2028.916 us; speedup vs baseline: 4.4730x; 1.4304x over previous
//
#include <hip/hip_runtime.h>
#include <hip/hip_bf16.h>

#define A_N 100000
#define C_N 230
#define V_N 800
#define G_N 60

#define FLAG_ACC  1
#define FLAG_RELU 2

#define NR_TOTAL 301950          // sum of dst-node counts over 8 relations
#define SCAN_N   302080          // 295 * 1024 (padded)
#define SCAN_NB  295
#define E_TOTAL  1804000

#define PCHUNK 16                // edges per thread per place_lds chunk

__device__ __forceinline__ float bf16dec(unsigned short u){
  return __uint_as_float(((unsigned)u) << 16);
}

static inline int imin(int a, int b){ return a < b ? a : b; }

// ---------------------------------------------------------------- detect dtype
__global__ void detect_dtype(const unsigned short* __restrict__ p, int* __restrict__ flag){
  __shared__ int bad;
  if (threadIdx.x == 0) bad = 0;
  __syncthreads();
  for (int i = threadIdx.x; i < 2048; i += blockDim.x){
    float v = fabsf(bf16dec(p[i]));
    if (!(v <= 1e6f)) atomicOr(&bad, 1);
  }
  __syncthreads();
  if (threadIdx.x == 0) *flag = bad;       // 1 => inputs stored as fp32
}

// ---------------------------------------------------------------- convert all
struct ConvTab {
  const void* src[29];
  int dstoff[29];
  int cum[30];
};

__global__ void convert_all(ConvTab tab, float* __restrict__ wsf,
                            const int* __restrict__ flagp, int total){
  const int f = *flagp;
  for (int idx = blockIdx.x*blockDim.x + threadIdx.x; idx < total;
       idx += gridDim.x*blockDim.x){
    int t = 0;
    while (idx >= tab.cum[t+1]) ++t;
    int l = idx - tab.cum[t];
    float v = f ? ((const float*)tab.src[t])[l]
                : bf16dec(((const unsigned short*)tab.src[t])[l]);
    wsf[tab.dstoff[t] + l] = v;
  }
}

// ---------------------------------------------------------------- prep combos
__global__ void prep_combos(const float* __restrict__ sWr, const float* __restrict__ sbl,
                            const float* __restrict__ gbias,
                            float* __restrict__ wrcomb, float* __restrict__ sbcomb,
                            float* __restrict__ gbcomb){
  const int sets[4][3] = {{1,3,5},{0,-1,-1},{2,7,-1},{4,6,-1}};
  const float inv[4] = {1.f/3.f, 1.f, 0.5f, 0.5f};
  int idx = blockIdx.x*blockDim.x + threadIdx.x;
  if (idx >= 4*16384) return;
  int t = idx >> 14, j = idx & 16383;
  float s = 0.f;
  #pragma unroll
  for (int q = 0; q < 3; ++q){
    int k = sets[t][q];
    if (k >= 0) s += sWr[k*16384 + j];
  }
  wrcomb[idx] = s * inv[t];
  if (j < 128){
    float b1 = 0.f, b2 = 0.f;
    #pragma unroll
    for (int q = 0; q < 3; ++q){
      int k = sets[t][q];
      if (k >= 0){ b1 += sbl[k*128 + j]; b2 += gbias[k*128 + j]; }
    }
    sbcomb[t*128 + j] = b1 * inv[t];
    gbcomb[t*128 + j] = b2 * inv[t];
  }
}

// ---------------------------------------------------------------- CSR build
// hist, big-dst (athlete: deg ~1-5, no hot lines) -> plain atomics
__global__ void hist_plain(const int* __restrict__ dp, int E, int* __restrict__ cnt){
  int i = blockIdx.x*blockDim.x + threadIdx.x;
  if (i < E) atomicAdd(&cnt[dp[i]], 1);
}

// hist, small-dst (ndst<=800): LDS-privatized histogram, one flush per block
__global__ void hist_lds(const int* __restrict__ dp, int E, int* __restrict__ cnt, int ndst){
  __shared__ int l[800];
  for (int i = threadIdx.x; i < ndst; i += blockDim.x) l[i] = 0;
  __syncthreads();
  for (int i = blockIdx.x*blockDim.x + threadIdx.x; i < E; i += gridDim.x*blockDim.x)
    atomicAdd(&l[dp[i]], 1);
  __syncthreads();
  for (int i = threadIdx.x; i < ndst; i += blockDim.x)
    if (l[i]) atomicAdd(&cnt[i], l[i]);
}

__global__ void scan1(const int* __restrict__ cnt, int* __restrict__ rp, int* __restrict__ bsum){
  __shared__ int sd[256];
  int tid = threadIdx.x, blk = blockIdx.x;
  int base = blk*1024 + tid*4;
  int4 v = *(const int4*)(cnt + base);
  int s = v.x + v.y + v.z + v.w;
  sd[tid] = s;
  __syncthreads();
  for (int off = 1; off < 256; off <<= 1){
    int t = (tid >= off) ? sd[tid-off] : 0;
    __syncthreads();
    sd[tid] += t;
    __syncthreads();
  }
  int excl = sd[tid] - s;
  rp[base+0] = excl;
  rp[base+1] = excl + v.x;
  rp[base+2] = excl + v.x + v.y;
  rp[base+3] = excl + v.x + v.y + v.z;
  if (tid == 255) bsum[blk] = sd[255];
}

__global__ void scan2(int* __restrict__ bsum){
  __shared__ int sd[512];
  int tid = threadIdx.x;
  int v = (tid < SCAN_NB) ? bsum[tid] : 0;
  sd[tid] = v;
  __syncthreads();
  for (int off = 1; off < 512; off <<= 1){
    int t = (tid >= off) ? sd[tid-off] : 0;
    __syncthreads();
    sd[tid] += t;
    __syncthreads();
  }
  if (tid < SCAN_NB) bsum[tid] = sd[tid] - v;
}

__global__ void scan3(int* __restrict__ rp, int* __restrict__ woff,
                      const int* __restrict__ bsum){
  int idx = blockIdx.x*blockDim.x + threadIdx.x;
  if (idx >= SCAN_N) return;
  int v = rp[idx] + bsum[idx >> 10];
  rp[idx] = v;
  woff[idx] = v;
}

// place, big-dst: plain (woff contention negligible at deg ~1-5)
__global__ void place_plain(const int* __restrict__ sp, const int* __restrict__ dp,
                            int E, int* __restrict__ woff, int* __restrict__ csr){
  int i = blockIdx.x*blockDim.x + threadIdx.x;
  if (i < E){
    int pos = atomicAdd(&woff[dp[i]], 1);
    csr[pos] = sp[i];
  }
}

// place, small-dst: two-phase per 4096-edge block-chunk.
// Phase 1: LDS rank per dst. Phase 2: one global atomicAdd per (chunk,dst).
// Phase 3: clustered csr writes at base+rank. Cuts hot-line atomics ~30x.
__global__ void place_lds(const int* __restrict__ sp, const int* __restrict__ dp,
                          int E, int* __restrict__ woff, int* __restrict__ csr, int ndst){
  __shared__ int lcnt[800];
  __shared__ int lbase[800];
  const int tid = threadIdx.x;
  const int span = blockDim.x * PCHUNK;
  for (int b0 = blockIdx.x*span; b0 < E; b0 += gridDim.x*span){
    for (int i = tid; i < ndst; i += blockDim.x) lcnt[i] = 0;
    __syncthreads();
    int d[PCHUNK], s[PCHUNK], r[PCHUNK];
    #pragma unroll
    for (int j = 0; j < PCHUNK; ++j){
      int e = b0 + j*blockDim.x + tid;
      d[j] = -1;
      if (e < E){
        s[j] = sp[e];
        d[j] = dp[e];
        r[j] = atomicAdd(&lcnt[d[j]], 1);
      }
    }
    __syncthreads();
    for (int i = tid; i < ndst; i += blockDim.x){
      int c = lcnt[i];
      if (c) lbase[i] = atomicAdd(&woff[i], c);
    }
    __syncthreads();
    #pragma unroll
    for (int j = 0; j < PCHUNK; ++j)
      if (d[j] >= 0) csr[lbase[d[j]] + r[j]] = s[j];
    __syncthreads();
  }
}

// ---------------------------------------------------------------- encoder L1 (tiny K)
__global__ void enc_l1(const float* __restrict__ X, const float* __restrict__ W1,
                       const float* __restrict__ b1, float* __restrict__ Z,
                       int M, int K){
  int idx = blockIdx.x*blockDim.x + threadIdx.x;
  if (idx >= M*128) return;
  int r = idx >> 7, c = idx & 127;
  float s = b1[c];
  for (int k = 0; k < K; ++k) s = fmaf(X[r*K + k], W1[(k<<7) + c], s);
  Z[idx] = fmaxf(s, 0.f);
}

// ---------------------------------------------------------------- generic N=128 GEMM
__global__ __launch_bounds__(256) void linear128(
    const float* __restrict__ X, const float* __restrict__ W,
    const float* __restrict__ bias, const int* __restrict__ rp,
    float* __restrict__ Y, int M, int K, float scale, int flags)
{
  __shared__ float Ws[64][128];
  __shared__ float XsT[64][36];
  const int tid  = threadIdx.x;
  const int m0   = blockIdx.x * 32;
  const int col4 = (tid & 31) * 4;
  const int row4 = (tid >> 5) * 4;
  float acc[4][4] = {};
  for (int k0 = 0; k0 < K; k0 += 64){
    const int kc = min(64, K - k0);
    for (int i = tid*4; i < kc*128; i += 1024){
      *(float4*)&Ws[i>>7][i&127] = *(const float4*)(W + (size_t)(k0 + (i>>7))*128 + (i&127));
    }
    const int nf4 = kc >> 2;
    for (int i = tid; i < 32*nf4; i += 256){
      int r = i / nf4, fq = i - r*nf4;
      int gr = m0 + r;
      float4 x = {0.f,0.f,0.f,0.f};
      if (gr < M){
        x = *(const float4*)(X + (size_t)gr*K + k0 + fq*4);
        if (rp){
          int deg = rp[gr+1] - rp[gr];
          float rs = 1.0f / (float)(deg > 1 ? deg : 1);
          x.x *= rs; x.y *= rs; x.z *= rs; x.w *= rs;
        }
      }
      XsT[fq*4+0][r] = x.x; XsT[fq*4+1][r] = x.y;
      XsT[fq*4+2][r] = x.z; XsT[fq*4+3][r] = x.w;
    }
    __syncthreads();
    #pragma unroll 8
    for (int k = 0; k < kc; ++k){
      float4 wv = *(float4*)&Ws[k][col4];
      float4 xv = *(float4*)&XsT[k][row4];
      acc[0][0] = fmaf(xv.x, wv.x, acc[0][0]); acc[0][1] = fmaf(xv.x, wv.y, acc[0][1]);
      acc[0][2] = fmaf(xv.x, wv.z, acc[0][2]); acc[0][3] = fmaf(xv.x, wv.w, acc[0][3]);
      acc[1][0] = fmaf(xv.y, wv.x, acc[1][0]); acc[1][1] = fmaf(xv.y, wv.y, acc[1][1]);
      acc[1][2] = fmaf(xv.y, wv.z, acc[1][2]); acc[1][3] = fmaf(xv.y, wv.w, acc[1][3]);
      acc[2][0] = fmaf(xv.z, wv.x, acc[2][0]); acc[2][1] = fmaf(xv.z, wv.y, acc[2][1]);
      acc[2][2] = fmaf(xv.z, wv.z, acc[2][2]); acc[2][3] = fmaf(xv.z, wv.w, acc[2][3]);
      acc[3][0] = fmaf(xv.w, wv.x, acc[3][0]); acc[3][1] = fmaf(xv.w, wv.y, acc[3][1]);
      acc[3][2] = fmaf(xv.w, wv.z, acc[3][2]); acc[3][3] = fmaf(xv.w, wv.w, acc[3][3]);
    }
    __syncthreads();
  }
  float4 bv = {0.f,0.f,0.f,0.f};
  if (bias) bv = *(const float4*)(bias + col4);
  #pragma unroll
  for (int i = 0; i < 4; ++i){
    int gr = m0 + row4 + i;
    if (gr >= M) break;
    float* yp = Y + (size_t)gr*128 + col4;
    float4 v;
    v.x = acc[i][0]*scale + bv.x; v.y = acc[i][1]*scale + bv.y;
    v.z = acc[i][2]*scale + bv.z; v.w = acc[i][3]*scale + bv.w;
    if (flags & FLAG_ACC){
      float4 o = *(float4*)yp;
      v.x += o.x; v.y += o.y; v.z += o.z; v.w += o.w;
    }
    if (flags & FLAG_RELU){
      v.x = fmaxf(v.x,0.f); v.y = fmaxf(v.y,0.f);
      v.z = fmaxf(v.z,0.f); v.w = fmaxf(v.w,0.f);
    }
    *(float4*)yp = v;
  }
}

// ---------------------------------------------------------------- SAGE gather (CSR)
__global__ void sage_gather(const float* __restrict__ feat, const int* __restrict__ csr,
                            const int* __restrict__ rp, float* __restrict__ agg,
                            int nd, int nchunk){
  int gid = (blockIdx.x*blockDim.x + threadIdx.x) >> 6;
  if (gid >= nd*nchunk) return;
  int lane = threadIdx.x & 63;
  int row = gid / nchunk, c = gid - row*nchunk;
  int f = lane*2;
  int start = rp[row], end = rp[row+1];
  float2 acc = {0.f, 0.f};
  for (int i = start + c; i < end; i += nchunk){
    int s = csr[i];
    float2 v = *(const float2*)(feat + (size_t)s*128 + f);
    acc.x += v.x; acc.y += v.y;
  }
  float* o = agg + (size_t)row*128 + f;
  if (nchunk == 1){ o[0] = acc.x; o[1] = acc.y; }
  else { atomicAdd(o, acc.x); atomicAdd(o+1, acc.y); }
}

__global__ void relu_k(float* __restrict__ x, int n){
  int idx = blockIdx.x*blockDim.x + threadIdx.x;
  if (idx < n) x[idx] = fmaxf(x[idx], 0.f);
}

// ---------------------------------------------------------------- GATv2 online softmax
__global__ void gat_online(const float* __restrict__ xl, const float* __restrict__ xr,
    const float* __restrict__ att, const int* __restrict__ csr, const int* __restrict__ rp,
    float* __restrict__ outp, float* __restrict__ part, int nd, int nchunk, float invS)
{
  int gid = (blockIdx.x*blockDim.x + threadIdx.x) >> 6;
  if (gid >= nd*nchunk) return;
  int lane = threadIdx.x & 63;
  int row = gid / nchunk, c = gid - row*nchunk;
  int f = lane*2, h = lane >> 4;
  float2 xrv = *(const float2*)(xr + (size_t)row*128 + f);
  float2 av  = *(const float2*)(att + f);
  int start = rp[row], end = rp[row+1];
  float m = -INFINITY, l = 0.f;
  float2 acc = {0.f, 0.f};
  for (int i = start + c; i < end; i += nchunk){
    int s = csr[i];
    float2 xv = *(const float2*)(xl + (size_t)s*128 + f);
    float e0 = xv.x + xrv.x, e1 = xv.y + xrv.y;
    e0 = e0 > 0.f ? e0 : 0.2f*e0;
    e1 = e1 > 0.f ? e1 : 0.2f*e1;
    float p = e0*av.x + e1*av.y;
    p += __shfl_xor(p, 1); p += __shfl_xor(p, 2);
    p += __shfl_xor(p, 4); p += __shfl_xor(p, 8);
    float nm = fmaxf(m, p);
    float sc = __expf(m - nm);          // first iter: exp(-inf)=0, safe
    float pe = __expf(p - nm);
    l = l*sc + pe;
    acc.x = acc.x*sc + pe*xv.x;
    acc.y = acc.y*sc + pe*xv.y;
    m = nm;
  }
  if (nchunk == 1){
    float inv = invS / (l + 1e-16f);
    float* o = outp + (size_t)row*128 + f;
    o[0] += acc.x * inv;
    o[1] += acc.y * inv;
  } else {
    float* pr = part + (size_t)gid*136;
    if ((lane & 15) == 0){ pr[h] = m; pr[4+h] = l; }
    pr[8+f]   = acc.x;
    pr[8+f+1] = acc.y;
  }
}

__global__ void gat_merge(const float* __restrict__ part, float* __restrict__ outp,
                          int nd, int nchunk, float invS){
  int gid = (blockIdx.x*blockDim.x + threadIdx.x) >> 6;
  if (gid >= nd) return;
  int lane = threadIdx.x & 63;
  int f = lane*2, h = lane >> 4;
  float M = -INFINITY;
  for (int c = 0; c < nchunk; ++c)
    M = fmaxf(M, part[((size_t)gid*nchunk + c)*136 + h]);
  float L = 0.f;
  float2 acc = {0.f, 0.f};
  for (int c = 0; c < nchunk; ++c){
    const float* pr = part + ((size_t)gid*nchunk + c)*136;
    float mc = pr[h];
    float w = (mc == -INFINITY) ? 0.f : __expf(mc - M);
    L += pr[4+h] * w;
    acc.x += pr[8+f]   * w;
    acc.y += pr[8+f+1] * w;
  }
  float inv = invS / (L + 1e-16f);
  float* o = outp + (size_t)gid*128 + f;
  o[0] += acc.x * inv;
  o[1] += acc.y * inv;
}

// ---------------------------------------------------------------- final output
__global__ void final_out(const float* __restrict__ outA, const float* __restrict__ outC,
  const float* __restrict__ outE, const float* __restrict__ outG,
  const float* __restrict__ gbcomb, const int* __restrict__ flagp, void* __restrict__ dout)
{
  const int fl = *flagp;
  int idx = blockIdx.x*blockDim.x + threadIdx.x;
  const int total = 101090*128;
  if (idx >= total) return;
  int row = idx >> 7, c = idx & 127;
  float v; int t;
  if (row < A_N){ v = outA[idx]; t = 0; }
  else if (row < A_N + C_N){ v = outC[(row - A_N)*128 + c]; t = 1; }
  else if (row < A_N + C_N + V_N){ v = outE[(row - A_N - C_N)*128 + c]; t = 2; }
  else { v = outG[(row - A_N - C_N - V_N)*128 + c]; t = 3; }
  v += gbcomb[t*128 + c];
  if (fl) ((float*)dout)[idx] = v;
  else    ((__hip_bfloat16*)dout)[idx] = __float2bfloat16(v);
}

__global__ void ws_fail(float* __restrict__ out, float mb){
  if (threadIdx.x == 0 && blockIdx.x == 0) out[0] = mb;
}

// ================================================================ host
extern "C" void kernel_launch(void* const* d_in, const int* in_sizes, int n_in,
                              void* d_out, int out_size, void* d_ws, size_t ws_size,
                              hipStream_t stream)
{
  float* wsf = (float*)d_ws;
  int* flagp = (int*)d_ws;
  size_t off = 16;
  auto alloc = [&](size_t n){ size_t o = off; off += (n + 15) & ~(size_t)15; return o; };

  static const int conv_in_idx[29] = {0,1,2,3, 8,9,10,11, 12,13,14,15, 16,17,18,19,
                                      20,21,22,23, 24,25,26, 27,28,29,30,31,32};
  static const int conv_n[29] = {700000,690,307200,120,
                                 896,128,16384,128, 384,128,16384,128,
                                 49152,128,16384,128, 256,128,16384,128,
                                 131072,1024,131072, 131072,1024,131072,1024,1024,1024};
  ConvTab tab;
  const float* cw[29];
  int total = 0;
  for (int i = 0; i < 29; ++i){
    tab.src[i] = d_in[conv_in_idx[i]];
    size_t o = alloc((size_t)conv_n[i]);
    tab.dstoff[i] = (int)o;
    cw[i] = wsf + o;
    tab.cum[i] = total; total += conv_n[i];
  }
  tab.cum[29] = total;

  const float* xf[4]  = {cw[0], cw[1], cw[2], cw[3]};
  const float* eW1[4] = {cw[4], cw[8],  cw[12], cw[16]};
  const float* eb1[4] = {cw[5], cw[9],  cw[13], cw[17]};
  const float* eW2[4] = {cw[6], cw[10], cw[14], cw[18]};
  const float* eb2[4] = {cw[7], cw[11], cw[15], cw[19]};
  const float* sWl = cw[20]; const float* sbl = cw[21]; const float* sWr = cw[22];
  const float* gWl = cw[23]; const float* gbl = cw[24]; const float* gWr = cw[25];
  const float* gbr = cw[26]; const float* gatt = cw[27]; const float* gbias = cw[28];

  float* wrcomb = wsf + alloc(4*16384);
  float* sbcomb = wsf + alloc(512);
  float* gbcomb = wsf + alloc(512);
  float* hC = wsf + alloc((size_t)C_N*128);
  float* hE = wsf + alloc((size_t)V_N*128);
  float* hG = wsf + alloc((size_t)G_N*128);
  float* yC = wsf + alloc((size_t)C_N*128);
  float* yE = wsf + alloc((size_t)V_N*128);
  float* yG = wsf + alloc((size_t)G_N*128);
  float* outC = wsf + alloc((size_t)C_N*128);
  float* outE = wsf + alloc((size_t)V_N*128);
  float* outG = wsf + alloc((size_t)G_N*128);
  float* fragL = wsf + alloc((size_t)V_N*128);
  float* fragR = wsf + alloc((size_t)V_N*128);
  float* aggS  = wsf + alloc((size_t)V_N*128);
  int* cntb   = (int*)(wsf + alloc(SCAN_N));
  int* rpb    = (int*)(wsf + alloc(SCAN_N));
  int* woffb  = (int*)(wsf + alloc(SCAN_N));
  int* bsumb  = (int*)(wsf + alloc(1024));
  int* csrb   = (int*)(wsf + alloc(E_TOTAL));
  float* part = wsf + alloc((size_t)6400*136);
  float* bufA = wsf + alloc((size_t)A_N*128);  // hA, then GAT athlete out-accumulator
  float* bufZ = wsf + alloc((size_t)A_N*128);  // enc scratch / SAGE agg / GAT big frag
  float* bufY = wsf + alloc((size_t)A_N*128);  // yA

  if (off*4 > ws_size){
    ws_fail<<<1, 64, 0, stream>>>((float*)d_out, (float)((off*4) >> 20));
    return;
  }

  const int n_nodes[4] = {A_N, C_N, V_N, G_N};
  const int et_src[8] = {0,1,0,2,0,3,2,3};
  const int et_dst[8] = {1,0,2,0,3,0,3,2};
  const int et_ei[8]  = {4,4,5,5,6,6,7,7};
  const int et_rev[8] = {0,1,0,1,0,1,0,1};
  const int et_E[8]   = {100000,100000,500000,500000,300000,300000,2000,2000};
  const int et_nchunk[8] = {8,1,8,1,64,1,8,1};
  const float invS[4] = {1.f/3.f, 1.f, 0.5f, 0.5f};

  float* hbuf[4] = {bufA, hC, hE, hG};
  float* ybuf[4] = {bufY, yC, yE, yG};
  float* obuf[4] = {bufA, outC, outE, outG};

  const int* esp[8]; const int* edp[8]; int rowbase[8];
  {
    int rb = 0;
    for (int k = 0; k < 8; ++k){
      const int* ei = (const int*)d_in[et_ei[k]];
      int E = et_E[k];
      esp[k] = ei + (et_rev[k] ? E : 0);
      edp[k] = ei + (et_rev[k] ? 0 : E);
      rowbase[k] = rb; rb += n_nodes[et_dst[k]];
    }
  }

  detect_dtype<<<1, 256, 0, stream>>>((const unsigned short*)d_in[2], flagp);
  convert_all<<<2048, 256, 0, stream>>>(tab, wsf, flagp, total);
  prep_combos<<<(4*16384 + 255)/256, 256, 0, stream>>>(sWr, sbl, gbias, wrcomb, sbcomb, gbcomb);

  // ---------------- CSR build (per relation; LDS-privatized for small dst)
  hipMemsetAsync(cntb, 0, (size_t)SCAN_N*4, stream);
  for (int k = 0; k < 8; ++k){
    int E = et_E[k], nd = n_nodes[et_dst[k]];
    if (nd <= 800)
      hist_lds<<<imin(256, (E + 255)/256), 256, 0, stream>>>(edp[k], E, cntb + rowbase[k], nd);
    else
      hist_plain<<<(E + 255)/256, 256, 0, stream>>>(edp[k], E, cntb + rowbase[k]);
  }
  scan1<<<SCAN_NB, 256, 0, stream>>>(cntb, rpb, bsumb);
  scan2<<<1, 512, 0, stream>>>(bsumb);
  scan3<<<(SCAN_N + 255)/256, 256, 0, stream>>>(rpb, woffb, bsumb);
  for (int k = 0; k < 8; ++k){
    int E = et_E[k], nd = n_nodes[et_dst[k]];
    if (nd <= 800){
      int span = 256*PCHUNK;
      place_lds<<<imin(304, (E + span - 1)/span), 256, 0, stream>>>(
          esp[k], edp[k], E, woffb + rowbase[k], csrb, nd);
    } else {
      place_plain<<<(E + 255)/256, 256, 0, stream>>>(esp[k], edp[k], E,
                                                     woffb + rowbase[k], csrb);
    }
  }

  // ---------------- encoders
  enc_l1<<<(A_N*128 + 255)/256, 256, 0, stream>>>(xf[0], eW1[0], eb1[0], bufZ, A_N, 7);
  linear128<<<(A_N + 31)/32, 256, 0, stream>>>(bufZ, eW2[0], eb2[0], nullptr, bufA, A_N, 128, 1.f, 0);
  enc_l1<<<(C_N*128 + 255)/256, 256, 0, stream>>>(xf[1], eW1[1], eb1[1], fragL, C_N, 3);
  linear128<<<(C_N + 31)/32, 256, 0, stream>>>(fragL, eW2[1], eb2[1], nullptr, hC, C_N, 128, 1.f, 0);
  linear128<<<(V_N + 31)/32, 256, 0, stream>>>(xf[2], eW1[2], eb1[2], nullptr, fragL, V_N, 384, 1.f, FLAG_RELU);
  linear128<<<(V_N + 31)/32, 256, 0, stream>>>(fragL, eW2[2], eb2[2], nullptr, hE, V_N, 128, 1.f, 0);
  enc_l1<<<(G_N*128 + 255)/256, 256, 0, stream>>>(xf[3], eW1[3], eb1[3], fragL, G_N, 2);
  linear128<<<(G_N + 31)/32, 256, 0, stream>>>(fragL, eW2[3], eb2[3], nullptr, hG, G_N, 128, 1.f, 0);

  // ---------------- layer 1: hetero SAGE (CSR gather, atomic-free big direction)
  for (int D = 0; D < 4; ++D){
    int nd = n_nodes[D];
    linear128<<<(nd + 31)/32, 256, 0, stream>>>(hbuf[D], wrcomb + D*16384, sbcomb + D*128,
                                                nullptr, ybuf[D], nd, 128, 1.f, 0);
    for (int k = 0; k < 8; ++k){
      if (et_dst[k] != D) continue;
      int nc = et_nchunk[k];
      const int* rp = rpb + rowbase[k];
      float* agg = (D == 0) ? bufZ : aggS;
      if (nc > 1) hipMemsetAsync(agg, 0, (size_t)nd*128*4, stream);
      int waves = nd * nc;
      sage_gather<<<(waves*64 + 255)/256, 256, 0, stream>>>(hbuf[et_src[k]], csrb, rp,
                                                            agg, nd, nc);
      linear128<<<(nd + 31)/32, 256, 0, stream>>>(agg, sWl + k*16384, nullptr, rp,
                                                  ybuf[D], nd, 128, invS[D], FLAG_ACC);
    }
    relu_k<<<(nd*128 + 255)/256, 256, 0, stream>>>(ybuf[D], nd*128);
  }

  // ---------------- layer 2: hetero GATv2 (online softmax over CSR)
  hipMemsetAsync(bufA, 0, (size_t)A_N*128*4, stream);
  hipMemsetAsync(outC, 0, (size_t)C_N*128*4, stream);
  hipMemsetAsync(outE, 0, (size_t)V_N*128*4, stream);
  hipMemsetAsync(outG, 0, (size_t)G_N*128*4, stream);
  for (int k = 0; k < 8; ++k){
    int st = et_src[k], dt = et_dst[k];
    int ns = n_nodes[st], nd = n_nodes[dt];
    int nc = et_nchunk[k];
    const int* rp = rpb + rowbase[k];
    float* xl = (st == 0) ? bufZ : fragL;   // exactly one side is athlete-sized
    float* xr = (dt == 0) ? bufZ : fragR;
    linear128<<<(ns + 31)/32, 256, 0, stream>>>(ybuf[st], gWl + k*16384, gbl + k*128,
                                                nullptr, xl, ns, 128, 1.f, 0);
    linear128<<<(nd + 31)/32, 256, 0, stream>>>(ybuf[dt], gWr + k*16384, gbr + k*128,
                                                nullptr, xr, nd, 128, 1.f, 0);
    int waves = nd * nc;
    gat_online<<<(waves*64 + 255)/256, 256, 0, stream>>>(xl, xr, gatt + k*128, csrb, rp,
                                                         obuf[dt], part, nd, nc, invS[dt]);
    if (nc > 1)
      gat_merge<<<(nd*64 + 255)/256, 256, 0, stream>>>(part, obuf[dt], nd, nc, invS[dt]);
  }

  final_out<<<(101090*128 + 255)/256, 256, 0, stream>>>(bufA, outC, outE, outG,
                                                        gbcomb, flagp, d_out);
}

// Round 4
// 1210.257 us; speedup vs baseline: 7.4987x; 1.6764x over previous
//
#include <hip/hip_runtime.h>
#include <hip/hip_bf16.h>

#define A_N 100000
#define C_N 230
#define V_N 800
#define G_N 60

#define FLAG_RELU 2

#define SCAN_N   302080          // 295 * 1024 (padded row-count over 8 relations)
#define SCAN_NB  295
#define E_TOTAL  1804000

#define PCHUNK 16

typedef __attribute__((ext_vector_type(8))) short short8;
typedef __attribute__((ext_vector_type(4))) float f32x4;

__device__ __forceinline__ float bf16dec(unsigned short u){
  return __uint_as_float(((unsigned)u) << 16);
}
__device__ __forceinline__ unsigned short f2b(float v){
  union { __hip_bfloat16 h; unsigned short u; } c;
  c.h = __float2bfloat16(v);
  return c.u;
}
__device__ __forceinline__ float2 ldb2(const unsigned short* p){
  unsigned v = *(const unsigned*)p;
  float2 r;
  r.x = __uint_as_float(v << 16);
  r.y = __uint_as_float(v & 0xffff0000u);
  return r;
}
static inline int imin(int a, int b){ return a < b ? a : b; }

// ---------------------------------------------------------------- detect dtype
__global__ void detect_dtype(const unsigned short* __restrict__ p, int* __restrict__ flag){
  __shared__ int bad;
  if (threadIdx.x == 0) bad = 0;
  __syncthreads();
  for (int i = threadIdx.x; i < 2048; i += blockDim.x){
    float v = fabsf(bf16dec(p[i]));
    if (!(v <= 1e6f)) atomicOr(&bad, 1);
  }
  __syncthreads();
  if (threadIdx.x == 0) *flag = bad;       // 1 => inputs stored as fp32
}

// ---------------------------------------------------------------- convert all
struct ConvTab { const void* src[29]; int dstoff[29]; int cum[30]; };

__global__ void convert_all(ConvTab tab, float* __restrict__ wsf,
                            const int* __restrict__ flagp, int total){
  const int f = *flagp;
  for (int idx = blockIdx.x*blockDim.x + threadIdx.x; idx < total;
       idx += gridDim.x*blockDim.x){
    int t = 0;
    while (idx >= tab.cum[t+1]) ++t;
    int l = idx - tab.cum[t];
    float v = f ? ((const float*)tab.src[t])[l]
                : bf16dec(((const unsigned short*)tab.src[t])[l]);
    wsf[tab.dstoff[t] + l] = v;
  }
}

// ---------------------------------------------------------------- prep combos
__global__ void prep_combos(const float* __restrict__ sWr, const float* __restrict__ sbl,
                            const float* __restrict__ gbias,
                            float* __restrict__ wrcomb, float* __restrict__ sbcomb,
                            float* __restrict__ gbcomb){
  const int sets[4][3] = {{1,3,5},{0,-1,-1},{2,7,-1},{4,6,-1}};
  const float inv[4] = {1.f/3.f, 1.f, 0.5f, 0.5f};
  int idx = blockIdx.x*blockDim.x + threadIdx.x;
  if (idx >= 4*16384) return;
  int t = idx >> 14, j = idx & 16383;
  float s = 0.f;
  #pragma unroll
  for (int q = 0; q < 3; ++q){
    int k = sets[t][q];
    if (k >= 0) s += sWr[k*16384 + j];
  }
  wrcomb[idx] = s * inv[t];
  if (j < 128){
    float b1 = 0.f, b2 = 0.f;
    #pragma unroll
    for (int q = 0; q < 3; ++q){
      int k = sets[t][q];
      if (k >= 0){ b1 += sbl[k*128 + j]; b2 += gbias[k*128 + j]; }
    }
    sbcomb[t*128 + j] = b1 * inv[t];
    gbcomb[t*128 + j] = b2 * inv[t];
  }
}

// gblx = concat(gbl[0],gbl[2],gbl[4]); gbrx = concat(gbr[1],gbr[3],gbr[5])
__global__ void prep_bias2(const float* __restrict__ gbl, const float* __restrict__ gbr,
                           float* __restrict__ gblx, float* __restrict__ gbrx){
  int i = blockIdx.x*blockDim.x + threadIdx.x;
  if (i >= 384) return;
  const int kl[3] = {0,2,4}, kr[3] = {1,3,5};
  int rel = i >> 7, j = i & 127;
  gblx[i] = gbl[kl[rel]*128 + j];
  gbrx[i] = gbr[kr[rel]*128 + j];
}

// ---------------------------------------------------------------- weight swizzle
// dst layout: wsu[dst + ((ntg*nkc + kc0+kc)*64 + lane)*8 + j] = W[k][n]*scale
// with k = kc*32 + (lane>>4)*8 + j, n = nt*16 + (lane&15), ntg = nt0 + nt.
struct SwzD { int src, dst, K, nkc, kc0, nt0; float scale; };
struct SwzTab { SwzD d[33]; int n, total; };

__global__ void swz_batch(const float* __restrict__ wsf, unsigned short* __restrict__ wsu,
                          SwzTab t){
  for (int idx = blockIdx.x*blockDim.x + threadIdx.x; idx < t.total;
       idx += gridDim.x*blockDim.x){
    int di = 0, local = idx;
    while (local >= t.d[di].K*128){ local -= t.d[di].K*128; ++di; }
    SwzD d = t.d[di];
    int j = local & 7, lane = (local>>3) & 63, rest = local >> 9;
    int kcn = d.K >> 5;
    int kc = rest % kcn, nt = rest / kcn;
    int k = kc*32 + (lane>>4)*8 + j;
    int n = nt*16 + (lane&15);
    float v = wsf[d.src + k*128 + n] * d.scale;
    wsu[(size_t)d.dst + ((size_t)((d.nt0+nt)*d.nkc + d.kc0+kc)*64 + lane)*8 + j] = f2b(v);
  }
}

// ---------------------------------------------------------------- CSR build
__global__ void hist_plain(const int* __restrict__ dp, int E, int* __restrict__ cnt){
  int i = blockIdx.x*blockDim.x + threadIdx.x;
  if (i < E) atomicAdd(&cnt[dp[i]], 1);
}

__global__ void hist_lds(const int* __restrict__ dp, int E, int* __restrict__ cnt, int ndst){
  __shared__ int l[800];
  for (int i = threadIdx.x; i < ndst; i += blockDim.x) l[i] = 0;
  __syncthreads();
  for (int i = blockIdx.x*blockDim.x + threadIdx.x; i < E; i += gridDim.x*blockDim.x)
    atomicAdd(&l[dp[i]], 1);
  __syncthreads();
  for (int i = threadIdx.x; i < ndst; i += blockDim.x)
    if (l[i]) atomicAdd(&cnt[i], l[i]);
}

__global__ void scan1(const int* __restrict__ cnt, int* __restrict__ rp, int* __restrict__ bsum){
  __shared__ int sd[256];
  int tid = threadIdx.x, blk = blockIdx.x;
  int base = blk*1024 + tid*4;
  int4 v = *(const int4*)(cnt + base);
  int s = v.x + v.y + v.z + v.w;
  sd[tid] = s;
  __syncthreads();
  for (int off = 1; off < 256; off <<= 1){
    int t = (tid >= off) ? sd[tid-off] : 0;
    __syncthreads();
    sd[tid] += t;
    __syncthreads();
  }
  int excl = sd[tid] - s;
  rp[base+0] = excl;
  rp[base+1] = excl + v.x;
  rp[base+2] = excl + v.x + v.y;
  rp[base+3] = excl + v.x + v.y + v.z;
  if (tid == 255) bsum[blk] = sd[255];
}

__global__ void scan2(int* __restrict__ bsum){
  __shared__ int sd[512];
  int tid = threadIdx.x;
  int v = (tid < SCAN_NB) ? bsum[tid] : 0;
  sd[tid] = v;
  __syncthreads();
  for (int off = 1; off < 512; off <<= 1){
    int t = (tid >= off) ? sd[tid-off] : 0;
    __syncthreads();
    sd[tid] += t;
    __syncthreads();
  }
  if (tid < SCAN_NB) bsum[tid] = sd[tid] - v;
}

__global__ void scan3(int* __restrict__ rp, int* __restrict__ woff,
                      const int* __restrict__ bsum){
  int idx = blockIdx.x*blockDim.x + threadIdx.x;
  if (idx >= SCAN_N) return;
  int v = rp[idx] + bsum[idx >> 10];
  rp[idx] = v;
  woff[idx] = v;
}

__global__ void place_plain(const int* __restrict__ sp, const int* __restrict__ dp,
                            int E, int* __restrict__ woff, int* __restrict__ csr){
  int i = blockIdx.x*blockDim.x + threadIdx.x;
  if (i < E){
    int pos = atomicAdd(&woff[dp[i]], 1);
    csr[pos] = sp[i];
  }
}

__global__ void place_lds(const int* __restrict__ sp, const int* __restrict__ dp,
                          int E, int* __restrict__ woff, int* __restrict__ csr, int ndst){
  __shared__ int lcnt[800];
  __shared__ int lbase[800];
  const int tid = threadIdx.x;
  const int span = blockDim.x * PCHUNK;
  for (int b0 = blockIdx.x*span; b0 < E; b0 += gridDim.x*span){
    for (int i = tid; i < ndst; i += blockDim.x) lcnt[i] = 0;
    __syncthreads();
    int d[PCHUNK], s[PCHUNK], r[PCHUNK];
    #pragma unroll
    for (int j = 0; j < PCHUNK; ++j){
      int e = b0 + j*blockDim.x + tid;
      d[j] = -1;
      if (e < E){
        s[j] = sp[e];
        d[j] = dp[e];
        r[j] = atomicAdd(&lcnt[d[j]], 1);
      }
    }
    __syncthreads();
    for (int i = tid; i < ndst; i += blockDim.x){
      int c = lcnt[i];
      if (c) lbase[i] = atomicAdd(&woff[i], c);
    }
    __syncthreads();
    #pragma unroll
    for (int j = 0; j < PCHUNK; ++j)
      if (d[j] >= 0) csr[lbase[d[j]] + r[j]] = s[j];
    __syncthreads();
  }
}

// ---------------------------------------------------------------- encoder L1 (tiny K)
__global__ void enc_l1(const float* __restrict__ X, const float* __restrict__ W1,
                       const float* __restrict__ b1, unsigned short* __restrict__ Z,
                       int M, int K){
  int idx = blockIdx.x*blockDim.x + threadIdx.x;
  if (idx >= M*128) return;
  int r = idx >> 7, c = idx & 127;
  float s = b1[c];
  for (int k = 0; k < K; ++k) s = fmaf(X[r*K + k], W1[(k<<7) + c], s);
  Z[idx] = f2b(fmaxf(s, 0.f));
}

__global__ void cvt_bf16(const float* __restrict__ src, unsigned short* __restrict__ dst, int n){
  int i = blockIdx.x*blockDim.x + threadIdx.x;
  if (i < n) dst[i] = f2b(src[i]);
}

// ---------------------------------------------------------------- MFMA GEMM
// Y[M, ystride](bf16) = op(X @ Wsw + bias). X split: kc<kcsplit from xoff, else x2off.
// Wave = 16 rows; block = 64 rows x 128 cols (8 n-tiles); grid.y = extra 128-col groups.
// A-frag: lane m=lane&15, k=quad*8+j. B pre-swizzled. C/D: col=lane&15, row=quad*4+reg.
__device__ __forceinline__ void mfma_core(
    const unsigned short* __restrict__ wsu, const float* __restrict__ wsf,
    int xoff, int xstride, int x2off, int x2stride, int kcsplit,
    int woff, int nkc, int biasoff, int yoff, int ystride,
    int M, int flags, int mblk, int nblk)
{
  int tid = threadIdx.x;
  int wv = tid >> 6, lane = tid & 63;
  int quad = lane >> 4, ml = lane & 15;
  int m0 = mblk*64 + wv*16;
  if (m0 >= M) return;
  int arow = m0 + ml;
  bool rowok = arow < M;
  f32x4 acc[8];
  #pragma unroll
  for (int i = 0; i < 8; ++i) acc[i] = (f32x4){0.f, 0.f, 0.f, 0.f};
  for (int kc = 0; kc < nkc; ++kc){
    short8 a = (short8){0,0,0,0,0,0,0,0};
    if (rowok){
      size_t ao = (kc < kcsplit)
        ? (size_t)xoff  + (size_t)arow*xstride  + kc*32 + quad*8
        : (size_t)x2off + (size_t)arow*x2stride + (kc - kcsplit)*32 + quad*8;
      a = *(const short8*)(wsu + ao);
    }
    size_t wbase = (size_t)woff + ((size_t)(nblk*8)*nkc + kc)*512 + lane*8;
    #pragma unroll
    for (int nt = 0; nt < 8; ++nt){
      short8 b = *(const short8*)(wsu + wbase + (size_t)nt*nkc*512);
      acc[nt] = __builtin_amdgcn_mfma_f32_16x16x32_bf16(a, b, acc[nt], 0, 0, 0);
    }
  }
  #pragma unroll
  for (int nt = 0; nt < 8; ++nt){
    int col = nblk*128 + nt*16 + ml;
    float bv = (biasoff >= 0) ? wsf[biasoff + col] : 0.f;
    #pragma unroll
    for (int r = 0; r < 4; ++r){
      int orow = m0 + quad*4 + r;
      if (orow < M){
        float v = acc[nt][r] + bv;
        if (flags & FLAG_RELU) v = fmaxf(v, 0.f);
        *((unsigned short*)wsu + (size_t)yoff + (size_t)orow*ystride + col) = f2b(v);
      }
    }
  }
}

__global__ __launch_bounds__(256) void mfma_gemm(
    void* ws, int xoff, int xstride, int x2off, int x2stride, int kcsplit,
    int woff, int nkc, int biasoff, int yoff, int ystride, int M, int flags)
{
  mfma_core((const unsigned short*)ws, (const float*)ws, xoff, xstride, x2off, x2stride,
            kcsplit, woff, nkc, biasoff, yoff, ystride, M, flags, blockIdx.x, blockIdx.y);
}

struct GB { int xoff, xstride, woff, biasoff, yoff, ystride, M, nkc, flags; };
struct GBTab { GB d[12]; int n; };

__global__ __launch_bounds__(256) void mfma_gemm_batch(void* ws, GBTab t){
  int di = blockIdx.x / 13, mb = blockIdx.x % 13;
  if (di >= t.n) return;
  GB g = t.d[di];
  mfma_core((const unsigned short*)ws, (const float*)ws, g.xoff, g.xstride, 0, 0, 1000,
            g.woff, g.nkc, g.biasoff, g.yoff, g.ystride, g.M, g.flags, mb, 0);
}

// ---------------------------------------------------------------- SAGE gathers
// fused athlete-dst: wave per row, 3 relations (k=1,3,5), mean written bf16 into aggA slices
__global__ void sage_gather_athA(const unsigned short* __restrict__ wsu,
    const int* __restrict__ csr, const int* __restrict__ rpb,
    int uhC, int uhE, int uhG, int rp1, int rp3, int rp5, int uagg)
{
  int gid = (blockIdx.x*blockDim.x + threadIdx.x) >> 6;
  if (gid >= A_N) return;
  int lane = threadIdx.x & 63, f = lane*2;
  int srcs[3] = {uhC, uhE, uhG};
  int sstr[3] = {256, 384, 384};
  int rps[3]  = {rp1, rp3, rp5};
  #pragma unroll
  for (int rel = 0; rel < 3; ++rel){
    int st = rpb[rps[rel] + gid], en = rpb[rps[rel] + gid + 1];
    float2 acc = {0.f, 0.f};
    for (int i = st; i < en; ++i){
      int s = csr[i];
      float2 v = ldb2(wsu + (size_t)srcs[rel] + (size_t)s*sstr[rel] + f);
      acc.x += v.x; acc.y += v.y;
    }
    int deg = en - st;
    float sc = 1.f / (float)(deg > 1 ? deg : 1);
    ushort2 o; o.x = f2b(acc.x*sc); o.y = f2b(acc.y*sc);
    *(ushort2*)((unsigned short*)wsu + (size_t)uagg + (size_t)gid*384 + rel*128 + f) = o;
  }
}

// small-dst gathers, batched; fp32 atomic accumulation into zeroed agg buffers
struct SgD { int src, sstr, rpoff, aggoff, nd, nc; };
struct SgTab { SgD d[5]; int cumw[6]; };

__global__ void sage_gather_small(const unsigned short* __restrict__ wsu,
    float* __restrict__ wsf, const int* __restrict__ csr, const int* __restrict__ rpb,
    SgTab t)
{
  int gid = (blockIdx.x*blockDim.x + threadIdx.x) >> 6;
  if (gid >= t.cumw[5]) return;
  int di = 0;
  while (gid >= t.cumw[di+1]) ++di;
  SgD d = t.d[di];
  int local = gid - t.cumw[di];
  int row = local / d.nc, c = local - row*d.nc;
  int lane = threadIdx.x & 63, f = lane*2;
  int st = rpb[d.rpoff + row], en = rpb[d.rpoff + row + 1];
  float2 acc = {0.f, 0.f};
  for (int i = st + c; i < en; i += d.nc){
    int s = csr[i];
    float2 v = ldb2(wsu + (size_t)d.src + (size_t)s*d.sstr + f);
    acc.x += v.x; acc.y += v.y;
  }
  float* o = wsf + (size_t)d.aggoff + (size_t)row*128 + f;
  atomicAdd(o, acc.x);
  atomicAdd(o+1, acc.y);
}

struct AfD { int aggoff, rpoff, dstu, dstr, nd; };
struct AfTab { AfD d[5]; int n; };

__global__ void aggfin_batch(unsigned short* __restrict__ wsu, const float* __restrict__ wsf,
                             const int* __restrict__ rpb, AfTab t, int total){
  int idx = blockIdx.x*blockDim.x + threadIdx.x;
  if (idx >= total) return;
  int di = 0, local = idx;
  while (local >= t.d[di].nd*128){ local -= t.d[di].nd*128; ++di; }
  AfD d = t.d[di];
  int row = local >> 7, col = local & 127;
  int deg = rpb[d.rpoff + row + 1] - rpb[d.rpoff + row];
  float sc = 1.f / (float)(deg > 1 ? deg : 1);
  wsu[(size_t)d.dstu + (size_t)row*d.dstr + col] = f2b(wsf[(size_t)d.aggoff + local] * sc);
}

// ---------------------------------------------------------------- GATv2 edge kernels
// fused athlete-dst (k=1,3,5): wave per row, online softmax, register accumulation
__global__ void gat_ath(const unsigned short* __restrict__ wsu, const float* __restrict__ wsf,
    const int* __restrict__ csr, const int* __restrict__ rpb,
    int ugxr, int uxl1, int uxl3, int uxl5, int oatt, int rp1, int rp3, int rp5, int uout)
{
  int gid = (blockIdx.x*blockDim.x + threadIdx.x) >> 6;
  if (gid >= A_N) return;
  int lane = threadIdx.x & 63, f = lane*2;
  int xls[3] = {uxl1, uxl3, uxl5};
  int rps[3] = {rp1, rp3, rp5};
  const int attk[3] = {1, 3, 5};
  float2 oacc = {0.f, 0.f};
  #pragma unroll
  for (int rel = 0; rel < 3; ++rel){
    float2 xrv = ldb2(wsu + (size_t)ugxr + (size_t)gid*384 + rel*128 + f);
    float2 av  = *(const float2*)(wsf + oatt + attk[rel]*128 + f);
    int st = rpb[rps[rel] + gid], en = rpb[rps[rel] + gid + 1];
    float m = -INFINITY, l = 0.f;
    float2 acc = {0.f, 0.f};
    for (int i = st; i < en; ++i){
      int s = csr[i];
      float2 xv = ldb2(wsu + (size_t)xls[rel] + (size_t)s*128 + f);
      float e0 = xv.x + xrv.x, e1 = xv.y + xrv.y;
      e0 = e0 > 0.f ? e0 : 0.2f*e0;
      e1 = e1 > 0.f ? e1 : 0.2f*e1;
      float p = e0*av.x + e1*av.y;
      p += __shfl_xor(p, 1); p += __shfl_xor(p, 2);
      p += __shfl_xor(p, 4); p += __shfl_xor(p, 8);
      float nm = fmaxf(m, p);
      float sc = __expf(m - nm);
      float pe = __expf(p - nm);
      l = l*sc + pe;
      acc.x = acc.x*sc + pe*xv.x;
      acc.y = acc.y*sc + pe*xv.y;
      m = nm;
    }
    float inv = 1.f / (l + 1e-16f);
    oacc.x += acc.x * inv;
    oacc.y += acc.y * inv;
  }
  ushort2 o; o.x = f2b(oacc.x * (1.f/3.f)); o.y = f2b(oacc.y * (1.f/3.f));
  *(ushort2*)((unsigned short*)wsu + (size_t)uout + (size_t)gid*128 + f) = o;
}

// small-dst relations (k=0,2,4,6,7), chunked online softmax -> partials
struct GoD { int xl, xlstr, xr, attoff, rpoff, prefix, nd, nc; };
struct GoTab { GoD d[5]; int cumw[6]; };

__global__ void gat_online_batch(const unsigned short* __restrict__ wsu,
    const float* __restrict__ wsf, const int* __restrict__ csr,
    const int* __restrict__ rpb, float* __restrict__ part, GoTab t)
{
  int gid = (blockIdx.x*blockDim.x + threadIdx.x) >> 6;
  if (gid >= t.cumw[5]) return;
  int di = 0;
  while (gid >= t.cumw[di+1]) ++di;
  GoD d = t.d[di];
  int local = gid - t.cumw[di];
  int row = local / d.nc, c = local - row*d.nc;
  int lane = threadIdx.x & 63, f = lane*2, h = lane >> 4;
  float2 xrv = ldb2(wsu + (size_t)d.xr + (size_t)row*128 + f);
  float2 av  = *(const float2*)(wsf + d.attoff + f);
  int st = rpb[d.rpoff + row], en = rpb[d.rpoff + row + 1];
  float m = -INFINITY, l = 0.f;
  float2 acc = {0.f, 0.f};
  for (int i = st + c; i < en; i += d.nc){
    int s = csr[i];
    float2 xv = ldb2(wsu + (size_t)d.xl + (size_t)s*d.xlstr + f);
    float e0 = xv.x + xrv.x, e1 = xv.y + xrv.y;
    e0 = e0 > 0.f ? e0 : 0.2f*e0;
    e1 = e1 > 0.f ? e1 : 0.2f*e1;
    float p = e0*av.x + e1*av.y;
    p += __shfl_xor(p, 1); p += __shfl_xor(p, 2);
    p += __shfl_xor(p, 4); p += __shfl_xor(p, 8);
    float nm = fmaxf(m, p);
    float sc = __expf(m - nm);
    float pe = __expf(p - nm);
    l = l*sc + pe;
    acc.x = acc.x*sc + pe*xv.x;
    acc.y = acc.y*sc + pe*xv.y;
    m = nm;
  }
  float* pr = part + (size_t)(d.prefix + local)*136;
  if ((lane & 15) == 0){ pr[h] = m; pr[4+h] = l; }
  pr[8+f]   = acc.x;
  pr[8+f+1] = acc.y;
}

struct MgD { int prefix, outoff, nd, nc; float invS; };
struct MgTab { MgD d[5]; int cumw[6]; };

__global__ void gat_merge_batch(const float* __restrict__ part, float* __restrict__ wsf,
                                MgTab t){
  int gid = (blockIdx.x*blockDim.x + threadIdx.x) >> 6;
  if (gid >= t.cumw[5]) return;
  int di = 0;
  while (gid >= t.cumw[di+1]) ++di;
  MgD d = t.d[di];
  int row = gid - t.cumw[di];
  int lane = threadIdx.x & 63, f = lane*2, h = lane >> 4;
  float M = -INFINITY;
  for (int c = 0; c < d.nc; ++c)
    M = fmaxf(M, part[(size_t)(d.prefix + row*d.nc + c)*136 + h]);
  float L = 0.f;
  float2 acc = {0.f, 0.f};
  for (int c = 0; c < d.nc; ++c){
    const float* pr = part + (size_t)(d.prefix + row*d.nc + c)*136;
    float mc = pr[h];
    float w = (mc == -INFINITY) ? 0.f : __expf(mc - M);
    L += pr[4+h] * w;
    acc.x += pr[8+f]   * w;
    acc.y += pr[8+f+1] * w;
  }
  float inv = d.invS / (L + 1e-16f);
  float* o = wsf + (size_t)d.outoff + (size_t)row*128 + f;
  o[0] = acc.x * inv;
  o[1] = acc.y * inv;
}

// ---------------------------------------------------------------- final output
__global__ void final_out(const unsigned short* __restrict__ wsu,
  const float* __restrict__ wsf, int uoutA, int oC0, int oE2, int oE7, int oG4, int oG6,
  int ogb, const int* __restrict__ flagp, void* __restrict__ dout)
{
  const int fl = *flagp;
  int idx = blockIdx.x*blockDim.x + threadIdx.x;
  const int total = 101090*128;
  if (idx >= total) return;
  int row = idx >> 7, c = idx & 127;
  float v; int t;
  if (row < A_N){ v = bf16dec(wsu[(size_t)uoutA + idx]); t = 0; }
  else if (row < A_N + C_N){ v = wsf[oC0 + (row - A_N)*128 + c]; t = 1; }
  else if (row < A_N + C_N + V_N){
    int l = (row - A_N - C_N)*128 + c;
    v = wsf[oE2 + l] + wsf[oE7 + l]; t = 2;
  } else {
    int l = (row - A_N - C_N - V_N)*128 + c;
    v = wsf[oG4 + l] + wsf[oG6 + l]; t = 3;
  }
  v += wsf[ogb + t*128 + c];
  if (fl) ((float*)dout)[idx] = v;
  else    ((__hip_bfloat16*)dout)[idx] = __float2bfloat16(v);
}

__global__ void ws_fail(float* __restrict__ out, float mb){
  if (threadIdx.x == 0 && blockIdx.x == 0) out[0] = mb;
}

// ================================================================ host
extern "C" void kernel_launch(void* const* d_in, const int* in_sizes, int n_in,
                              void* d_out, int out_size, void* d_ws, size_t ws_size,
                              hipStream_t stream)
{
  float* wsf = (float*)d_ws;
  unsigned short* wsu = (unsigned short*)d_ws;
  int* flagp = (int*)d_ws;
  size_t off = 16;
  auto alloc = [&](size_t n){ size_t o = off; off += (n + 15) & ~(size_t)15; return (int)o; };
  auto allocU = [&](size_t nu){ return 2*alloc((nu + 1)/2); };  // returns ushort offset

  static const int conv_in_idx[29] = {0,1,2,3, 8,9,10,11, 12,13,14,15, 16,17,18,19,
                                      20,21,22,23, 24,25,26, 27,28,29,30,31,32};
  static const int conv_n[29] = {700000,690,307200,120,
                                 896,128,16384,128, 384,128,16384,128,
                                 49152,128,16384,128, 256,128,16384,128,
                                 131072,1024,131072, 131072,1024,131072,1024,1024,1024};
  ConvTab tab;
  int coff[29];
  int total = 0;
  for (int i = 0; i < 29; ++i){
    tab.src[i] = d_in[conv_in_idx[i]];
    coff[i] = alloc((size_t)conv_n[i]);
    tab.dstoff[i] = coff[i];
    tab.cum[i] = total; total += conv_n[i];
  }
  tab.cum[29] = total;

  const int o_sWl = coff[20], o_sbl = coff[21];
  const int o_gWl = coff[23], o_gbl = coff[24], o_gWr = coff[25], o_gbr = coff[26];
  const int o_gatt = coff[27], o_gbias = coff[28];

  int o_wrcomb = alloc(4*16384);
  int o_sbcomb = alloc(512);
  int o_gbcomb = alloc(512);
  int o_gblx = alloc(384);
  int o_gbrx = alloc(384);
  int o_cnt  = alloc(SCAN_N);
  int o_rp   = alloc(SCAN_N);
  int o_woff = alloc(SCAN_N);
  int o_bsum = alloc(1024);
  int o_csr  = alloc(E_TOTAL);
  int o_part = alloc((size_t)22320*136);
  int o_aggS = alloc((size_t)1950*128);           // 5 buffers: 230,800,800,60,60 rows
  int o_outC0 = alloc(230*128);
  int o_outE2 = alloc(800*128);
  int o_outE7 = alloc(800*128);
  int o_outG4 = alloc(60*128);
  int o_outG6 = alloc(60*128);

  // bf16 buffers (ushort offsets)
  int u_bswz = allocU(573440);
  int u_xEb  = allocU(307200);
  int u_zC   = allocU(230*128);
  int u_zE   = allocU(800*128);
  int u_zG   = allocU(60*128);
  int u_sxC  = allocU(230*256);
  int u_sxE  = allocU(800*384);
  int u_sxG  = allocU(60*384);
  int u_yC   = allocU(230*128);
  int u_yE   = allocU(800*128);
  int u_yG   = allocU(60*128);
  int u_xl1  = allocU(230*128);
  int u_xl3  = allocU(800*128);
  int u_xl5  = allocU(60*128);
  int u_xl6  = allocU(800*128);
  int u_xl7  = allocU(60*128);
  int u_xr0  = allocU(230*128);
  int u_xr2  = allocU(800*128);
  int u_xr4  = allocU(60*128);
  int u_xr6  = allocU(60*128);
  int u_xr7  = allocU(800*128);
  int u_big0 = allocU((size_t)A_N*128);   // zA, then yA
  int u_bigH = allocU((size_t)A_N*128);   // hA, then outA
  int u_bigA = allocU((size_t)A_N*384);   // aggA, then gxl, then gxr

  if (off*4 > ws_size){
    ws_fail<<<1, 64, 0, stream>>>((float*)d_out, (float)((off*4) >> 20));
    return;
  }

  // swizzled-weight sub-offsets (within bswz)
  const int u_eAW2 = u_bswz + 0,      u_eCW2 = u_bswz + 16384;
  const int u_eEW2 = u_bswz + 32768,  u_eGW2 = u_bswz + 49152;
  const int u_eEW1 = u_bswz + 65536;
  const int u_sxAW = u_bswz + 114688, u_sxCW = u_bswz + 180224;
  const int u_sxEW = u_bswz + 212992, u_sxGW = u_bswz + 262144;
  const int u_gxlW = u_bswz + 311296, u_gxrW = u_bswz + 360448;
  int u_smW[10];
  for (int i = 0; i < 10; ++i) u_smW[i] = u_bswz + 409600 + i*16384;

  const int n_nodes[4] = {A_N, C_N, V_N, G_N};
  const int et_dst[8] = {1,0,2,0,3,0,3,2};
  const int et_ei[8]  = {4,4,5,5,6,6,7,7};
  const int et_rev[8] = {0,1,0,1,0,1,0,1};
  const int et_E[8]   = {100000,100000,500000,500000,300000,300000,2000,2000};

  const int* esp[8]; const int* edp[8]; int rowbase[8];
  {
    int rb = 0;
    for (int k = 0; k < 8; ++k){
      const int* ei = (const int*)d_in[et_ei[k]];
      int E = et_E[k];
      esp[k] = ei + (et_rev[k] ? E : 0);
      edp[k] = ei + (et_rev[k] ? 0 : E);
      rowbase[k] = rb; rb += n_nodes[et_dst[k]];
    }
  }
  int* rpb_p  = (int*)(wsf + o_rp);
  int* csr_p  = (int*)(wsf + o_csr);

  // ---------------- conversions / weight prep
  detect_dtype<<<1, 256, 0, stream>>>((const unsigned short*)d_in[2], flagp);
  convert_all<<<2048, 256, 0, stream>>>(tab, wsf, flagp, total);
  prep_combos<<<(4*16384 + 255)/256, 256, 0, stream>>>(wsf + o_sWl + 0, wsf + o_sbl,
      wsf + o_gbias, wsf + o_wrcomb, wsf + o_sbcomb, wsf + o_gbcomb);
  // NOTE: prep_combos expects sWr = coff[22]
  prep_combos<<<1, 1, 0, stream>>>(wsf, wsf, wsf, wsf + o_wrcomb, wsf + o_sbcomb, wsf + o_gbcomb);

  // (the dummy 1-thread launch above is a no-op guard; real call fixed here)
  // -- real prep: sWr is conv entry 22
  prep_combos<<<(4*16384 + 255)/256, 256, 0, stream>>>(wsf + coff[22], wsf + o_sbl,
      wsf + o_gbias, wsf + o_wrcomb, wsf + o_sbcomb, wsf + o_gbcomb);
  prep_bias2<<<2, 256, 0, stream>>>(wsf + o_gbl, wsf + o_gbr, wsf + o_gblx, wsf + o_gbrx);

  SwzTab st; int sn = 0, stotal = 0;
  auto push = [&](int src, int K, int dst, int nkc, int kc0, int nt0, float sc){
    st.d[sn++] = SwzD{src, dst, K, nkc, kc0, nt0, sc};
    stotal += K*128;
  };
  push(coff[6],  128, u_eAW2, 4, 0, 0, 1.f);
  push(coff[10], 128, u_eCW2, 4, 0, 0, 1.f);
  push(coff[14], 128, u_eEW2, 4, 0, 0, 1.f);
  push(coff[18], 128, u_eGW2, 4, 0, 0, 1.f);
  push(coff[12], 384, u_eEW1, 12, 0, 0, 1.f);
  push(o_wrcomb + 0,     128, u_sxAW, 16, 0,  0, 1.f);
  push(o_sWl + 1*16384,  128, u_sxAW, 16, 4,  0, 1.f/3.f);
  push(o_sWl + 3*16384,  128, u_sxAW, 16, 8,  0, 1.f/3.f);
  push(o_sWl + 5*16384,  128, u_sxAW, 16, 12, 0, 1.f/3.f);
  push(o_wrcomb + 16384, 128, u_sxCW, 8, 0, 0, 1.f);
  push(o_sWl + 0*16384,  128, u_sxCW, 8, 4, 0, 1.f);
  push(o_wrcomb + 32768, 128, u_sxEW, 12, 0, 0, 1.f);
  push(o_sWl + 2*16384,  128, u_sxEW, 12, 4, 0, 0.5f);
  push(o_sWl + 7*16384,  128, u_sxEW, 12, 8, 0, 0.5f);
  push(o_wrcomb + 49152, 128, u_sxGW, 12, 0, 0, 1.f);
  push(o_sWl + 4*16384,  128, u_sxGW, 12, 4, 0, 0.5f);
  push(o_sWl + 6*16384,  128, u_sxGW, 12, 8, 0, 0.5f);
  push(o_gWl + 0*16384, 128, u_gxlW, 4, 0, 0,  1.f);
  push(o_gWl + 2*16384, 128, u_gxlW, 4, 0, 8,  1.f);
  push(o_gWl + 4*16384, 128, u_gxlW, 4, 0, 16, 1.f);
  push(o_gWr + 1*16384, 128, u_gxrW, 4, 0, 0,  1.f);
  push(o_gWr + 3*16384, 128, u_gxrW, 4, 0, 8,  1.f);
  push(o_gWr + 5*16384, 128, u_gxrW, 4, 0, 16, 1.f);
  const int xlk[5] = {1,3,5,6,7};
  for (int i = 0; i < 5; ++i) push(o_gWl + xlk[i]*16384, 128, u_smW[i], 4, 0, 0, 1.f);
  const int xrk[5] = {0,2,4,6,7};
  for (int i = 0; i < 5; ++i) push(o_gWr + xrk[i]*16384, 128, u_smW[5+i], 4, 0, 0, 1.f);
  st.n = sn; st.total = stotal;
  swz_batch<<<(stotal + 255)/256, 256, 0, stream>>>(wsf, wsu, st);

  // ---------------- CSR build
  hipMemsetAsync(wsf + o_cnt, 0, (size_t)SCAN_N*4, stream);
  for (int k = 0; k < 8; ++k){
    int E = et_E[k], nd = n_nodes[et_dst[k]];
    if (nd <= 800)
      hist_lds<<<imin(256, (E + 255)/256), 256, 0, stream>>>(edp[k], E,
          (int*)(wsf + o_cnt) + rowbase[k], nd);
    else
      hist_plain<<<(E + 255)/256, 256, 0, stream>>>(edp[k], E,
          (int*)(wsf + o_cnt) + rowbase[k]);
  }
  scan1<<<SCAN_NB, 256, 0, stream>>>((int*)(wsf + o_cnt), rpb_p, (int*)(wsf + o_bsum));
  scan2<<<1, 512, 0, stream>>>((int*)(wsf + o_bsum));
  scan3<<<(SCAN_N + 255)/256, 256, 0, stream>>>(rpb_p, (int*)(wsf + o_woff),
                                                (int*)(wsf + o_bsum));
  for (int k = 0; k < 8; ++k){
    int E = et_E[k], nd = n_nodes[et_dst[k]];
    if (nd <= 800){
      int span = 256*PCHUNK;
      place_lds<<<imin(304, (E + span - 1)/span), 256, 0, stream>>>(
          esp[k], edp[k], E, (int*)(wsf + o_woff) + rowbase[k], csr_p, nd);
    } else {
      place_plain<<<(E + 255)/256, 256, 0, stream>>>(esp[k], edp[k], E,
          (int*)(wsf + o_woff) + rowbase[k], csr_p);
    }
  }

  // ---------------- encoders
  enc_l1<<<(A_N*128 + 255)/256, 256, 0, stream>>>(wsf + coff[0], wsf + coff[4],
      wsf + coff[5], wsu + u_big0, A_N, 7);
  enc_l1<<<(C_N*128 + 255)/256, 256, 0, stream>>>(wsf + coff[1], wsf + coff[8],
      wsf + coff[9], wsu + u_zC, C_N, 3);
  enc_l1<<<(G_N*128 + 255)/256, 256, 0, stream>>>(wsf + coff[3], wsf + coff[16],
      wsf + coff[17], wsu + u_zG, G_N, 2);
  cvt_bf16<<<(307200 + 255)/256, 256, 0, stream>>>(wsf + coff[2], wsu + u_xEb, 307200);

  GBTab e1; e1.n = 3;
  e1.d[0] = GB{u_zC, 128, u_eCW2, coff[11], u_sxC, 256, C_N, 4, 0};
  e1.d[1] = GB{u_xEb, 384, u_eEW1, coff[13], u_zE, 128, V_N, 12, FLAG_RELU};
  e1.d[2] = GB{u_zG, 128, u_eGW2, coff[19], u_sxG, 384, G_N, 4, 0};
  mfma_gemm_batch<<<3*13, 256, 0, stream>>>(d_ws, e1);
  GBTab e2; e2.n = 1;
  e2.d[0] = GB{u_zE, 128, u_eEW2, coff[15], u_sxE, 384, V_N, 4, 0};
  mfma_gemm_batch<<<13, 256, 0, stream>>>(d_ws, e2);
  // athlete l2: zA -> hA
  mfma_gemm<<<dim3((A_N + 63)/64, 1), 256, 0, stream>>>(d_ws, u_big0, 128, 0, 0, 1000,
      u_eAW2, 4, coff[7], u_bigH, 128, A_N, 0);

  // ---------------- SAGE layer
  sage_gather_athA<<<(A_N*64 + 255)/256, 256, 0, stream>>>(wsu, csr_p, rpb_p,
      u_sxC, u_sxE, u_sxG, rowbase[1], rowbase[3], rowbase[5], u_bigA);
  hipMemsetAsync(wsf + o_aggS, 0, (size_t)1950*128*4, stream);
  const int b0 = o_aggS, b2 = o_aggS + 230*128, b7 = b2 + 800*128,
            b4 = b7 + 800*128, b6 = b4 + 60*128;
  SgTab sg;
  sg.d[0] = SgD{u_bigH, 128, rowbase[0], b0, C_N, 8};
  sg.d[1] = SgD{u_bigH, 128, rowbase[2], b2, V_N, 8};
  sg.d[2] = SgD{u_sxG, 384, rowbase[7], b7, V_N, 8};
  sg.d[3] = SgD{u_bigH, 128, rowbase[4], b4, G_N, 64};
  sg.d[4] = SgD{u_sxE, 384, rowbase[6], b6, G_N, 64};
  sg.cumw[0] = 0;
  {
    int c = 0;
    for (int i = 0; i < 5; ++i){ c += sg.d[i].nd*sg.d[i].nc; sg.cumw[i+1] = c; }
  }
  sage_gather_small<<<(sg.cumw[5]*64 + 255)/256, 256, 0, stream>>>(wsu, wsf, csr_p, rpb_p, sg);
  AfTab af; af.n = 5;
  af.d[0] = AfD{b0, rowbase[0], u_sxC + 128, 256, C_N};
  af.d[1] = AfD{b2, rowbase[2], u_sxE + 128, 384, V_N};
  af.d[2] = AfD{b7, rowbase[7], u_sxE + 256, 384, V_N};
  af.d[3] = AfD{b4, rowbase[4], u_sxG + 128, 384, G_N};
  af.d[4] = AfD{b6, rowbase[6], u_sxG + 256, 384, G_N};
  int aftot = 1950*128;
  aggfin_batch<<<(aftot + 255)/256, 256, 0, stream>>>(wsu, wsf, rpb_p, af, aftot);
  GBTab sgm; sgm.n = 3;
  sgm.d[0] = GB{u_sxC, 256, u_sxCW, o_sbcomb + 128, u_yC, 128, C_N, 8,  FLAG_RELU};
  sgm.d[1] = GB{u_sxE, 384, u_sxEW, o_sbcomb + 256, u_yE, 128, V_N, 12, FLAG_RELU};
  sgm.d[2] = GB{u_sxG, 384, u_sxGW, o_sbcomb + 384, u_yG, 128, G_N, 12, FLAG_RELU};
  mfma_gemm_batch<<<3*13, 256, 0, stream>>>(d_ws, sgm);
  // SAGE athlete: [hA | aggA] @ sxAW -> yA (big0)
  mfma_gemm<<<dim3((A_N + 63)/64, 1), 256, 0, stream>>>(d_ws, u_bigH, 128, u_bigA, 384, 4,
      u_sxAW, 16, o_sbcomb, u_big0, 128, A_N, FLAG_RELU);

  // ---------------- GAT layer
  // gxl = yA @ [gWl0|gWl2|gWl4] -> bigA (aggA dead)
  mfma_gemm<<<dim3((A_N + 63)/64, 3), 256, 0, stream>>>(d_ws, u_big0, 128, 0, 0, 1000,
      u_gxlW, 4, o_gblx, u_bigA, 384, A_N, 0);
  GBTab gm; gm.n = 10;
  gm.d[0] = GB{u_yC, 128, u_smW[0], o_gbl + 1*128, u_xl1, 128, C_N, 4, 0};
  gm.d[1] = GB{u_yE, 128, u_smW[1], o_gbl + 3*128, u_xl3, 128, V_N, 4, 0};
  gm.d[2] = GB{u_yG, 128, u_smW[2], o_gbl + 5*128, u_xl5, 128, G_N, 4, 0};
  gm.d[3] = GB{u_yE, 128, u_smW[3], o_gbl + 6*128, u_xl6, 128, V_N, 4, 0};
  gm.d[4] = GB{u_yG, 128, u_smW[4], o_gbl + 7*128, u_xl7, 128, G_N, 4, 0};
  gm.d[5] = GB{u_yC, 128, u_smW[5], o_gbr + 0*128, u_xr0, 128, C_N, 4, 0};
  gm.d[6] = GB{u_yE, 128, u_smW[6], o_gbr + 2*128, u_xr2, 128, V_N, 4, 0};
  gm.d[7] = GB{u_yG, 128, u_smW[7], o_gbr + 4*128, u_xr4, 128, G_N, 4, 0};
  gm.d[8] = GB{u_yG, 128, u_smW[8], o_gbr + 6*128, u_xr6, 128, G_N, 4, 0};
  gm.d[9] = GB{u_yE, 128, u_smW[9], o_gbr + 7*128, u_xr7, 128, V_N, 4, 0};
  mfma_gemm_batch<<<10*13, 256, 0, stream>>>(d_ws, gm);

  GoTab go;
  go.d[0] = GoD{u_bigA + 0,   384, u_xr0, o_gatt + 0*128, rowbase[0], 0,     C_N, 8};
  go.d[1] = GoD{u_bigA + 128, 384, u_xr2, o_gatt + 2*128, rowbase[2], 1840,  V_N, 8};
  go.d[2] = GoD{u_bigA + 256, 384, u_xr4, o_gatt + 4*128, rowbase[4], 8240,  G_N, 64};
  go.d[3] = GoD{u_xl6, 128,        u_xr6, o_gatt + 6*128, rowbase[6], 12080, G_N, 64};
  go.d[4] = GoD{u_xl7, 128,        u_xr7, o_gatt + 7*128, rowbase[7], 15920, V_N, 8};
  go.cumw[0] = 0;
  {
    int c = 0;
    for (int i = 0; i < 5; ++i){ c += go.d[i].nd*go.d[i].nc; go.cumw[i+1] = c; }
  }
  gat_online_batch<<<(go.cumw[5]*64 + 255)/256, 256, 0, stream>>>(wsu, wsf, csr_p, rpb_p,
      wsf + o_part, go);

  // gxr = yA @ [gWr1|gWr3|gWr5] -> bigA (gxl dead after gat_online_batch)
  mfma_gemm<<<dim3((A_N + 63)/64, 3), 256, 0, stream>>>(d_ws, u_big0, 128, 0, 0, 1000,
      u_gxrW, 4, o_gbrx, u_bigA, 384, A_N, 0);
  gat_ath<<<(A_N*64 + 255)/256, 256, 0, stream>>>(wsu, wsf, csr_p, rpb_p,
      u_bigA, u_xl1, u_xl3, u_xl5, o_gatt, rowbase[1], rowbase[3], rowbase[5], u_bigH);

  MgTab mg;
  mg.d[0] = MgD{0,     o_outC0, C_N, 8,  1.0f};
  mg.d[1] = MgD{1840,  o_outE2, V_N, 8,  0.5f};
  mg.d[2] = MgD{8240,  o_outG4, G_N, 64, 0.5f};
  mg.d[3] = MgD{12080, o_outG6, G_N, 64, 0.5f};
  mg.d[4] = MgD{15920, o_outE7, V_N, 8,  0.5f};
  mg.cumw[0] = 0;
  {
    int c = 0;
    for (int i = 0; i < 5; ++i){ c += mg.d[i].nd; mg.cumw[i+1] = c; }
  }
  gat_merge_batch<<<(mg.cumw[5]*64 + 255)/256, 256, 0, stream>>>(wsf + o_part, wsf, mg);

  final_out<<<(101090*128 + 255)/256, 256, 0, stream>>>(wsu, wsf, u_bigH,
      o_outC0, o_outE2, o_outE7, o_outG4, o_outG6, o_gbcomb, flagp, d_out);
}

// Round 5
// 1093.440 us; speedup vs baseline: 8.2998x; 1.1068x over previous
//
#include <hip/hip_runtime.h>
#include <hip/hip_bf16.h>

#define A_N 100000
#define C_N 230
#define V_N 800
#define G_N 60

#define FLAG_RELU 2

#define SCAN_N   302080          // 295 * 1024 (padded row-count over 8 relations)
#define SCAN_NB  295
#define E_TOTAL  1804000

#define PCHUNK 16

typedef __attribute__((ext_vector_type(8))) short short8;
typedef __attribute__((ext_vector_type(4))) float f32x4;

__device__ __forceinline__ float bf16dec(unsigned short u){
  return __uint_as_float(((unsigned)u) << 16);
}
__device__ __forceinline__ unsigned short f2b(float v){
  union { __hip_bfloat16 h; unsigned short u; } c;
  c.h = __float2bfloat16(v);
  return c.u;
}
__device__ __forceinline__ float4 ldb4(const unsigned short* p){
  uint2 v = *(const uint2*)p;
  float4 r;
  r.x = __uint_as_float(v.x << 16);
  r.y = __uint_as_float(v.x & 0xffff0000u);
  r.z = __uint_as_float(v.y << 16);
  r.w = __uint_as_float(v.y & 0xffff0000u);
  return r;
}
static inline int imin(int a, int b){ return a < b ? a : b; }

// ---------------------------------------------------------------- detect dtype
__global__ void detect_dtype(const unsigned short* __restrict__ p, int* __restrict__ flag){
  __shared__ int bad;
  if (threadIdx.x == 0) bad = 0;
  __syncthreads();
  for (int i = threadIdx.x; i < 2048; i += blockDim.x){
    float v = fabsf(bf16dec(p[i]));
    if (!(v <= 1e6f)) atomicOr(&bad, 1);
  }
  __syncthreads();
  if (threadIdx.x == 0) *flag = bad;       // 1 => inputs stored as fp32
}

// ---------------------------------------------------------------- convert all
struct ConvTab { const void* src[29]; int dstoff[29]; int cum[30]; };

__global__ void convert_all(ConvTab tab, float* __restrict__ wsf,
                            const int* __restrict__ flagp, int total){
  const int f = *flagp;
  for (int idx = blockIdx.x*blockDim.x + threadIdx.x; idx < total;
       idx += gridDim.x*blockDim.x){
    int t = 0;
    while (idx >= tab.cum[t+1]) ++t;
    int l = idx - tab.cum[t];
    float v = f ? ((const float*)tab.src[t])[l]
                : bf16dec(((const unsigned short*)tab.src[t])[l]);
    wsf[tab.dstoff[t] + l] = v;
  }
}

// ---------------------------------------------------------------- prep combos
__global__ void prep_combos(const float* __restrict__ sWr, const float* __restrict__ sbl,
                            const float* __restrict__ gbias,
                            float* __restrict__ wrcomb, float* __restrict__ sbcomb,
                            float* __restrict__ gbcomb){
  const int sets[4][3] = {{1,3,5},{0,-1,-1},{2,7,-1},{4,6,-1}};
  const float inv[4] = {1.f/3.f, 1.f, 0.5f, 0.5f};
  int idx = blockIdx.x*blockDim.x + threadIdx.x;
  if (idx >= 4*16384) return;
  int t = idx >> 14, j = idx & 16383;
  float s = 0.f;
  #pragma unroll
  for (int q = 0; q < 3; ++q){
    int k = sets[t][q];
    if (k >= 0) s += sWr[k*16384 + j];
  }
  wrcomb[idx] = s * inv[t];
  if (j < 128){
    float b1 = 0.f, b2 = 0.f;
    #pragma unroll
    for (int q = 0; q < 3; ++q){
      int k = sets[t][q];
      if (k >= 0){ b1 += sbl[k*128 + j]; b2 += gbias[k*128 + j]; }
    }
    sbcomb[t*128 + j] = b1 * inv[t];
    gbcomb[t*128 + j] = b2 * inv[t];
  }
}

// gblx = concat(gbl[0],gbl[2],gbl[4]); gbrx = concat(gbr[1],gbr[3],gbr[5])
__global__ void prep_bias2(const float* __restrict__ gbl, const float* __restrict__ gbr,
                           float* __restrict__ gblx, float* __restrict__ gbrx){
  int i = blockIdx.x*blockDim.x + threadIdx.x;
  if (i >= 384) return;
  const int kl[3] = {0,2,4}, kr[3] = {1,3,5};
  int rel = i >> 7, j = i & 127;
  gblx[i] = gbl[kl[rel]*128 + j];
  gbrx[i] = gbr[kr[rel]*128 + j];
}

// ---------------------------------------------------------------- weight swizzle
struct SwzD { int src, dst, K, nkc, kc0, nt0; float scale; };
struct SwzTab { SwzD d[33]; int n, total; };

__global__ void swz_batch(const float* __restrict__ wsf, unsigned short* __restrict__ wsu,
                          SwzTab t){
  for (int idx = blockIdx.x*blockDim.x + threadIdx.x; idx < t.total;
       idx += gridDim.x*blockDim.x){
    int di = 0, local = idx;
    while (local >= t.d[di].K*128){ local -= t.d[di].K*128; ++di; }
    SwzD d = t.d[di];
    int j = local & 7, lane = (local>>3) & 63, rest = local >> 9;
    int kcn = d.K >> 5;
    int kc = rest % kcn, nt = rest / kcn;
    int k = kc*32 + (lane>>4)*8 + j;
    int n = nt*16 + (lane&15);
    float v = wsf[d.src + k*128 + n] * d.scale;
    wsu[(size_t)d.dst + ((size_t)((d.nt0+nt)*d.nkc + d.kc0+kc)*64 + lane)*8 + j] = f2b(v);
  }
}

// ---------------------------------------------------------------- CSR build
__global__ void hist_plain(const int* __restrict__ dp, int E, int* __restrict__ cnt){
  int i = blockIdx.x*blockDim.x + threadIdx.x;
  if (i < E) atomicAdd(&cnt[dp[i]], 1);
}

__global__ void hist_lds(const int* __restrict__ dp, int E, int* __restrict__ cnt, int ndst){
  __shared__ int l[800];
  for (int i = threadIdx.x; i < ndst; i += blockDim.x) l[i] = 0;
  __syncthreads();
  for (int i = blockIdx.x*blockDim.x + threadIdx.x; i < E; i += gridDim.x*blockDim.x)
    atomicAdd(&l[dp[i]], 1);
  __syncthreads();
  for (int i = threadIdx.x; i < ndst; i += blockDim.x)
    if (l[i]) atomicAdd(&cnt[i], l[i]);
}

__global__ void scan1(const int* __restrict__ cnt, int* __restrict__ rp, int* __restrict__ bsum){
  __shared__ int sd[256];
  int tid = threadIdx.x, blk = blockIdx.x;
  int base = blk*1024 + tid*4;
  int4 v = *(const int4*)(cnt + base);
  int s = v.x + v.y + v.z + v.w;
  sd[tid] = s;
  __syncthreads();
  for (int off = 1; off < 256; off <<= 1){
    int t = (tid >= off) ? sd[tid-off] : 0;
    __syncthreads();
    sd[tid] += t;
    __syncthreads();
  }
  int excl = sd[tid] - s;
  rp[base+0] = excl;
  rp[base+1] = excl + v.x;
  rp[base+2] = excl + v.x + v.y;
  rp[base+3] = excl + v.x + v.y + v.z;
  if (tid == 255) bsum[blk] = sd[255];
}

__global__ void scan2(int* __restrict__ bsum){
  __shared__ int sd[512];
  int tid = threadIdx.x;
  int v = (tid < SCAN_NB) ? bsum[tid] : 0;
  sd[tid] = v;
  __syncthreads();
  for (int off = 1; off < 512; off <<= 1){
    int t = (tid >= off) ? sd[tid-off] : 0;
    __syncthreads();
    sd[tid] += t;
    __syncthreads();
  }
  if (tid < SCAN_NB) bsum[tid] = sd[tid] - v;
}

__global__ void scan3(int* __restrict__ rp, int* __restrict__ woff,
                      const int* __restrict__ bsum){
  int idx = blockIdx.x*blockDim.x + threadIdx.x;
  if (idx >= SCAN_N) return;
  int v = rp[idx] + bsum[idx >> 10];
  rp[idx] = v;
  woff[idx] = v;
}

__global__ void place_plain(const int* __restrict__ sp, const int* __restrict__ dp,
                            int E, int* __restrict__ woff, int* __restrict__ csr){
  int i = blockIdx.x*blockDim.x + threadIdx.x;
  if (i < E){
    int pos = atomicAdd(&woff[dp[i]], 1);
    csr[pos] = sp[i];
  }
}

__global__ void place_lds(const int* __restrict__ sp, const int* __restrict__ dp,
                          int E, int* __restrict__ woff, int* __restrict__ csr, int ndst){
  __shared__ int lcnt[800];
  __shared__ int lbase[800];
  const int tid = threadIdx.x;
  const int span = blockDim.x * PCHUNK;
  for (int b0 = blockIdx.x*span; b0 < E; b0 += gridDim.x*span){
    for (int i = tid; i < ndst; i += blockDim.x) lcnt[i] = 0;
    __syncthreads();
    int d[PCHUNK], s[PCHUNK], r[PCHUNK];
    #pragma unroll
    for (int j = 0; j < PCHUNK; ++j){
      int e = b0 + j*blockDim.x + tid;
      d[j] = -1;
      if (e < E){
        s[j] = sp[e];
        d[j] = dp[e];
        r[j] = atomicAdd(&lcnt[d[j]], 1);
      }
    }
    __syncthreads();
    for (int i = tid; i < ndst; i += blockDim.x){
      int c = lcnt[i];
      if (c) lbase[i] = atomicAdd(&woff[i], c);
    }
    __syncthreads();
    #pragma unroll
    for (int j = 0; j < PCHUNK; ++j)
      if (d[j] >= 0) csr[lbase[d[j]] + r[j]] = s[j];
    __syncthreads();
  }
}

// ---------------------------------------------------------------- encoder L1 (tiny K)
__global__ void enc_l1(const float* __restrict__ X, const float* __restrict__ W1,
                       const float* __restrict__ b1, unsigned short* __restrict__ Z,
                       int M, int K){
  int idx = blockIdx.x*blockDim.x + threadIdx.x;
  if (idx >= M*128) return;
  int r = idx >> 7, c = idx & 127;
  float s = b1[c];
  for (int k = 0; k < K; ++k) s = fmaf(X[r*K + k], W1[(k<<7) + c], s);
  Z[idx] = f2b(fmaxf(s, 0.f));
}

__global__ void cvt_bf16(const float* __restrict__ src, unsigned short* __restrict__ dst, int n){
  int i = blockIdx.x*blockDim.x + threadIdx.x;
  if (i < n) dst[i] = f2b(src[i]);
}

// ---------------------------------------------------------------- MFMA GEMM
__device__ __forceinline__ void mfma_core(
    const unsigned short* __restrict__ wsu, const float* __restrict__ wsf,
    int xoff, int xstride, int x2off, int x2stride, int kcsplit,
    int woff, int nkc, int biasoff, int yoff, int ystride,
    int M, int flags, int mblk, int nblk)
{
  int tid = threadIdx.x;
  int wv = tid >> 6, lane = tid & 63;
  int quad = lane >> 4, ml = lane & 15;
  int m0 = mblk*64 + wv*16;
  if (m0 >= M) return;
  int arow = m0 + ml;
  bool rowok = arow < M;
  f32x4 acc[8];
  #pragma unroll
  for (int i = 0; i < 8; ++i) acc[i] = (f32x4){0.f, 0.f, 0.f, 0.f};
  for (int kc = 0; kc < nkc; ++kc){
    short8 a = (short8){0,0,0,0,0,0,0,0};
    if (rowok){
      size_t ao = (kc < kcsplit)
        ? (size_t)xoff  + (size_t)arow*xstride  + kc*32 + quad*8
        : (size_t)x2off + (size_t)arow*x2stride + (kc - kcsplit)*32 + quad*8;
      a = *(const short8*)(wsu + ao);
    }
    size_t wbase = (size_t)woff + ((size_t)(nblk*8)*nkc + kc)*512 + lane*8;
    #pragma unroll
    for (int nt = 0; nt < 8; ++nt){
      short8 b = *(const short8*)(wsu + wbase + (size_t)nt*nkc*512);
      acc[nt] = __builtin_amdgcn_mfma_f32_16x16x32_bf16(a, b, acc[nt], 0, 0, 0);
    }
  }
  #pragma unroll
  for (int nt = 0; nt < 8; ++nt){
    int col = nblk*128 + nt*16 + ml;
    float bv = (biasoff >= 0) ? wsf[biasoff + col] : 0.f;
    #pragma unroll
    for (int r = 0; r < 4; ++r){
      int orow = m0 + quad*4 + r;
      if (orow < M){
        float v = acc[nt][r] + bv;
        if (flags & FLAG_RELU) v = fmaxf(v, 0.f);
        *((unsigned short*)wsu + (size_t)yoff + (size_t)orow*ystride + col) = f2b(v);
      }
    }
  }
}

__global__ __launch_bounds__(256) void mfma_gemm(
    void* ws, int xoff, int xstride, int x2off, int x2stride, int kcsplit,
    int woff, int nkc, int biasoff, int yoff, int ystride, int M, int flags)
{
  mfma_core((const unsigned short*)ws, (const float*)ws, xoff, xstride, x2off, x2stride,
            kcsplit, woff, nkc, biasoff, yoff, ystride, M, flags, blockIdx.x, blockIdx.y);
}

struct GB { int xoff, xstride, woff, biasoff, yoff, ystride, M, nkc, flags; };
struct GBTab { GB d[12]; int n; };

__global__ __launch_bounds__(256) void mfma_gemm_batch(void* ws, GBTab t){
  int di = blockIdx.x / 13, mb = blockIdx.x % 13;
  if (di >= t.n) return;
  GB g = t.d[di];
  mfma_core((const unsigned short*)ws, (const float*)ws, g.xoff, g.xstride, 0, 0, 1000,
            g.woff, g.nkc, g.biasoff, g.yoff, g.ystride, g.M, g.flags, mb, 0);
}

// ---------------------------------------------------------------- SAGE gathers
// 32 lanes/edge (4 bf16/lane), two edge streams per wave, unroll-2 per stream.
__global__ void sage_gather_athA(const unsigned short* __restrict__ wsu,
    const int* __restrict__ csr, const int* __restrict__ rpb,
    int uhC, int uhE, int uhG, int rp1, int rp3, int rp5, int uagg)
{
  int gid = (blockIdx.x*blockDim.x + threadIdx.x) >> 6;
  if (gid >= A_N) return;
  int lane = threadIdx.x & 63;
  int half = lane >> 5, sub = lane & 31, f = sub*4;
  int srcs[3] = {uhC, uhE, uhG};
  int sstr[3] = {256, 384, 384};
  int rps[3]  = {rp1, rp3, rp5};
  #pragma unroll
  for (int rel = 0; rel < 3; ++rel){
    const unsigned short* base = wsu + (size_t)srcs[rel] + f;
    int str = sstr[rel];
    int st = rpb[rps[rel] + gid], en = rpb[rps[rel] + gid + 1];
    float4 acc = {0.f, 0.f, 0.f, 0.f};
    int i = st + half;
    for (; i + 2 < en; i += 4){
      int s0 = csr[i], s1 = csr[i+2];
      float4 v0 = ldb4(base + (size_t)s0*str);
      float4 v1 = ldb4(base + (size_t)s1*str);
      acc.x += v0.x + v1.x; acc.y += v0.y + v1.y;
      acc.z += v0.z + v1.z; acc.w += v0.w + v1.w;
    }
    if (i < en){
      float4 v0 = ldb4(base + (size_t)csr[i]*str);
      acc.x += v0.x; acc.y += v0.y; acc.z += v0.z; acc.w += v0.w;
    }
    acc.x += __shfl_xor(acc.x, 32); acc.y += __shfl_xor(acc.y, 32);
    acc.z += __shfl_xor(acc.z, 32); acc.w += __shfl_xor(acc.w, 32);
    if (half == 0){
      int deg = en - st;
      float sc = 1.f / (float)(deg > 1 ? deg : 1);
      ushort4 o;
      o.x = f2b(acc.x*sc); o.y = f2b(acc.y*sc);
      o.z = f2b(acc.z*sc); o.w = f2b(acc.w*sc);
      *(ushort4*)((unsigned short*)wsu + (size_t)uagg + (size_t)gid*384 + rel*128 + f) = o;
    }
  }
}

struct SgD { int src, sstr, rpoff, aggoff, nd, nc; };
struct SgTab { SgD d[5]; int cumw[6]; };

__global__ void sage_gather_small(const unsigned short* __restrict__ wsu,
    float* __restrict__ wsf, const int* __restrict__ csr, const int* __restrict__ rpb,
    SgTab t)
{
  int gid = (blockIdx.x*blockDim.x + threadIdx.x) >> 6;
  if (gid >= t.cumw[5]) return;
  int di = 0;
  while (gid >= t.cumw[di+1]) ++di;
  SgD d = t.d[di];
  int local = gid - t.cumw[di];
  int row = local / d.nc, c = local - row*d.nc;
  int lane = threadIdx.x & 63;
  int half = lane >> 5, sub = lane & 31, f = sub*4;
  const unsigned short* base = wsu + (size_t)d.src + f;
  int st = rpb[d.rpoff + row], en = rpb[d.rpoff + row + 1];
  float4 acc = {0.f, 0.f, 0.f, 0.f};
  int i = st + c + half*d.nc;
  int step = 2*d.nc;
  for (; i + step < en; i += 2*step){
    int s0 = csr[i], s1 = csr[i+step];
    float4 v0 = ldb4(base + (size_t)s0*d.sstr);
    float4 v1 = ldb4(base + (size_t)s1*d.sstr);
    acc.x += v0.x + v1.x; acc.y += v0.y + v1.y;
    acc.z += v0.z + v1.z; acc.w += v0.w + v1.w;
  }
  if (i < en){
    float4 v0 = ldb4(base + (size_t)csr[i]*d.sstr);
    acc.x += v0.x; acc.y += v0.y; acc.z += v0.z; acc.w += v0.w;
  }
  acc.x += __shfl_xor(acc.x, 32); acc.y += __shfl_xor(acc.y, 32);
  acc.z += __shfl_xor(acc.z, 32); acc.w += __shfl_xor(acc.w, 32);
  if (half == 0){
    float* o = wsf + (size_t)d.aggoff + (size_t)row*128 + f;
    atomicAdd(o,   acc.x); atomicAdd(o+1, acc.y);
    atomicAdd(o+2, acc.z); atomicAdd(o+3, acc.w);
  }
}

struct AfD { int aggoff, rpoff, dstu, dstr, nd; };
struct AfTab { AfD d[5]; int n; };

__global__ void aggfin_batch(unsigned short* __restrict__ wsu, const float* __restrict__ wsf,
                             const int* __restrict__ rpb, AfTab t, int total){
  int idx = blockIdx.x*blockDim.x + threadIdx.x;
  if (idx >= total) return;
  int di = 0, local = idx;
  while (local >= t.d[di].nd*128){ local -= t.d[di].nd*128; ++di; }
  AfD d = t.d[di];
  int row = local >> 7, col = local & 127;
  int deg = rpb[d.rpoff + row + 1] - rpb[d.rpoff + row];
  float sc = 1.f / (float)(deg > 1 ? deg : 1);
  wsu[(size_t)d.dstu + (size_t)row*d.dstr + col] = f2b(wsf[(size_t)d.aggoff + local] * sc);
}

// ---------------------------------------------------------------- GATv2 edge kernels
// 32 lanes/edge online softmax. Head h = sub>>3 (8 lanes x 4 feats = 32/head).
#define GAT_UPD(xv)                                                        \
  {                                                                        \
    float e0 = (xv).x + xrv.x, e1 = (xv).y + xrv.y;                        \
    float e2 = (xv).z + xrv.z, e3 = (xv).w + xrv.w;                        \
    e0 = e0 > 0.f ? e0 : 0.2f*e0; e1 = e1 > 0.f ? e1 : 0.2f*e1;            \
    e2 = e2 > 0.f ? e2 : 0.2f*e2; e3 = e3 > 0.f ? e3 : 0.2f*e3;            \
    float p = e0*av.x + e1*av.y + e2*av.z + e3*av.w;                       \
    p += __shfl_xor(p, 1); p += __shfl_xor(p, 2); p += __shfl_xor(p, 4);   \
    float nm = fmaxf(m, p);                                                \
    float scw = __expf(m - nm);                                            \
    float pe = __expf(p - nm);                                             \
    l = l*scw + pe;                                                        \
    acc.x = acc.x*scw + pe*(xv).x; acc.y = acc.y*scw + pe*(xv).y;          \
    acc.z = acc.z*scw + pe*(xv).z; acc.w = acc.w*scw + pe*(xv).w;          \
    m = nm;                                                                \
  }

#define GAT_MERGE_HALVES                                                   \
  {                                                                        \
    float mo = __shfl_xor(m, 32);                                          \
    float lo = __shfl_xor(l, 32);                                          \
    float4 ao;                                                             \
    ao.x = __shfl_xor(acc.x, 32); ao.y = __shfl_xor(acc.y, 32);            \
    ao.z = __shfl_xor(acc.z, 32); ao.w = __shfl_xor(acc.w, 32);            \
    float nm = fmaxf(m, mo);                                               \
    float w  = (m  == -INFINITY) ? 0.f : __expf(m  - nm);                  \
    float wo = (mo == -INFINITY) ? 0.f : __expf(mo - nm);                  \
    l = l*w + lo*wo;                                                       \
    acc.x = acc.x*w + ao.x*wo; acc.y = acc.y*w + ao.y*wo;                  \
    acc.z = acc.z*w + ao.z*wo; acc.w = acc.w*w + ao.w*wo;                  \
    m = nm;                                                                \
  }

// fused athlete-dst (k=1,3,5)
__global__ void gat_ath(const unsigned short* __restrict__ wsu, const float* __restrict__ wsf,
    const int* __restrict__ csr, const int* __restrict__ rpb,
    int ugxr, int uxl1, int uxl3, int uxl5, int oatt, int rp1, int rp3, int rp5, int uout)
{
  int gid = (blockIdx.x*blockDim.x + threadIdx.x) >> 6;
  if (gid >= A_N) return;
  int lane = threadIdx.x & 63;
  int half = lane >> 5, sub = lane & 31, f = sub*4;
  int xls[3] = {uxl1, uxl3, uxl5};
  int rps[3] = {rp1, rp3, rp5};
  const int attk[3] = {1, 3, 5};
  float4 oacc = {0.f, 0.f, 0.f, 0.f};
  #pragma unroll
  for (int rel = 0; rel < 3; ++rel){
    float4 xrv = ldb4(wsu + (size_t)ugxr + (size_t)gid*384 + rel*128 + f);
    float4 av  = *(const float4*)(wsf + oatt + attk[rel]*128 + f);
    const unsigned short* base = wsu + (size_t)xls[rel] + f;
    int st = rpb[rps[rel] + gid], en = rpb[rps[rel] + gid + 1];
    float m = -INFINITY, l = 0.f;
    float4 acc = {0.f, 0.f, 0.f, 0.f};
    int i = st + half;
    for (; i + 2 < en; i += 4){
      int s0 = csr[i], s1 = csr[i+2];
      float4 x0 = ldb4(base + (size_t)s0*128);
      float4 x1 = ldb4(base + (size_t)s1*128);
      GAT_UPD(x0);
      GAT_UPD(x1);
    }
    if (i < en){
      float4 x0 = ldb4(base + (size_t)csr[i]*128);
      GAT_UPD(x0);
    }
    GAT_MERGE_HALVES;
    float inv = 1.f / (l + 1e-16f);
    oacc.x += acc.x * inv; oacc.y += acc.y * inv;
    oacc.z += acc.z * inv; oacc.w += acc.w * inv;
  }
  if (half == 0){
    ushort4 o;
    o.x = f2b(oacc.x * (1.f/3.f)); o.y = f2b(oacc.y * (1.f/3.f));
    o.z = f2b(oacc.z * (1.f/3.f)); o.w = f2b(oacc.w * (1.f/3.f));
    *(ushort4*)((unsigned short*)wsu + (size_t)uout + (size_t)gid*128 + f) = o;
  }
}

// small-dst relations (k=0,2,4,6,7) -> partials
struct GoD { int xl, xlstr, xr, attoff, rpoff, prefix, nd, nc; };
struct GoTab { GoD d[5]; int cumw[6]; };

__global__ void gat_online_batch(const unsigned short* __restrict__ wsu,
    const float* __restrict__ wsf, const int* __restrict__ csr,
    const int* __restrict__ rpb, float* __restrict__ part, GoTab t)
{
  int gid = (blockIdx.x*blockDim.x + threadIdx.x) >> 6;
  if (gid >= t.cumw[5]) return;
  int di = 0;
  while (gid >= t.cumw[di+1]) ++di;
  GoD d = t.d[di];
  int local = gid - t.cumw[di];
  int row = local / d.nc, c = local - row*d.nc;
  int lane = threadIdx.x & 63;
  int half = lane >> 5, sub = lane & 31, f = sub*4, h = sub >> 3;
  float4 xrv = ldb4(wsu + (size_t)d.xr + (size_t)row*128 + f);
  float4 av  = *(const float4*)(wsf + d.attoff + f);
  const unsigned short* base = wsu + (size_t)d.xl + f;
  int st = rpb[d.rpoff + row], en = rpb[d.rpoff + row + 1];
  float m = -INFINITY, l = 0.f;
  float4 acc = {0.f, 0.f, 0.f, 0.f};
  int i = st + c + half*d.nc;
  int step = 2*d.nc;
  for (; i + step < en; i += 2*step){
    int s0 = csr[i], s1 = csr[i+step];
    float4 x0 = ldb4(base + (size_t)s0*d.xlstr);
    float4 x1 = ldb4(base + (size_t)s1*d.xlstr);
    GAT_UPD(x0);
    GAT_UPD(x1);
  }
  if (i < en){
    float4 x0 = ldb4(base + (size_t)csr[i]*d.xlstr);
    GAT_UPD(x0);
  }
  GAT_MERGE_HALVES;
  if (half == 0){
    float* pr = part + (size_t)(d.prefix + local)*136;
    if ((sub & 7) == 0){ pr[h] = m; pr[4+h] = l; }
    *(float4*)(pr + 8 + f) = acc;
  }
}

struct MgD { int prefix, outoff, nd, nc; float invS; };
struct MgTab { MgD d[5]; int cumw[6]; };

__global__ void gat_merge_batch(const float* __restrict__ part, float* __restrict__ wsf,
                                MgTab t){
  int gid = (blockIdx.x*blockDim.x + threadIdx.x) >> 6;
  if (gid >= t.cumw[5]) return;
  int di = 0;
  while (gid >= t.cumw[di+1]) ++di;
  MgD d = t.d[di];
  int row = gid - t.cumw[di];
  int lane = threadIdx.x & 63, f = lane*2, h = lane >> 4;
  float M = -INFINITY;
  for (int c = 0; c < d.nc; ++c)
    M = fmaxf(M, part[(size_t)(d.prefix + row*d.nc + c)*136 + h]);
  float L = 0.f;
  float2 acc = {0.f, 0.f};
  for (int c = 0; c < d.nc; ++c){
    const float* pr = part + (size_t)(d.prefix + row*d.nc + c)*136;
    float mc = pr[h];
    float w = (mc == -INFINITY) ? 0.f : __expf(mc - M);
    L += pr[4+h] * w;
    acc.x += pr[8+f]   * w;
    acc.y += pr[8+f+1] * w;
  }
  float inv = d.invS / (L + 1e-16f);
  float* o = wsf + (size_t)d.outoff + (size_t)row*128 + f;
  o[0] = acc.x * inv;
  o[1] = acc.y * inv;
}

// ---------------------------------------------------------------- final output
__global__ void final_out(const unsigned short* __restrict__ wsu,
  const float* __restrict__ wsf, int uoutA, int oC0, int oE2, int oE7, int oG4, int oG6,
  int ogb, const int* __restrict__ flagp, void* __restrict__ dout)
{
  const int fl = *flagp;
  int idx = blockIdx.x*blockDim.x + threadIdx.x;
  const int total = 101090*128;
  if (idx >= total) return;
  int row = idx >> 7, c = idx & 127;
  float v; int t;
  if (row < A_N){ v = bf16dec(wsu[(size_t)uoutA + idx]); t = 0; }
  else if (row < A_N + C_N){ v = wsf[oC0 + (row - A_N)*128 + c]; t = 1; }
  else if (row < A_N + C_N + V_N){
    int l = (row - A_N - C_N)*128 + c;
    v = wsf[oE2 + l] + wsf[oE7 + l]; t = 2;
  } else {
    int l = (row - A_N - C_N - V_N)*128 + c;
    v = wsf[oG4 + l] + wsf[oG6 + l]; t = 3;
  }
  v += wsf[ogb + t*128 + c];
  if (fl) ((float*)dout)[idx] = v;
  else    ((__hip_bfloat16*)dout)[idx] = __float2bfloat16(v);
}

__global__ void ws_fail(float* __restrict__ out, float mb){
  if (threadIdx.x == 0 && blockIdx.x == 0) out[0] = mb;
}

// ================================================================ host
extern "C" void kernel_launch(void* const* d_in, const int* in_sizes, int n_in,
                              void* d_out, int out_size, void* d_ws, size_t ws_size,
                              hipStream_t stream)
{
  float* wsf = (float*)d_ws;
  unsigned short* wsu = (unsigned short*)d_ws;
  int* flagp = (int*)d_ws;
  size_t off = 16;
  auto alloc = [&](size_t n){ size_t o = off; off += (n + 15) & ~(size_t)15; return (int)o; };
  auto allocU = [&](size_t nu){ return 2*alloc((nu + 1)/2); };  // returns ushort offset

  static const int conv_in_idx[29] = {0,1,2,3, 8,9,10,11, 12,13,14,15, 16,17,18,19,
                                      20,21,22,23, 24,25,26, 27,28,29,30,31,32};
  static const int conv_n[29] = {700000,690,307200,120,
                                 896,128,16384,128, 384,128,16384,128,
                                 49152,128,16384,128, 256,128,16384,128,
                                 131072,1024,131072, 131072,1024,131072,1024,1024,1024};
  ConvTab tab;
  int coff[29];
  int total = 0;
  for (int i = 0; i < 29; ++i){
    tab.src[i] = d_in[conv_in_idx[i]];
    coff[i] = alloc((size_t)conv_n[i]);
    tab.dstoff[i] = coff[i];
    tab.cum[i] = total; total += conv_n[i];
  }
  tab.cum[29] = total;

  const int o_sWl = coff[20], o_sbl = coff[21];
  const int o_gWl = coff[23], o_gbl = coff[24], o_gWr = coff[25], o_gbr = coff[26];
  const int o_gatt = coff[27], o_gbias = coff[28];

  int o_wrcomb = alloc(4*16384);
  int o_sbcomb = alloc(512);
  int o_gbcomb = alloc(512);
  int o_gblx = alloc(384);
  int o_gbrx = alloc(384);
  int o_cnt  = alloc(SCAN_N);
  int o_rp   = alloc(SCAN_N);
  int o_woff = alloc(SCAN_N);
  int o_bsum = alloc(1024);
  int o_csr  = alloc(E_TOTAL);
  int o_part = alloc((size_t)22320*136);
  int o_aggS = alloc((size_t)1950*128);           // 5 buffers: 230,800,800,60,60 rows
  int o_outC0 = alloc(230*128);
  int o_outE2 = alloc(800*128);
  int o_outE7 = alloc(800*128);
  int o_outG4 = alloc(60*128);
  int o_outG6 = alloc(60*128);

  // bf16 buffers (ushort offsets)
  int u_bswz = allocU(573440);
  int u_xEb  = allocU(307200);
  int u_zC   = allocU(230*128);
  int u_zE   = allocU(800*128);
  int u_zG   = allocU(60*128);
  int u_sxC  = allocU(230*256);
  int u_sxE  = allocU(800*384);
  int u_sxG  = allocU(60*384);
  int u_yC   = allocU(230*128);
  int u_yE   = allocU(800*128);
  int u_yG   = allocU(60*128);
  int u_xl1  = allocU(230*128);
  int u_xl3  = allocU(800*128);
  int u_xl5  = allocU(60*128);
  int u_xl6  = allocU(800*128);
  int u_xl7  = allocU(60*128);
  int u_xr0  = allocU(230*128);
  int u_xr2  = allocU(800*128);
  int u_xr4  = allocU(60*128);
  int u_xr6  = allocU(60*128);
  int u_xr7  = allocU(800*128);
  int u_big0 = allocU((size_t)A_N*128);   // zA, then yA
  int u_bigH = allocU((size_t)A_N*128);   // hA, then outA
  int u_bigA = allocU((size_t)A_N*384);   // aggA, then gxl, then gxr

  if (off*4 > ws_size){
    ws_fail<<<1, 64, 0, stream>>>((float*)d_out, (float)((off*4) >> 20));
    return;
  }

  // swizzled-weight sub-offsets (within bswz)
  const int u_eAW2 = u_bswz + 0,      u_eCW2 = u_bswz + 16384;
  const int u_eEW2 = u_bswz + 32768,  u_eGW2 = u_bswz + 49152;
  const int u_eEW1 = u_bswz + 65536;
  const int u_sxAW = u_bswz + 114688, u_sxCW = u_bswz + 180224;
  const int u_sxEW = u_bswz + 212992, u_sxGW = u_bswz + 262144;
  const int u_gxlW = u_bswz + 311296, u_gxrW = u_bswz + 360448;
  int u_smW[10];
  for (int i = 0; i < 10; ++i) u_smW[i] = u_bswz + 409600 + i*16384;

  const int n_nodes[4] = {A_N, C_N, V_N, G_N};
  const int et_dst[8] = {1,0,2,0,3,0,3,2};
  const int et_ei[8]  = {4,4,5,5,6,6,7,7};
  const int et_rev[8] = {0,1,0,1,0,1,0,1};
  const int et_E[8]   = {100000,100000,500000,500000,300000,300000,2000,2000};

  const int* esp[8]; const int* edp[8]; int rowbase[8];
  {
    int rb = 0;
    for (int k = 0; k < 8; ++k){
      const int* ei = (const int*)d_in[et_ei[k]];
      int E = et_E[k];
      esp[k] = ei + (et_rev[k] ? E : 0);
      edp[k] = ei + (et_rev[k] ? 0 : E);
      rowbase[k] = rb; rb += n_nodes[et_dst[k]];
    }
  }
  int* rpb_p  = (int*)(wsf + o_rp);
  int* csr_p  = (int*)(wsf + o_csr);

  // ---------------- conversions / weight prep
  detect_dtype<<<1, 256, 0, stream>>>((const unsigned short*)d_in[2], flagp);
  convert_all<<<2048, 256, 0, stream>>>(tab, wsf, flagp, total);
  prep_combos<<<(4*16384 + 255)/256, 256, 0, stream>>>(wsf + coff[22], wsf + o_sbl,
      wsf + o_gbias, wsf + o_wrcomb, wsf + o_sbcomb, wsf + o_gbcomb);
  prep_bias2<<<2, 256, 0, stream>>>(wsf + o_gbl, wsf + o_gbr, wsf + o_gblx, wsf + o_gbrx);

  SwzTab st; int sn = 0, stotal = 0;
  auto push = [&](int src, int K, int dst, int nkc, int kc0, int nt0, float sc){
    st.d[sn++] = SwzD{src, dst, K, nkc, kc0, nt0, sc};
    stotal += K*128;
  };
  push(coff[6],  128, u_eAW2, 4, 0, 0, 1.f);
  push(coff[10], 128, u_eCW2, 4, 0, 0, 1.f);
  push(coff[14], 128, u_eEW2, 4, 0, 0, 1.f);
  push(coff[18], 128, u_eGW2, 4, 0, 0, 1.f);
  push(coff[12], 384, u_eEW1, 12, 0, 0, 1.f);
  push(o_wrcomb + 0,     128, u_sxAW, 16, 0,  0, 1.f);
  push(o_sWl + 1*16384,  128, u_sxAW, 16, 4,  0, 1.f/3.f);
  push(o_sWl + 3*16384,  128, u_sxAW, 16, 8,  0, 1.f/3.f);
  push(o_sWl + 5*16384,  128, u_sxAW, 16, 12, 0, 1.f/3.f);
  push(o_wrcomb + 16384, 128, u_sxCW, 8, 0, 0, 1.f);
  push(o_sWl + 0*16384,  128, u_sxCW, 8, 4, 0, 1.f);
  push(o_wrcomb + 32768, 128, u_sxEW, 12, 0, 0, 1.f);
  push(o_sWl + 2*16384,  128, u_sxEW, 12, 4, 0, 0.5f);
  push(o_sWl + 7*16384,  128, u_sxEW, 12, 8, 0, 0.5f);
  push(o_wrcomb + 49152, 128, u_sxGW, 12, 0, 0, 1.f);
  push(o_sWl + 4*16384,  128, u_sxGW, 12, 4, 0, 0.5f);
  push(o_sWl + 6*16384,  128, u_sxGW, 12, 8, 0, 0.5f);
  push(o_gWl + 0*16384, 128, u_gxlW, 4, 0, 0,  1.f);
  push(o_gWl + 2*16384, 128, u_gxlW, 4, 0, 8,  1.f);
  push(o_gWl + 4*16384, 128, u_gxlW, 4, 0, 16, 1.f);
  push(o_gWr + 1*16384, 128, u_gxrW, 4, 0, 0,  1.f);
  push(o_gWr + 3*16384, 128, u_gxrW, 4, 0, 8,  1.f);
  push(o_gWr + 5*16384, 128, u_gxrW, 4, 0, 16, 1.f);
  const int xlk[5] = {1,3,5,6,7};
  for (int i = 0; i < 5; ++i) push(o_gWl + xlk[i]*16384, 128, u_smW[i], 4, 0, 0, 1.f);
  const int xrk[5] = {0,2,4,6,7};
  for (int i = 0; i < 5; ++i) push(o_gWr + xrk[i]*16384, 128, u_smW[5+i], 4, 0, 0, 1.f);
  st.n = sn; st.total = stotal;
  swz_batch<<<(stotal + 255)/256, 256, 0, stream>>>(wsf, wsu, st);

  // ---------------- CSR build
  hipMemsetAsync(wsf + o_cnt, 0, (size_t)SCAN_N*4, stream);
  for (int k = 0; k < 8; ++k){
    int E = et_E[k], nd = n_nodes[et_dst[k]];
    if (nd <= 800)
      hist_lds<<<imin(256, (E + 255)/256), 256, 0, stream>>>(edp[k], E,
          (int*)(wsf + o_cnt) + rowbase[k], nd);
    else
      hist_plain<<<(E + 255)/256, 256, 0, stream>>>(edp[k], E,
          (int*)(wsf + o_cnt) + rowbase[k]);
  }
  scan1<<<SCAN_NB, 256, 0, stream>>>((int*)(wsf + o_cnt), rpb_p, (int*)(wsf + o_bsum));
  scan2<<<1, 512, 0, stream>>>((int*)(wsf + o_bsum));
  scan3<<<(SCAN_N + 255)/256, 256, 0, stream>>>(rpb_p, (int*)(wsf + o_woff),
                                                (int*)(wsf + o_bsum));
  for (int k = 0; k < 8; ++k){
    int E = et_E[k], nd = n_nodes[et_dst[k]];
    if (nd <= 800){
      int span = 256*PCHUNK;
      place_lds<<<imin(304, (E + span - 1)/span), 256, 0, stream>>>(
          esp[k], edp[k], E, (int*)(wsf + o_woff) + rowbase[k], csr_p, nd);
    } else {
      place_plain<<<(E + 255)/256, 256, 0, stream>>>(esp[k], edp[k], E,
          (int*)(wsf + o_woff) + rowbase[k], csr_p);
    }
  }

  // ---------------- encoders
  enc_l1<<<(A_N*128 + 255)/256, 256, 0, stream>>>(wsf + coff[0], wsf + coff[4],
      wsf + coff[5], wsu + u_big0, A_N, 7);
  enc_l1<<<(C_N*128 + 255)/256, 256, 0, stream>>>(wsf + coff[1], wsf + coff[8],
      wsf + coff[9], wsu + u_zC, C_N, 3);
  enc_l1<<<(G_N*128 + 255)/256, 256, 0, stream>>>(wsf + coff[3], wsf + coff[16],
      wsf + coff[17], wsu + u_zG, G_N, 2);
  cvt_bf16<<<(307200 + 255)/256, 256, 0, stream>>>(wsf + coff[2], wsu + u_xEb, 307200);

  GBTab e1; e1.n = 3;
  e1.d[0] = GB{u_zC, 128, u_eCW2, coff[11], u_sxC, 256, C_N, 4, 0};
  e1.d[1] = GB{u_xEb, 384, u_eEW1, coff[13], u_zE, 128, V_N, 12, FLAG_RELU};
  e1.d[2] = GB{u_zG, 128, u_eGW2, coff[19], u_sxG, 384, G_N, 4, 0};
  mfma_gemm_batch<<<3*13, 256, 0, stream>>>(d_ws, e1);
  GBTab e2; e2.n = 1;
  e2.d[0] = GB{u_zE, 128, u_eEW2, coff[15], u_sxE, 384, V_N, 4, 0};
  mfma_gemm_batch<<<13, 256, 0, stream>>>(d_ws, e2);
  // athlete l2: zA -> hA
  mfma_gemm<<<dim3((A_N + 63)/64, 1), 256, 0, stream>>>(d_ws, u_big0, 128, 0, 0, 1000,
      u_eAW2, 4, coff[7], u_bigH, 128, A_N, 0);

  // ---------------- SAGE layer
  sage_gather_athA<<<(A_N*64 + 255)/256, 256, 0, stream>>>(wsu, csr_p, rpb_p,
      u_sxC, u_sxE, u_sxG, rowbase[1], rowbase[3], rowbase[5], u_bigA);
  hipMemsetAsync(wsf + o_aggS, 0, (size_t)1950*128*4, stream);
  const int b0 = o_aggS, b2 = o_aggS + 230*128, b7 = b2 + 800*128,
            b4 = b7 + 800*128, b6 = b4 + 60*128;
  SgTab sg;
  sg.d[0] = SgD{u_bigH, 128, rowbase[0], b0, C_N, 8};
  sg.d[1] = SgD{u_bigH, 128, rowbase[2], b2, V_N, 8};
  sg.d[2] = SgD{u_sxG, 384, rowbase[7], b7, V_N, 8};
  sg.d[3] = SgD{u_bigH, 128, rowbase[4], b4, G_N, 64};
  sg.d[4] = SgD{u_sxE, 384, rowbase[6], b6, G_N, 64};
  sg.cumw[0] = 0;
  {
    int c = 0;
    for (int i = 0; i < 5; ++i){ c += sg.d[i].nd*sg.d[i].nc; sg.cumw[i+1] = c; }
  }
  sage_gather_small<<<(sg.cumw[5]*64 + 255)/256, 256, 0, stream>>>(wsu, wsf, csr_p, rpb_p, sg);
  AfTab af; af.n = 5;
  af.d[0] = AfD{b0, rowbase[0], u_sxC + 128, 256, C_N};
  af.d[1] = AfD{b2, rowbase[2], u_sxE + 128, 384, V_N};
  af.d[2] = AfD{b7, rowbase[7], u_sxE + 256, 384, V_N};
  af.d[3] = AfD{b4, rowbase[4], u_sxG + 128, 384, G_N};
  af.d[4] = AfD{b6, rowbase[6], u_sxG + 256, 384, G_N};
  int aftot = 1950*128;
  aggfin_batch<<<(aftot + 255)/256, 256, 0, stream>>>(wsu, wsf, rpb_p, af, aftot);
  GBTab sgm; sgm.n = 3;
  sgm.d[0] = GB{u_sxC, 256, u_sxCW, o_sbcomb + 128, u_yC, 128, C_N, 8,  FLAG_RELU};
  sgm.d[1] = GB{u_sxE, 384, u_sxEW, o_sbcomb + 256, u_yE, 128, V_N, 12, FLAG_RELU};
  sgm.d[2] = GB{u_sxG, 384, u_sxGW, o_sbcomb + 384, u_yG, 128, G_N, 12, FLAG_RELU};
  mfma_gemm_batch<<<3*13, 256, 0, stream>>>(d_ws, sgm);
  // SAGE athlete: [hA | aggA] @ sxAW -> yA (big0)
  mfma_gemm<<<dim3((A_N + 63)/64, 1), 256, 0, stream>>>(d_ws, u_bigH, 128, u_bigA, 384, 4,
      u_sxAW, 16, o_sbcomb, u_big0, 128, A_N, FLAG_RELU);

  // ---------------- GAT layer
  // gxl = yA @ [gWl0|gWl2|gWl4] -> bigA (aggA dead)
  mfma_gemm<<<dim3((A_N + 63)/64, 3), 256, 0, stream>>>(d_ws, u_big0, 128, 0, 0, 1000,
      u_gxlW, 4, o_gblx, u_bigA, 384, A_N, 0);
  GBTab gm; gm.n = 10;
  gm.d[0] = GB{u_yC, 128, u_smW[0], o_gbl + 1*128, u_xl1, 128, C_N, 4, 0};
  gm.d[1] = GB{u_yE, 128, u_smW[1], o_gbl + 3*128, u_xl3, 128, V_N, 4, 0};
  gm.d[2] = GB{u_yG, 128, u_smW[2], o_gbl + 5*128, u_xl5, 128, G_N, 4, 0};
  gm.d[3] = GB{u_yE, 128, u_smW[3], o_gbl + 6*128, u_xl6, 128, V_N, 4, 0};
  gm.d[4] = GB{u_yG, 128, u_smW[4], o_gbl + 7*128, u_xl7, 128, G_N, 4, 0};
  gm.d[5] = GB{u_yC, 128, u_smW[5], o_gbr + 0*128, u_xr0, 128, C_N, 4, 0};
  gm.d[6] = GB{u_yE, 128, u_smW[6], o_gbr + 2*128, u_xr2, 128, V_N, 4, 0};
  gm.d[7] = GB{u_yG, 128, u_smW[7], o_gbr + 4*128, u_xr4, 128, G_N, 4, 0};
  gm.d[8] = GB{u_yG, 128, u_smW[8], o_gbr + 6*128, u_xr6, 128, G_N, 4, 0};
  gm.d[9] = GB{u_yE, 128, u_smW[9], o_gbr + 7*128, u_xr7, 128, V_N, 4, 0};
  mfma_gemm_batch<<<10*13, 256, 0, stream>>>(d_ws, gm);

  GoTab go;
  go.d[0] = GoD{u_bigA + 0,   384, u_xr0, o_gatt + 0*128, rowbase[0], 0,     C_N, 8};
  go.d[1] = GoD{u_bigA + 128, 384, u_xr2, o_gatt + 2*128, rowbase[2], 1840,  V_N, 8};
  go.d[2] = GoD{u_bigA + 256, 384, u_xr4, o_gatt + 4*128, rowbase[4], 8240,  G_N, 64};
  go.d[3] = GoD{u_xl6, 128,        u_xr6, o_gatt + 6*128, rowbase[6], 12080, G_N, 64};
  go.d[4] = GoD{u_xl7, 128,        u_xr7, o_gatt + 7*128, rowbase[7], 15920, V_N, 8};
  go.cumw[0] = 0;
  {
    int c = 0;
    for (int i = 0; i < 5; ++i){ c += go.d[i].nd*go.d[i].nc; go.cumw[i+1] = c; }
  }
  gat_online_batch<<<(go.cumw[5]*64 + 255)/256, 256, 0, stream>>>(wsu, wsf, csr_p, rpb_p,
      wsf + o_part, go);

  // gxr = yA @ [gWr1|gWr3|gWr5] -> bigA (gxl dead after gat_online_batch)
  mfma_gemm<<<dim3((A_N + 63)/64, 3), 256, 0, stream>>>(d_ws, u_big0, 128, 0, 0, 1000,
      u_gxrW, 4, o_gbrx, u_bigA, 384, A_N, 0);
  gat_ath<<<(A_N*64 + 255)/256, 256, 0, stream>>>(wsu, wsf, csr_p, rpb_p,
      u_bigA, u_xl1, u_xl3, u_xl5, o_gatt, rowbase[1], rowbase[3], rowbase[5], u_bigH);

  MgTab mg;
  mg.d[0] = MgD{0,     o_outC0, C_N, 8,  1.0f};
  mg.d[1] = MgD{1840,  o_outE2, V_N, 8,  0.5f};
  mg.d[2] = MgD{8240,  o_outG4, G_N, 64, 0.5f};
  mg.d[3] = MgD{12080, o_outG6, G_N, 64, 0.5f};
  mg.d[4] = MgD{15920, o_outE7, V_N, 8,  0.5f};
  mg.cumw[0] = 0;
  {
    int c = 0;
    for (int i = 0; i < 5; ++i){ c += mg.d[i].nd; mg.cumw[i+1] = c; }
  }
  gat_merge_batch<<<(mg.cumw[5]*64 + 255)/256, 256, 0, stream>>>(wsf + o_part, wsf, mg);

  final_out<<<(101090*128 + 255)/256, 256, 0, stream>>>(wsu, wsf, u_bigH,
      o_outC0, o_outE2, o_outE7, o_outG4, o_outG6, o_gbcomb, flagp, d_out);
}

// Round 6
// 1021.031 us; speedup vs baseline: 8.8884x; 1.0709x over previous
//
#include <hip/hip_runtime.h>
#include <hip/hip_bf16.h>

#define A_N 100000
#define C_N 230
#define V_N 800
#define G_N 60

#define FLAG_RELU 2

#define SCAN_N   302080          // 295 * 1024 (padded row-count over 8 relations)
#define SCAN_NB  295
#define E_TOTAL  1804000

#define PCHUNK 16

typedef __attribute__((ext_vector_type(8))) short short8;
typedef __attribute__((ext_vector_type(4))) float f32x4;

__device__ __forceinline__ float bf16dec(unsigned short u){
  return __uint_as_float(((unsigned)u) << 16);
}
__device__ __forceinline__ unsigned short f2b(float v){
  union { __hip_bfloat16 h; unsigned short u; } c;
  c.h = __float2bfloat16(v);
  return c.u;
}
__device__ __forceinline__ float4 ldb4(const unsigned short* p){
  uint2 v = *(const uint2*)p;
  float4 r;
  r.x = __uint_as_float(v.x << 16);
  r.y = __uint_as_float(v.x & 0xffff0000u);
  r.z = __uint_as_float(v.y << 16);
  r.w = __uint_as_float(v.y & 0xffff0000u);
  return r;
}
static inline int imin(int a, int b){ return a < b ? a : b; }

// ---------------------------------------------------------------- detect dtype
__global__ void detect_dtype(const unsigned short* __restrict__ p, int* __restrict__ flag){
  __shared__ int bad;
  if (threadIdx.x == 0) bad = 0;
  __syncthreads();
  for (int i = threadIdx.x; i < 2048; i += blockDim.x){
    float v = fabsf(bf16dec(p[i]));
    if (!(v <= 1e6f)) atomicOr(&bad, 1);
  }
  __syncthreads();
  if (threadIdx.x == 0) *flag = bad;       // 1 => inputs stored as fp32
}

// ---------------------------------------------------------------- convert all
struct ConvTab { const void* src[29]; int dstoff[29]; int cum[30]; };

__global__ void convert_all(ConvTab tab, float* __restrict__ wsf,
                            const int* __restrict__ flagp, int total){
  const int f = *flagp;
  for (int idx = blockIdx.x*blockDim.x + threadIdx.x; idx < total;
       idx += gridDim.x*blockDim.x){
    int t = 0;
    while (idx >= tab.cum[t+1]) ++t;
    int l = idx - tab.cum[t];
    float v = f ? ((const float*)tab.src[t])[l]
                : bf16dec(((const unsigned short*)tab.src[t])[l]);
    wsf[tab.dstoff[t] + l] = v;
  }
}

// ---------------------------------------------------------------- prep combos (+ gat bias concat)
__global__ void prep_combos(const float* __restrict__ sWr, const float* __restrict__ sbl,
                            const float* __restrict__ gbias,
                            const float* __restrict__ gbl, const float* __restrict__ gbr,
                            float* __restrict__ wrcomb, float* __restrict__ sbcomb,
                            float* __restrict__ gbcomb,
                            float* __restrict__ gblx, float* __restrict__ gbrx){
  const int sets[4][3] = {{1,3,5},{0,-1,-1},{2,7,-1},{4,6,-1}};
  const float inv[4] = {1.f/3.f, 1.f, 0.5f, 0.5f};
  int idx = blockIdx.x*blockDim.x + threadIdx.x;
  if (idx >= 4*16384) return;
  int t = idx >> 14, j = idx & 16383;
  float s = 0.f;
  #pragma unroll
  for (int q = 0; q < 3; ++q){
    int k = sets[t][q];
    if (k >= 0) s += sWr[k*16384 + j];
  }
  wrcomb[idx] = s * inv[t];
  if (j < 128){
    float b1 = 0.f, b2 = 0.f;
    #pragma unroll
    for (int q = 0; q < 3; ++q){
      int k = sets[t][q];
      if (k >= 0){ b1 += sbl[k*128 + j]; b2 += gbias[k*128 + j]; }
    }
    sbcomb[t*128 + j] = b1 * inv[t];
    gbcomb[t*128 + j] = b2 * inv[t];
  }
  if (idx < 384){
    const int kl[3] = {0,2,4}, kr[3] = {1,3,5};
    int rel = idx >> 7, jj = idx & 127;
    gblx[idx] = gbl[kl[rel]*128 + jj];
    gbrx[idx] = gbr[kr[rel]*128 + jj];
  }
}

// ---------------------------------------------------------------- weight swizzle
struct SwzD { int src, dst, K, nkc, kc0, nt0; float scale; };
struct SwzTab { SwzD d[33]; int n, total; };

__global__ void swz_batch(const float* __restrict__ wsf, unsigned short* __restrict__ wsu,
                          SwzTab t){
  for (int idx = blockIdx.x*blockDim.x + threadIdx.x; idx < t.total;
       idx += gridDim.x*blockDim.x){
    int di = 0, local = idx;
    while (local >= t.d[di].K*128){ local -= t.d[di].K*128; ++di; }
    SwzD d = t.d[di];
    int j = local & 7, lane = (local>>3) & 63, rest = local >> 9;
    int kcn = d.K >> 5;
    int kc = rest % kcn, nt = rest / kcn;
    int k = kc*32 + (lane>>4)*8 + j;
    int n = nt*16 + (lane&15);
    float v = wsf[d.src + k*128 + n] * d.scale;
    wsu[(size_t)d.dst + ((size_t)((d.nt0+nt)*d.nkc + d.kc0+kc)*64 + lane)*8 + j] = f2b(v);
  }
}

// ---------------------------------------------------------------- CSR build (merged)
struct HTab {
  const int* dp[8];
  int E[8], cntoff[8], ndst[8], mode[8], bstart[9];
};

__global__ void hist_all(HTab t, int* __restrict__ cnt){
  __shared__ int l[800];
  int k = 0;
  while ((int)blockIdx.x >= t.bstart[k+1]) ++k;
  int lb = blockIdx.x - t.bstart[k], nb = t.bstart[k+1] - t.bstart[k];
  const int* dp = t.dp[k];
  int E = t.E[k];
  int* c = cnt + t.cntoff[k];
  if (t.mode[k]){
    int nd = t.ndst[k];
    for (int i = threadIdx.x; i < nd; i += blockDim.x) l[i] = 0;
    __syncthreads();
    for (int i = lb*blockDim.x + threadIdx.x; i < E; i += nb*blockDim.x)
      atomicAdd(&l[dp[i]], 1);
    __syncthreads();
    for (int i = threadIdx.x; i < nd; i += blockDim.x)
      if (l[i]) atomicAdd(&c[i], l[i]);
  } else {
    for (int i = lb*blockDim.x + threadIdx.x; i < E; i += nb*blockDim.x)
      atomicAdd(&c[dp[i]], 1);
  }
}

struct PTab {
  const int* sp[8]; const int* dp[8];
  int E[8], woffoff[8], ndst[8], mode[8], bstart[9];
};

__global__ void place_all(PTab t, int* __restrict__ woffb, int* __restrict__ csr){
  __shared__ int lcnt[800];
  __shared__ int lbase[800];
  int k = 0;
  while ((int)blockIdx.x >= t.bstart[k+1]) ++k;
  int lb = blockIdx.x - t.bstart[k], nb = t.bstart[k+1] - t.bstart[k];
  const int* sp = t.sp[k];
  const int* dp = t.dp[k];
  int E = t.E[k];
  int* woff = woffb + t.woffoff[k];
  const int tid = threadIdx.x;
  if (t.mode[k]){
    int nd = t.ndst[k];
    const int span = blockDim.x * PCHUNK;
    for (int b0 = lb*span; b0 < E; b0 += nb*span){
      for (int i = tid; i < nd; i += blockDim.x) lcnt[i] = 0;
      __syncthreads();
      int d[PCHUNK], s[PCHUNK], r[PCHUNK];
      #pragma unroll
      for (int j = 0; j < PCHUNK; ++j){
        int e = b0 + j*blockDim.x + tid;
        d[j] = -1;
        if (e < E){
          s[j] = sp[e];
          d[j] = dp[e];
          r[j] = atomicAdd(&lcnt[d[j]], 1);
        }
      }
      __syncthreads();
      for (int i = tid; i < nd; i += blockDim.x){
        int c = lcnt[i];
        if (c) lbase[i] = atomicAdd(&woff[i], c);
      }
      __syncthreads();
      #pragma unroll
      for (int j = 0; j < PCHUNK; ++j)
        if (d[j] >= 0) csr[lbase[d[j]] + r[j]] = s[j];
      __syncthreads();
    }
  } else {
    for (int i = lb*blockDim.x + tid; i < E; i += nb*blockDim.x){
      int pos = atomicAdd(&woff[dp[i]], 1);
      csr[pos] = sp[i];
    }
  }
}

__global__ void scan1(const int* __restrict__ cnt, int* __restrict__ rp, int* __restrict__ bsum){
  __shared__ int sd[256];
  int tid = threadIdx.x, blk = blockIdx.x;
  int base = blk*1024 + tid*4;
  int4 v = *(const int4*)(cnt + base);
  int s = v.x + v.y + v.z + v.w;
  sd[tid] = s;
  __syncthreads();
  for (int off = 1; off < 256; off <<= 1){
    int t = (tid >= off) ? sd[tid-off] : 0;
    __syncthreads();
    sd[tid] += t;
    __syncthreads();
  }
  int excl = sd[tid] - s;
  rp[base+0] = excl;
  rp[base+1] = excl + v.x;
  rp[base+2] = excl + v.x + v.y;
  rp[base+3] = excl + v.x + v.y + v.z;
  if (tid == 255) bsum[blk] = sd[255];
}

__global__ void scan2(int* __restrict__ bsum){
  __shared__ int sd[512];
  int tid = threadIdx.x;
  int v = (tid < SCAN_NB) ? bsum[tid] : 0;
  sd[tid] = v;
  __syncthreads();
  for (int off = 1; off < 512; off <<= 1){
    int t = (tid >= off) ? sd[tid-off] : 0;
    __syncthreads();
    sd[tid] += t;
    __syncthreads();
  }
  if (tid < SCAN_NB) bsum[tid] = sd[tid] - v;
}

__global__ void scan3(int* __restrict__ rp, int* __restrict__ woff,
                      const int* __restrict__ bsum){
  int idx = blockIdx.x*blockDim.x + threadIdx.x;
  if (idx >= SCAN_N) return;
  int v = rp[idx] + bsum[idx >> 10];
  rp[idx] = v;
  woff[idx] = v;
}

// ---------------------------------------------------------------- merged encoders
struct EncTab {
  int cum[5];
  int xoff[4], woff[4], boff[4], zoff[4], K[4];
};

__global__ void enc_batch(const float* __restrict__ wsf, unsigned short* __restrict__ wsu,
                          EncTab t){
  for (int idx = blockIdx.x*blockDim.x + threadIdx.x; idx < t.cum[4];
       idx += gridDim.x*blockDim.x){
    int s = 0;
    while (idx >= t.cum[s+1]) ++s;
    int local = idx - t.cum[s];
    if (s < 3){
      int r = local >> 7, c = local & 127;
      int K = t.K[s];
      float acc = wsf[t.boff[s] + c];
      for (int k = 0; k < K; ++k)
        acc = fmaf(wsf[t.xoff[s] + r*K + k], wsf[t.woff[s] + (k<<7) + c], acc);
      wsu[(size_t)t.zoff[s] + (size_t)r*128 + c] = f2b(fmaxf(acc, 0.f));
    } else {
      wsu[(size_t)t.zoff[3] + local] = f2b(wsf[t.xoff[3] + local]);
    }
  }
}

// ---------------------------------------------------------------- MFMA GEMM
__device__ __forceinline__ void mfma_core(
    const unsigned short* __restrict__ wsu, const float* __restrict__ wsf,
    int xoff, int xstride, int x2off, int x2stride, int kcsplit,
    int woff, int nkc, int biasoff, int yoff, int ystride,
    int M, int flags, int mblk, int nblk)
{
  int tid = threadIdx.x;
  int wv = tid >> 6, lane = tid & 63;
  int quad = lane >> 4, ml = lane & 15;
  int m0 = mblk*64 + wv*16;
  if (m0 >= M) return;
  int arow = m0 + ml;
  bool rowok = arow < M;
  f32x4 acc[8];
  #pragma unroll
  for (int i = 0; i < 8; ++i) acc[i] = (f32x4){0.f, 0.f, 0.f, 0.f};
  for (int kc = 0; kc < nkc; ++kc){
    short8 a = (short8){0,0,0,0,0,0,0,0};
    if (rowok){
      size_t ao = (kc < kcsplit)
        ? (size_t)xoff  + (size_t)arow*xstride  + kc*32 + quad*8
        : (size_t)x2off + (size_t)arow*x2stride + (kc - kcsplit)*32 + quad*8;
      a = *(const short8*)(wsu + ao);
    }
    size_t wbase = (size_t)woff + ((size_t)(nblk*8)*nkc + kc)*512 + lane*8;
    #pragma unroll
    for (int nt = 0; nt < 8; ++nt){
      short8 b = *(const short8*)(wsu + wbase + (size_t)nt*nkc*512);
      acc[nt] = __builtin_amdgcn_mfma_f32_16x16x32_bf16(a, b, acc[nt], 0, 0, 0);
    }
  }
  #pragma unroll
  for (int nt = 0; nt < 8; ++nt){
    int col = nblk*128 + nt*16 + ml;
    float bv = (biasoff >= 0) ? wsf[biasoff + col] : 0.f;
    #pragma unroll
    for (int r = 0; r < 4; ++r){
      int orow = m0 + quad*4 + r;
      if (orow < M){
        float v = acc[nt][r] + bv;
        if (flags & FLAG_RELU) v = fmaxf(v, 0.f);
        *((unsigned short*)wsu + (size_t)yoff + (size_t)orow*ystride + col) = f2b(v);
      }
    }
  }
}

struct GB2 { int xoff, xstride, x2off, x2stride, kcsplit, woff, nkc, biasoff,
             yoff, ystride, M, flags, nblk; };
struct GB2Tab { GB2 d[13]; int b0[14]; int n; };

__global__ __launch_bounds__(256) void mfma_gemm_b2(void* ws, GB2Tab t){
  int b = blockIdx.x, di = 0;
  while (b >= t.b0[di+1]) ++di;
  GB2 g = t.d[di];
  mfma_core((const unsigned short*)ws, (const float*)ws, g.xoff, g.xstride,
            g.x2off, g.x2stride, g.kcsplit, g.woff, g.nkc, g.biasoff,
            g.yoff, g.ystride, g.M, g.flags, b - t.b0[di], g.nblk);
}

// ---------------------------------------------------------------- SAGE gathers (merged)
struct SgD { int src, sstr, rpoff, aggoff, nd, nc; };
struct SgTab { SgD d[5]; int cumw[6]; };

__global__ void sage_all(const unsigned short* __restrict__ wsu, float* __restrict__ wsf,
    const int* __restrict__ csr, const int* __restrict__ rpb, SgTab t,
    int uhC, int uhE, int uhG, int rp1, int rp3, int rp5, int uagg)
{
  int gid = (blockIdx.x*blockDim.x + threadIdx.x) >> 6;
  int lane = threadIdx.x & 63;
  int half = lane >> 5, sub = lane & 31, f = sub*4;
  if (gid < A_N){
    // athlete-dst: wave per row, 3 relations, mean -> bf16 aggA slices
    int srcs[3] = {uhC, uhE, uhG};
    int sstr[3] = {256, 384, 384};
    int rps[3]  = {rp1, rp3, rp5};
    #pragma unroll
    for (int rel = 0; rel < 3; ++rel){
      const unsigned short* base = wsu + (size_t)srcs[rel] + f;
      int str = sstr[rel];
      int st = rpb[rps[rel] + gid], en = rpb[rps[rel] + gid + 1];
      float4 acc = {0.f, 0.f, 0.f, 0.f};
      int i = st + half;
      for (; i + 2 < en; i += 4){
        int s0 = csr[i], s1 = csr[i+2];
        float4 v0 = ldb4(base + (size_t)s0*str);
        float4 v1 = ldb4(base + (size_t)s1*str);
        acc.x += v0.x + v1.x; acc.y += v0.y + v1.y;
        acc.z += v0.z + v1.z; acc.w += v0.w + v1.w;
      }
      if (i < en){
        float4 v0 = ldb4(base + (size_t)csr[i]*str);
        acc.x += v0.x; acc.y += v0.y; acc.z += v0.z; acc.w += v0.w;
      }
      acc.x += __shfl_xor(acc.x, 32); acc.y += __shfl_xor(acc.y, 32);
      acc.z += __shfl_xor(acc.z, 32); acc.w += __shfl_xor(acc.w, 32);
      if (half == 0){
        int deg = en - st;
        float sc = 1.f / (float)(deg > 1 ? deg : 1);
        ushort4 o;
        o.x = f2b(acc.x*sc); o.y = f2b(acc.y*sc);
        o.z = f2b(acc.z*sc); o.w = f2b(acc.w*sc);
        *(ushort4*)((unsigned short*)wsu + (size_t)uagg + (size_t)gid*384 + rel*128 + f) = o;
      }
    }
  } else {
    int wid = gid - A_N;
    if (wid >= t.cumw[5]) return;
    int di = 0;
    while (wid >= t.cumw[di+1]) ++di;
    SgD d = t.d[di];
    int local = wid - t.cumw[di];
    int row = local / d.nc, c = local - row*d.nc;
    const unsigned short* base = wsu + (size_t)d.src + f;
    int st = rpb[d.rpoff + row], en = rpb[d.rpoff + row + 1];
    float4 acc = {0.f, 0.f, 0.f, 0.f};
    int i = st + c + half*d.nc;
    int step = 2*d.nc;
    for (; i + step < en; i += 2*step){
      int s0 = csr[i], s1 = csr[i+step];
      float4 v0 = ldb4(base + (size_t)s0*d.sstr);
      float4 v1 = ldb4(base + (size_t)s1*d.sstr);
      acc.x += v0.x + v1.x; acc.y += v0.y + v1.y;
      acc.z += v0.z + v1.z; acc.w += v0.w + v1.w;
    }
    if (i < en){
      float4 v0 = ldb4(base + (size_t)csr[i]*d.sstr);
      acc.x += v0.x; acc.y += v0.y; acc.z += v0.z; acc.w += v0.w;
    }
    acc.x += __shfl_xor(acc.x, 32); acc.y += __shfl_xor(acc.y, 32);
    acc.z += __shfl_xor(acc.z, 32); acc.w += __shfl_xor(acc.w, 32);
    if (half == 0){
      float* o = wsf + (size_t)d.aggoff + (size_t)row*128 + f;
      atomicAdd(o,   acc.x); atomicAdd(o+1, acc.y);
      atomicAdd(o+2, acc.z); atomicAdd(o+3, acc.w);
    }
  }
}

struct AfD { int aggoff, rpoff, dstu, dstr, nd; };
struct AfTab { AfD d[5]; int n; };

__global__ void aggfin_batch(unsigned short* __restrict__ wsu, const float* __restrict__ wsf,
                             const int* __restrict__ rpb, AfTab t, int total){
  int idx = blockIdx.x*blockDim.x + threadIdx.x;
  if (idx >= total) return;
  int di = 0, local = idx;
  while (local >= t.d[di].nd*128){ local -= t.d[di].nd*128; ++di; }
  AfD d = t.d[di];
  int row = local >> 7, col = local & 127;
  int deg = rpb[d.rpoff + row + 1] - rpb[d.rpoff + row];
  float sc = 1.f / (float)(deg > 1 ? deg : 1);
  wsu[(size_t)d.dstu + (size_t)row*d.dstr + col] = f2b(wsf[(size_t)d.aggoff + local] * sc);
}

// ---------------------------------------------------------------- GATv2 edge kernels
// 32 lanes/edge. Pair update: one shared rescale + 3 exps per 2 edges.
#define GAT_LOGIT(xv, pout)                                                \
  {                                                                        \
    float e0 = (xv).x + xrv.x, e1 = (xv).y + xrv.y;                        \
    float e2 = (xv).z + xrv.z, e3 = (xv).w + xrv.w;                        \
    e0 = e0 > 0.f ? e0 : 0.2f*e0; e1 = e1 > 0.f ? e1 : 0.2f*e1;            \
    e2 = e2 > 0.f ? e2 : 0.2f*e2; e3 = e3 > 0.f ? e3 : 0.2f*e3;            \
    pout = e0*av.x + e1*av.y + e2*av.z + e3*av.w;                          \
    pout += __shfl_xor(pout, 1); pout += __shfl_xor(pout, 2);              \
    pout += __shfl_xor(pout, 4);                                           \
  }

#define GAT_UPD(xv)                                                        \
  {                                                                        \
    float p;                                                               \
    GAT_LOGIT(xv, p);                                                      \
    float nm = fmaxf(m, p);                                                \
    float scw = __expf(m - nm);                                            \
    float pe = __expf(p - nm);                                             \
    l = l*scw + pe;                                                        \
    acc.x = acc.x*scw + pe*(xv).x; acc.y = acc.y*scw + pe*(xv).y;          \
    acc.z = acc.z*scw + pe*(xv).z; acc.w = acc.w*scw + pe*(xv).w;          \
    m = nm;                                                                \
  }

#define GAT_UPD2(x0, x1)                                                   \
  {                                                                        \
    float p0, p1;                                                          \
    GAT_LOGIT(x0, p0);                                                     \
    GAT_LOGIT(x1, p1);                                                     \
    float nm = fmaxf(m, fmaxf(p0, p1));                                    \
    float scw = __expf(m - nm);                                            \
    float pe0 = __expf(p0 - nm);                                           \
    float pe1 = __expf(p1 - nm);                                           \
    l = l*scw + pe0 + pe1;                                                 \
    acc.x = acc.x*scw + pe0*(x0).x + pe1*(x1).x;                           \
    acc.y = acc.y*scw + pe0*(x0).y + pe1*(x1).y;                           \
    acc.z = acc.z*scw + pe0*(x0).z + pe1*(x1).z;                           \
    acc.w = acc.w*scw + pe0*(x0).w + pe1*(x1).w;                           \
    m = nm;                                                                \
  }

#define GAT_MERGE_HALVES                                                   \
  {                                                                        \
    float mo = __shfl_xor(m, 32);                                          \
    float lo = __shfl_xor(l, 32);                                          \
    float4 ao;                                                             \
    ao.x = __shfl_xor(acc.x, 32); ao.y = __shfl_xor(acc.y, 32);            \
    ao.z = __shfl_xor(acc.z, 32); ao.w = __shfl_xor(acc.w, 32);            \
    float nm = fmaxf(m, mo);                                               \
    float w  = (m  == -INFINITY) ? 0.f : __expf(m  - nm);                  \
    float wo = (mo == -INFINITY) ? 0.f : __expf(mo - nm);                  \
    l = l*w + lo*wo;                                                       \
    acc.x = acc.x*w + ao.x*wo; acc.y = acc.y*w + ao.y*wo;                  \
    acc.z = acc.z*w + ao.z*wo; acc.w = acc.w*w + ao.w*wo;                  \
    m = nm;                                                                \
  }

// fused athlete-dst (k=1,3,5)
__global__ void gat_ath(const unsigned short* __restrict__ wsu, const float* __restrict__ wsf,
    const int* __restrict__ csr, const int* __restrict__ rpb,
    int ugxr, int uxl1, int uxl3, int uxl5, int oatt, int rp1, int rp3, int rp5, int uout)
{
  int gid = (blockIdx.x*blockDim.x + threadIdx.x) >> 6;
  if (gid >= A_N) return;
  int lane = threadIdx.x & 63;
  int half = lane >> 5, sub = lane & 31, f = sub*4;
  int xls[3] = {uxl1, uxl3, uxl5};
  int rps[3] = {rp1, rp3, rp5};
  const int attk[3] = {1, 3, 5};
  float4 oacc = {0.f, 0.f, 0.f, 0.f};
  #pragma unroll
  for (int rel = 0; rel < 3; ++rel){
    float4 xrv = ldb4(wsu + (size_t)ugxr + (size_t)gid*384 + rel*128 + f);
    float4 av  = *(const float4*)(wsf + oatt + attk[rel]*128 + f);
    const unsigned short* base = wsu + (size_t)xls[rel] + f;
    int st = rpb[rps[rel] + gid], en = rpb[rps[rel] + gid + 1];
    float m = -INFINITY, l = 0.f;
    float4 acc = {0.f, 0.f, 0.f, 0.f};
    int i = st + half;
    for (; i + 2 < en; i += 4){
      int s0 = csr[i], s1 = csr[i+2];
      float4 x0 = ldb4(base + (size_t)s0*128);
      float4 x1 = ldb4(base + (size_t)s1*128);
      GAT_UPD2(x0, x1);
    }
    if (i < en){
      float4 x0 = ldb4(base + (size_t)csr[i]*128);
      GAT_UPD(x0);
    }
    GAT_MERGE_HALVES;
    float inv = 1.f / (l + 1e-16f);
    oacc.x += acc.x * inv; oacc.y += acc.y * inv;
    oacc.z += acc.z * inv; oacc.w += acc.w * inv;
  }
  if (half == 0){
    ushort4 o;
    o.x = f2b(oacc.x * (1.f/3.f)); o.y = f2b(oacc.y * (1.f/3.f));
    o.z = f2b(oacc.z * (1.f/3.f)); o.w = f2b(oacc.w * (1.f/3.f));
    *(ushort4*)((unsigned short*)wsu + (size_t)uout + (size_t)gid*128 + f) = o;
  }
}

// small-dst relations (k=0,2,4,6,7) -> partials
struct GoD { int xl, xlstr, xr, attoff, rpoff, prefix, nd, nc; };
struct GoTab { GoD d[5]; int cumw[6]; };

__global__ void gat_online_batch(const unsigned short* __restrict__ wsu,
    const float* __restrict__ wsf, const int* __restrict__ csr,
    const int* __restrict__ rpb, float* __restrict__ part, GoTab t)
{
  int gid = (blockIdx.x*blockDim.x + threadIdx.x) >> 6;
  if (gid >= t.cumw[5]) return;
  int di = 0;
  while (gid >= t.cumw[di+1]) ++di;
  GoD d = t.d[di];
  int local = gid - t.cumw[di];
  int row = local / d.nc, c = local - row*d.nc;
  int lane = threadIdx.x & 63;
  int half = lane >> 5, sub = lane & 31, f = sub*4, h = sub >> 3;
  float4 xrv = ldb4(wsu + (size_t)d.xr + (size_t)row*128 + f);
  float4 av  = *(const float4*)(wsf + d.attoff + f);
  const unsigned short* base = wsu + (size_t)d.xl + f;
  int st = rpb[d.rpoff + row], en = rpb[d.rpoff + row + 1];
  float m = -INFINITY, l = 0.f;
  float4 acc = {0.f, 0.f, 0.f, 0.f};
  int i = st + c + half*d.nc;
  int step = 2*d.nc;
  for (; i + step < en; i += 2*step){
    int s0 = csr[i], s1 = csr[i+step];
    float4 x0 = ldb4(base + (size_t)s0*d.xlstr);
    float4 x1 = ldb4(base + (size_t)s1*d.xlstr);
    GAT_UPD2(x0, x1);
  }
  if (i < en){
    float4 x0 = ldb4(base + (size_t)csr[i]*d.xlstr);
    GAT_UPD(x0);
  }
  GAT_MERGE_HALVES;
  if (half == 0){
    float* pr = part + (size_t)(d.prefix + local)*136;
    if ((sub & 7) == 0){ pr[h] = m; pr[4+h] = l; }
    *(float4*)(pr + 8 + f) = acc;
  }
}

struct MgD { int prefix, outoff, nd, nc; float invS; };
struct MgTab { MgD d[5]; int cumw[6]; };

__global__ void gat_merge_batch(const float* __restrict__ part, float* __restrict__ wsf,
                                MgTab t){
  int gid = (blockIdx.x*blockDim.x + threadIdx.x) >> 6;
  if (gid >= t.cumw[5]) return;
  int di = 0;
  while (gid >= t.cumw[di+1]) ++di;
  MgD d = t.d[di];
  int row = gid - t.cumw[di];
  int lane = threadIdx.x & 63, f = lane*2, h = lane >> 4;
  float M = -INFINITY;
  for (int c = 0; c < d.nc; ++c)
    M = fmaxf(M, part[(size_t)(d.prefix + row*d.nc + c)*136 + h]);
  float L = 0.f;
  float2 acc = {0.f, 0.f};
  for (int c = 0; c < d.nc; ++c){
    const float* pr = part + (size_t)(d.prefix + row*d.nc + c)*136;
    float mc = pr[h];
    float w = (mc == -INFINITY) ? 0.f : __expf(mc - M);
    L += pr[4+h] * w;
    acc.x += pr[8+f]   * w;
    acc.y += pr[8+f+1] * w;
  }
  float inv = d.invS / (L + 1e-16f);
  float* o = wsf + (size_t)d.outoff + (size_t)row*128 + f;
  o[0] = acc.x * inv;
  o[1] = acc.y * inv;
}

// ---------------------------------------------------------------- final output
__global__ void final_out(const unsigned short* __restrict__ wsu,
  const float* __restrict__ wsf, int uoutA, int oC0, int oE2, int oE7, int oG4, int oG6,
  int ogb, const int* __restrict__ flagp, void* __restrict__ dout)
{
  const int fl = *flagp;
  int idx = blockIdx.x*blockDim.x + threadIdx.x;
  const int total = 101090*128;
  if (idx >= total) return;
  int row = idx >> 7, c = idx & 127;
  float v; int t;
  if (row < A_N){ v = bf16dec(wsu[(size_t)uoutA + idx]); t = 0; }
  else if (row < A_N + C_N){ v = wsf[oC0 + (row - A_N)*128 + c]; t = 1; }
  else if (row < A_N + C_N + V_N){
    int l = (row - A_N - C_N)*128 + c;
    v = wsf[oE2 + l] + wsf[oE7 + l]; t = 2;
  } else {
    int l = (row - A_N - C_N - V_N)*128 + c;
    v = wsf[oG4 + l] + wsf[oG6 + l]; t = 3;
  }
  v += wsf[ogb + t*128 + c];
  if (fl) ((float*)dout)[idx] = v;
  else    ((__hip_bfloat16*)dout)[idx] = __float2bfloat16(v);
}

__global__ void ws_fail(float* __restrict__ out, float mb){
  if (threadIdx.x == 0 && blockIdx.x == 0) out[0] = mb;
}

// ================================================================ host
extern "C" void kernel_launch(void* const* d_in, const int* in_sizes, int n_in,
                              void* d_out, int out_size, void* d_ws, size_t ws_size,
                              hipStream_t stream)
{
  float* wsf = (float*)d_ws;
  unsigned short* wsu = (unsigned short*)d_ws;
  int* flagp = (int*)d_ws;
  size_t off = 16;
  auto alloc = [&](size_t n){ size_t o = off; off += (n + 15) & ~(size_t)15; return (int)o; };
  auto allocU = [&](size_t nu){ return 2*alloc((nu + 1)/2); };  // returns ushort offset

  static const int conv_in_idx[29] = {0,1,2,3, 8,9,10,11, 12,13,14,15, 16,17,18,19,
                                      20,21,22,23, 24,25,26, 27,28,29,30,31,32};
  static const int conv_n[29] = {700000,690,307200,120,
                                 896,128,16384,128, 384,128,16384,128,
                                 49152,128,16384,128, 256,128,16384,128,
                                 131072,1024,131072, 131072,1024,131072,1024,1024,1024};
  ConvTab tab;
  int coff[29];
  int total = 0;
  for (int i = 0; i < 29; ++i){
    tab.src[i] = d_in[conv_in_idx[i]];
    coff[i] = alloc((size_t)conv_n[i]);
    tab.dstoff[i] = coff[i];
    tab.cum[i] = total; total += conv_n[i];
  }
  tab.cum[29] = total;

  const int o_sWl = coff[20], o_sbl = coff[21];
  const int o_gWl = coff[23], o_gbl = coff[24], o_gWr = coff[25], o_gbr = coff[26];
  const int o_gatt = coff[27], o_gbias = coff[28];

  int o_wrcomb = alloc(4*16384);
  int o_sbcomb = alloc(512);
  int o_gbcomb = alloc(512);
  int o_gblx = alloc(384);
  int o_gbrx = alloc(384);
  int o_cnt  = alloc(SCAN_N);
  int o_rp   = alloc(SCAN_N);
  int o_woff = alloc(SCAN_N);
  int o_bsum = alloc(1024);
  int o_csr  = alloc(E_TOTAL);
  int o_part = alloc((size_t)36160*136);
  int o_aggS = alloc((size_t)1950*128);           // 5 buffers: 230,800,800,60,60 rows
  int o_outC0 = alloc(230*128);
  int o_outE2 = alloc(800*128);
  int o_outE7 = alloc(800*128);
  int o_outG4 = alloc(60*128);
  int o_outG6 = alloc(60*128);

  // bf16 buffers (ushort offsets)
  int u_bswz = allocU(573440);
  int u_xEb  = allocU(307200);
  int u_zC   = allocU(230*128);
  int u_zE   = allocU(800*128);
  int u_zG   = allocU(60*128);
  int u_sxC  = allocU(230*256);
  int u_sxE  = allocU(800*384);
  int u_sxG  = allocU(60*384);
  int u_yC   = allocU(230*128);
  int u_yE   = allocU(800*128);
  int u_yG   = allocU(60*128);
  int u_xl1  = allocU(230*128);
  int u_xl3  = allocU(800*128);
  int u_xl5  = allocU(60*128);
  int u_xl6  = allocU(800*128);
  int u_xl7  = allocU(60*128);
  int u_xr0  = allocU(230*128);
  int u_xr2  = allocU(800*128);
  int u_xr4  = allocU(60*128);
  int u_xr6  = allocU(60*128);
  int u_xr7  = allocU(800*128);
  int u_big0 = allocU((size_t)A_N*128);   // zA, then yA
  int u_bigH = allocU((size_t)A_N*128);   // hA, then outA
  int u_bigA = allocU((size_t)A_N*384);   // aggA, then gxl, then gxr

  if (off*4 > ws_size){
    ws_fail<<<1, 64, 0, stream>>>((float*)d_out, (float)((off*4) >> 20));
    return;
  }

  // swizzled-weight sub-offsets (within bswz)
  const int u_eAW2 = u_bswz + 0,      u_eCW2 = u_bswz + 16384;
  const int u_eEW2 = u_bswz + 32768,  u_eGW2 = u_bswz + 49152;
  const int u_eEW1 = u_bswz + 65536;
  const int u_sxAW = u_bswz + 114688, u_sxCW = u_bswz + 180224;
  const int u_sxEW = u_bswz + 212992, u_sxGW = u_bswz + 262144;
  const int u_gxlW = u_bswz + 311296, u_gxrW = u_bswz + 360448;
  int u_smW[10];
  for (int i = 0; i < 10; ++i) u_smW[i] = u_bswz + 409600 + i*16384;

  const int n_nodes[4] = {A_N, C_N, V_N, G_N};
  const int et_dst[8] = {1,0,2,0,3,0,3,2};
  const int et_ei[8]  = {4,4,5,5,6,6,7,7};
  const int et_rev[8] = {0,1,0,1,0,1,0,1};
  const int et_E[8]   = {100000,100000,500000,500000,300000,300000,2000,2000};

  const int* esp[8]; const int* edp[8]; int rowbase[8];
  {
    int rb = 0;
    for (int k = 0; k < 8; ++k){
      const int* ei = (const int*)d_in[et_ei[k]];
      int E = et_E[k];
      esp[k] = ei + (et_rev[k] ? E : 0);
      edp[k] = ei + (et_rev[k] ? 0 : E);
      rowbase[k] = rb; rb += n_nodes[et_dst[k]];
    }
  }
  int* rpb_p  = (int*)(wsf + o_rp);
  int* csr_p  = (int*)(wsf + o_csr);

  // ---------------- conversions / weight prep
  detect_dtype<<<1, 256, 0, stream>>>((const unsigned short*)d_in[2], flagp);
  convert_all<<<2048, 256, 0, stream>>>(tab, wsf, flagp, total);
  prep_combos<<<(4*16384 + 255)/256, 256, 0, stream>>>(wsf + coff[22], wsf + o_sbl,
      wsf + o_gbias, wsf + o_gbl, wsf + o_gbr,
      wsf + o_wrcomb, wsf + o_sbcomb, wsf + o_gbcomb, wsf + o_gblx, wsf + o_gbrx);

  SwzTab st; int sn = 0, stotal = 0;
  auto push = [&](int src, int K, int dst, int nkc, int kc0, int nt0, float sc){
    st.d[sn++] = SwzD{src, dst, K, nkc, kc0, nt0, sc};
    stotal += K*128;
  };
  push(coff[6],  128, u_eAW2, 4, 0, 0, 1.f);
  push(coff[10], 128, u_eCW2, 4, 0, 0, 1.f);
  push(coff[14], 128, u_eEW2, 4, 0, 0, 1.f);
  push(coff[18], 128, u_eGW2, 4, 0, 0, 1.f);
  push(coff[12], 384, u_eEW1, 12, 0, 0, 1.f);
  push(o_wrcomb + 0,     128, u_sxAW, 16, 0,  0, 1.f);
  push(o_sWl + 1*16384,  128, u_sxAW, 16, 4,  0, 1.f/3.f);
  push(o_sWl + 3*16384,  128, u_sxAW, 16, 8,  0, 1.f/3.f);
  push(o_sWl + 5*16384,  128, u_sxAW, 16, 12, 0, 1.f/3.f);
  push(o_wrcomb + 16384, 128, u_sxCW, 8, 0, 0, 1.f);
  push(o_sWl + 0*16384,  128, u_sxCW, 8, 4, 0, 1.f);
  push(o_wrcomb + 32768, 128, u_sxEW, 12, 0, 0, 1.f);
  push(o_sWl + 2*16384,  128, u_sxEW, 12, 4, 0, 0.5f);
  push(o_sWl + 7*16384,  128, u_sxEW, 12, 8, 0, 0.5f);
  push(o_wrcomb + 49152, 128, u_sxGW, 12, 0, 0, 1.f);
  push(o_sWl + 4*16384,  128, u_sxGW, 12, 4, 0, 0.5f);
  push(o_sWl + 6*16384,  128, u_sxGW, 12, 8, 0, 0.5f);
  push(o_gWl + 0*16384, 128, u_gxlW, 4, 0, 0,  1.f);
  push(o_gWl + 2*16384, 128, u_gxlW, 4, 0, 8,  1.f);
  push(o_gWl + 4*16384, 128, u_gxlW, 4, 0, 16, 1.f);
  push(o_gWr + 1*16384, 128, u_gxrW, 4, 0, 0,  1.f);
  push(o_gWr + 3*16384, 128, u_gxrW, 4, 0, 8,  1.f);
  push(o_gWr + 5*16384, 128, u_gxrW, 4, 0, 16, 1.f);
  const int xlk[5] = {1,3,5,6,7};
  for (int i = 0; i < 5; ++i) push(o_gWl + xlk[i]*16384, 128, u_smW[i], 4, 0, 0, 1.f);
  const int xrk[5] = {0,2,4,6,7};
  for (int i = 0; i < 5; ++i) push(o_gWr + xrk[i]*16384, 128, u_smW[5+i], 4, 0, 0, 1.f);
  st.n = sn; st.total = stotal;
  swz_batch<<<(stotal + 255)/256, 256, 0, stream>>>(wsf, wsu, st);

  // ---------------- CSR build (merged hist / place)
  hipMemsetAsync(wsf + o_cnt, 0, (size_t)SCAN_N*4, stream);
  {
    HTab ht; PTab pt;
    int hb = 0, pb = 0;
    for (int k = 0; k < 8; ++k){
      int E = et_E[k], nd = n_nodes[et_dst[k]];
      int small = (nd <= 800);
      ht.dp[k] = edp[k]; ht.E[k] = E; ht.cntoff[k] = rowbase[k];
      ht.ndst[k] = nd; ht.mode[k] = small;
      ht.bstart[k] = hb;
      hb += small ? imin(128, (E + 255)/256) : (E + 255)/256;
      pt.sp[k] = esp[k]; pt.dp[k] = edp[k]; pt.E[k] = E;
      pt.woffoff[k] = rowbase[k]; pt.ndst[k] = nd; pt.mode[k] = small;
      pt.bstart[k] = pb;
      pb += small ? imin(128, (E + 256*PCHUNK - 1)/(256*PCHUNK)) : (E + 255)/256;
    }
    ht.bstart[8] = hb; pt.bstart[8] = pb;
    hist_all<<<hb, 256, 0, stream>>>(ht, (int*)(wsf + o_cnt));
    scan1<<<SCAN_NB, 256, 0, stream>>>((int*)(wsf + o_cnt), rpb_p, (int*)(wsf + o_bsum));
    scan2<<<1, 512, 0, stream>>>((int*)(wsf + o_bsum));
    scan3<<<(SCAN_N + 255)/256, 256, 0, stream>>>(rpb_p, (int*)(wsf + o_woff),
                                                  (int*)(wsf + o_bsum));
    place_all<<<pb, 256, 0, stream>>>(pt, (int*)(wsf + o_woff), csr_p);
  }

  // ---------------- encoders (merged)
  {
    EncTab et2;
    et2.cum[0] = 0;
    et2.cum[1] = A_N*128;
    et2.cum[2] = et2.cum[1] + C_N*128;
    et2.cum[3] = et2.cum[2] + G_N*128;
    et2.cum[4] = et2.cum[3] + 307200;
    et2.xoff[0] = coff[0]; et2.woff[0] = coff[4];  et2.boff[0] = coff[5];
    et2.zoff[0] = u_big0;  et2.K[0] = 7;
    et2.xoff[1] = coff[1]; et2.woff[1] = coff[8];  et2.boff[1] = coff[9];
    et2.zoff[1] = u_zC;    et2.K[1] = 3;
    et2.xoff[2] = coff[3]; et2.woff[2] = coff[16]; et2.boff[2] = coff[17];
    et2.zoff[2] = u_zG;    et2.K[2] = 2;
    et2.xoff[3] = coff[2]; et2.woff[3] = 0; et2.boff[3] = 0;
    et2.zoff[3] = u_xEb;   et2.K[3] = 0;
    enc_batch<<<(et2.cum[4] + 255)/256, 256, 0, stream>>>(wsf, wsu, et2);
  }

  auto pushG = [&](GB2Tab& T, GB2 g){
    T.d[T.n] = g;
    T.b0[T.n + 1] = T.b0[T.n] + (g.M + 63)/64;
    T.n++;
  };

  // gemmA: country l2, event l1, games l2, athlete l2
  {
    GB2Tab t; t.n = 0; t.b0[0] = 0;
    pushG(t, GB2{u_zC, 128, 0,0,1000, u_eCW2, 4, coff[11], u_sxC, 256, C_N, 0, 0});
    pushG(t, GB2{u_xEb, 384, 0,0,1000, u_eEW1, 12, coff[13], u_zE, 128, V_N, FLAG_RELU, 0});
    pushG(t, GB2{u_zG, 128, 0,0,1000, u_eGW2, 4, coff[19], u_sxG, 384, G_N, 0, 0});
    pushG(t, GB2{u_big0, 128, 0,0,1000, u_eAW2, 4, coff[7], u_bigH, 128, A_N, 0, 0});
    mfma_gemm_b2<<<t.b0[t.n], 256, 0, stream>>>(d_ws, t);
  }
  // gemmB: event l2
  {
    GB2Tab t; t.n = 0; t.b0[0] = 0;
    pushG(t, GB2{u_zE, 128, 0,0,1000, u_eEW2, 4, coff[15], u_sxE, 384, V_N, 0, 0});
    mfma_gemm_b2<<<t.b0[t.n], 256, 0, stream>>>(d_ws, t);
  }

  // ---------------- SAGE layer (merged gathers)
  hipMemsetAsync(wsf + o_aggS, 0, (size_t)1950*128*4, stream);
  const int b0 = o_aggS, b2 = o_aggS + 230*128, b7 = b2 + 800*128,
            b4 = b7 + 800*128, b6 = b4 + 60*128;
  SgTab sg;
  sg.d[0] = SgD{u_bigH, 128, rowbase[0], b0, C_N, 32};
  sg.d[1] = SgD{u_bigH, 128, rowbase[2], b2, V_N, 16};
  sg.d[2] = SgD{u_sxG, 384, rowbase[7], b7, V_N, 8};
  sg.d[3] = SgD{u_bigH, 128, rowbase[4], b4, G_N, 128};
  sg.d[4] = SgD{u_sxE, 384, rowbase[6], b6, G_N, 32};
  sg.cumw[0] = 0;
  {
    int c = 0;
    for (int i = 0; i < 5; ++i){ c += sg.d[i].nd*sg.d[i].nc; sg.cumw[i+1] = c; }
  }
  {
    int waves = A_N + sg.cumw[5];
    sage_all<<<(waves*64 + 255)/256, 256, 0, stream>>>(wsu, wsf, csr_p, rpb_p, sg,
        u_sxC, u_sxE, u_sxG, rowbase[1], rowbase[3], rowbase[5], u_bigA);
  }
  AfTab af; af.n = 5;
  af.d[0] = AfD{b0, rowbase[0], u_sxC + 128, 256, C_N};
  af.d[1] = AfD{b2, rowbase[2], u_sxE + 128, 384, V_N};
  af.d[2] = AfD{b7, rowbase[7], u_sxE + 256, 384, V_N};
  af.d[3] = AfD{b4, rowbase[4], u_sxG + 128, 384, G_N};
  af.d[4] = AfD{b6, rowbase[6], u_sxG + 256, 384, G_N};
  int aftot = 1950*128;
  aggfin_batch<<<(aftot + 255)/256, 256, 0, stream>>>(wsu, wsf, rpb_p, af, aftot);

  // gemmC: SAGE linears (C/E/G) + athlete K=512
  {
    GB2Tab t; t.n = 0; t.b0[0] = 0;
    pushG(t, GB2{u_sxC, 256, 0,0,1000, u_sxCW, 8,  o_sbcomb + 128, u_yC, 128, C_N, FLAG_RELU, 0});
    pushG(t, GB2{u_sxE, 384, 0,0,1000, u_sxEW, 12, o_sbcomb + 256, u_yE, 128, V_N, FLAG_RELU, 0});
    pushG(t, GB2{u_sxG, 384, 0,0,1000, u_sxGW, 12, o_sbcomb + 384, u_yG, 128, G_N, FLAG_RELU, 0});
    pushG(t, GB2{u_bigH, 128, u_bigA, 384, 4, u_sxAW, 16, o_sbcomb, u_big0, 128, A_N, FLAG_RELU, 0});
    mfma_gemm_b2<<<t.b0[t.n], 256, 0, stream>>>(d_ws, t);
  }

  // ---------------- GAT layer
  // gemmD: gxl (3 col-groups) + 10 small frag GEMMs
  {
    GB2Tab t; t.n = 0; t.b0[0] = 0;
    pushG(t, GB2{u_big0, 128, 0,0,1000, u_gxlW, 4, o_gblx, u_bigA, 384, A_N, 0, 0});
    pushG(t, GB2{u_big0, 128, 0,0,1000, u_gxlW, 4, o_gblx, u_bigA, 384, A_N, 0, 1});
    pushG(t, GB2{u_big0, 128, 0,0,1000, u_gxlW, 4, o_gblx, u_bigA, 384, A_N, 0, 2});
    pushG(t, GB2{u_yC, 128, 0,0,1000, u_smW[0], 4, o_gbl + 1*128, u_xl1, 128, C_N, 0, 0});
    pushG(t, GB2{u_yE, 128, 0,0,1000, u_smW[1], 4, o_gbl + 3*128, u_xl3, 128, V_N, 0, 0});
    pushG(t, GB2{u_yG, 128, 0,0,1000, u_smW[2], 4, o_gbl + 5*128, u_xl5, 128, G_N, 0, 0});
    pushG(t, GB2{u_yE, 128, 0,0,1000, u_smW[3], 4, o_gbl + 6*128, u_xl6, 128, V_N, 0, 0});
    pushG(t, GB2{u_yG, 128, 0,0,1000, u_smW[4], 4, o_gbl + 7*128, u_xl7, 128, G_N, 0, 0});
    pushG(t, GB2{u_yC, 128, 0,0,1000, u_smW[5], 4, o_gbr + 0*128, u_xr0, 128, C_N, 0, 0});
    pushG(t, GB2{u_yE, 128, 0,0,1000, u_smW[6], 4, o_gbr + 2*128, u_xr2, 128, V_N, 0, 0});
    pushG(t, GB2{u_yG, 128, 0,0,1000, u_smW[7], 4, o_gbr + 4*128, u_xr4, 128, G_N, 0, 0});
    pushG(t, GB2{u_yG, 128, 0,0,1000, u_smW[8], 4, o_gbr + 6*128, u_xr6, 128, G_N, 0, 0});
    pushG(t, GB2{u_yE, 128, 0,0,1000, u_smW[9], 4, o_gbr + 7*128, u_xr7, 128, V_N, 0, 0});
    mfma_gemm_b2<<<t.b0[t.n], 256, 0, stream>>>(d_ws, t);
  }

  GoTab go;
  go.d[0] = GoD{u_bigA + 0,   384, u_xr0, o_gatt + 0*128, rowbase[0], 0,     C_N, 32};
  go.d[1] = GoD{u_bigA + 128, 384, u_xr2, o_gatt + 2*128, rowbase[2], 7360,  V_N, 16};
  go.d[2] = GoD{u_bigA + 256, 384, u_xr4, o_gatt + 4*128, rowbase[4], 20160, G_N, 128};
  go.d[3] = GoD{u_xl6, 128,        u_xr6, o_gatt + 6*128, rowbase[6], 27840, G_N, 32};
  go.d[4] = GoD{u_xl7, 128,        u_xr7, o_gatt + 7*128, rowbase[7], 29760, V_N, 8};
  go.cumw[0] = 0;
  {
    int c = 0;
    for (int i = 0; i < 5; ++i){ c += go.d[i].nd*go.d[i].nc; go.cumw[i+1] = c; }
  }
  gat_online_batch<<<(go.cumw[5]*64 + 255)/256, 256, 0, stream>>>(wsu, wsf, csr_p, rpb_p,
      wsf + o_part, go);

  // gemmE: gxr -> bigA (gxl dead after gat_online_batch)
  {
    GB2Tab t; t.n = 0; t.b0[0] = 0;
    pushG(t, GB2{u_big0, 128, 0,0,1000, u_gxrW, 4, o_gbrx, u_bigA, 384, A_N, 0, 0});
    pushG(t, GB2{u_big0, 128, 0,0,1000, u_gxrW, 4, o_gbrx, u_bigA, 384, A_N, 0, 1});
    pushG(t, GB2{u_big0, 128, 0,0,1000, u_gxrW, 4, o_gbrx, u_bigA, 384, A_N, 0, 2});
    mfma_gemm_b2<<<t.b0[t.n], 256, 0, stream>>>(d_ws, t);
  }
  gat_ath<<<(A_N*64 + 255)/256, 256, 0, stream>>>(wsu, wsf, csr_p, rpb_p,
      u_bigA, u_xl1, u_xl3, u_xl5, o_gatt, rowbase[1], rowbase[3], rowbase[5], u_bigH);

  MgTab mg;
  mg.d[0] = MgD{0,     o_outC0, C_N, 32,  1.0f};
  mg.d[1] = MgD{7360,  o_outE2, V_N, 16,  0.5f};
  mg.d[2] = MgD{20160, o_outG4, G_N, 128, 0.5f};
  mg.d[3] = MgD{27840, o_outG6, G_N, 32,  0.5f};
  mg.d[4] = MgD{29760, o_outE7, V_N, 8,   0.5f};
  mg.cumw[0] = 0;
  {
    int c = 0;
    for (int i = 0; i < 5; ++i){ c += mg.d[i].nd; mg.cumw[i+1] = c; }
  }
  gat_merge_batch<<<(mg.cumw[5]*64 + 255)/256, 256, 0, stream>>>(wsf + o_part, wsf, mg);

  final_out<<<(101090*128 + 255)/256, 256, 0, stream>>>(wsu, wsf, u_bigH,
      o_outC0, o_outE2, o_outE7, o_outG4, o_outG6, o_gbcomb, flagp, d_out);
}